// Round 11
// baseline (212.967 us; speedup 1.0000x reference)
//
#include <hip/hip_runtime.h>
#include <cstdint>
#include <math.h>

typedef unsigned short us;
typedef __attribute__((ext_vector_type(8))) __bf16 bf16x8;
typedef __attribute__((ext_vector_type(8))) unsigned short ushort8;
typedef __attribute__((ext_vector_type(4))) float f32x4;

__device__ __forceinline__ us f2bf(float x){
  union { float f; unsigned int u; } v; v.f = x;
  unsigned int r = v.u + 0x7FFFu + ((v.u >> 16) & 1u);   // RNE
  return (us)(r >> 16);
}
__device__ __forceinline__ float b2f(us u){
  union { unsigned int u; float f; } v; v.u = ((unsigned int)u) << 16; return v.f;
}
__device__ __forceinline__ void split2(float x, us& hi, us& lo){
  hi = f2bf(x); lo = f2bf(x - b2f(hi));
}
__device__ __forceinline__ f32x4 fzero(){ f32x4 v; v.x=0.f; v.y=0.f; v.z=0.f; v.w=0.f; return v; }
__device__ __forceinline__ f32x4 mfma16(bf16x8 a, bf16x8 b, f32x4 c){
  return __builtin_amdgcn_mfma_f32_16x16x32_bf16(a, b, c, 0, 0, 0);
}
__device__ __forceinline__ void gload_lds16(const void* g, void* l){
  __builtin_amdgcn_global_load_lds(
      (const __attribute__((address_space(1))) unsigned int*)(uintptr_t)g,
      (__attribute__((address_space(3))) unsigned int*)(uintptr_t)l,
      16, 0, 0);
}

// exp2-folded scales
#define QS2 (0.07216878364870322f * 1.4426950408889634f)   // 1/sqrt(192) * log2(e)
#define BS  (0.08838834764831845f * 1.4426950408889634f)   // 1/sqrt(128) * log2(e)

// ---------------- 1: fused prep: convx | convw | lnrel | bucket ----------------
__global__ __launch_bounds__(256) void k_prep(const float* __restrict__ xq,
                                              const float* __restrict__ xkv,
                                              const float* __restrict__ w0, const float* __restrict__ w1,
                                              const float* __restrict__ w2, const float* __restrict__ w3,
                                              const float* __restrict__ w4, const float* __restrict__ w5,
                                              const float* __restrict__ rel,
                                              const float* __restrict__ g, const float* __restrict__ bLN,
                                              us* __restrict__ qhi, us* __restrict__ kvhi,
                                              us* __restrict__ wt, us* __restrict__ reln_hi,
                                              signed char* __restrict__ idxt)
{
  __shared__ float tile[32][33];
  __shared__ float sm[8];
  const int bid = blockIdx.x, t = threadIdx.x;

  if (bid < 8192){                      // ---- convx (hi only)
    int i = bid * 256 + t;
    const float* src; us* dh;
    if (i < 1048576){ src = xq  + (size_t)i*4;           dh = qhi  + (size_t)i*4; }
    else            { src = xkv + (size_t)(i-1048576)*4; dh = kvhi + (size_t)(i-1048576)*4; }
    f32x4 v = *(const f32x4*)src;
    dh[0]=f2bf(v.x); dh[1]=f2bf(v.y); dh[2]=f2bf(v.z); dh[3]=f2bf(v.w);
    return;
  }
  if (bid < 14336){                     // ---- convw: transpose + hi/lo split
    int rem = bid - 8192;
    int z = rem >> 10, r2 = rem & 1023;
    const float* W = (z==0)?w0:(z==1)?w1:(z==2)?w2:(z==3)?w3:(z==4)?w4:w5;
    us* dst_hi = wt + (size_t)z * 2097152;
    us* dst_lo = dst_hi + 1048576;
    bool wlo = (z == 2) || (z == 5);
    int n0 = (r2 & 31) * 32, k0 = (r2 >> 5) * 32;
    int c = t & 31, r = t >> 5;
#pragma unroll
    for (int i = 0; i < 4; i++)
      tile[r + i*8][c] = W[(size_t)(k0 + r + i*8)*1024 + n0 + c];
    __syncthreads();
#pragma unroll
    for (int i = 0; i < 4; i++){
      int nn = r + i*8;
      us h,l; split2(tile[c][nn], h, l);
      dst_hi[(size_t)(n0 + nn)*1024 + k0 + c] = h;
      if (wlo) dst_lo[(size_t)(n0 + nn)*1024 + k0 + c] = l;
    }
    return;
  }
  if (bid < 14400){                     // ---- lnrel
    int row = bid - 14336;
    const float* x = rel + (size_t)row * 1024;
    float v[4]; float s = 0.f, ss = 0.f;
#pragma unroll
    for (int i=0;i<4;i++){ v[i] = x[t + 256*i]; s += v[i]; ss += v[i]*v[i]; }
    for (int o=32;o;o>>=1){ s += __shfl_xor(s,o); ss += __shfl_xor(ss,o); }
    int w = t >> 6;
    if ((t & 63) == 0){ sm[w] = s; sm[4+w] = ss; }
    __syncthreads();
    s  = sm[0]+sm[1]+sm[2]+sm[3];
    ss = sm[4]+sm[5]+sm[6]+sm[7];
    float mu  = s  * (1.0f/1024.0f);
    float var = ss * (1.0f/1024.0f) - mu*mu;
    float rs  = rsqrtf(var + 1e-5f);
#pragma unroll
    for (int i=0;i<4;i++){
      int cc = t + 256*i;
      reln_hi[(size_t)row*1024 + cc] = f2bf((v[i]-mu)*rs*g[cc] + bLN[cc]);
    }
    return;
  }
  {                                     // ---- bucket table
    int i = (bid - 14400) * 256 + t;
    if (i >= 2052) return;
    int d = i - 1023;
    int ad = d < 0 ? -d : d;
    int abspos = (d < 16 && d > -16) ? 15 : ad;
    int bucket;
    if (abspos <= 16) bucket = d;
    else {
      float num = (float)log((double)abspos * 0.0625);
      float den = (float)log(7.9375);
      float lp = ceilf(num / den * 15.0f) + 16.0f;
      bucket = (int)lp * (d > 0 ? 1 : -1);
    }
    int s = bucket + 32;
    s = s < 0 ? 0 : (s > 63 ? 63 : s);
    idxt[i] = (signed char)s;
  }
}

// ---------------- 2: merged QKV GEMM, uniform work: 4 classes x 256 blocks x NKT=32 ----------------
// cls 0: Q -> qbuf bf16; cls 1: K -> kbuf bf16;
// cls 2: Xkv@Wv_hi -> vtb_p0 fp32; cls 3: Xkv@Wv_lo -> vtb_p1 fp32 (no bias; combined in k_cp)
// blocks [1024,1056): pos_k / pos_q projections
__global__ __launch_bounds__(256) void k_qkvp(const us* __restrict__ Xq, const us* __restrict__ Xkv,
                                              const us* __restrict__ wt,
                                              const float* __restrict__ bq, const float* __restrict__ bk,
                                              const us* __restrict__ reln_hi,
                                              const float* __restrict__ bpk, const float* __restrict__ bpq,
                                              us* __restrict__ qbuf, us* __restrict__ kbuf,
                                              float* __restrict__ vtb_p0, float* __restrict__ vtb_p1,
                                              us* __restrict__ posk_hi, us* __restrict__ posq_hi)
{
  __shared__ __align__(16) us a_lds[2][4096];   // 128 x 32
  __shared__ __align__(16) us b_lds[2][4096];   // 128 x 32
  const int bid = blockIdx.x;
  const int t = threadIdx.x, w = t >> 6, lane = t & 63, lg = lane >> 4, li = lane & 15;

  if (bid >= 1024){                     // ---- pos projections (32 blocks)
    int wg2 = bid - 1024;
    int ntile = wg2 & 15, z = wg2 >> 4;
    const us* W_hi = wt + (size_t)(3 + z) * 2097152;
    const float* bias = z ? bpq : bpk;
    us* out_hi = z ? posq_hi : posk_hi;
    f32x4 acc[4];
#pragma unroll
    for (int i=0;i<4;i++) acc[i] = fzero();
    int srow = w*16 + li;
    for (int kt = 0; kt < 32; kt++){
      int k0 = kt*32 + lg*8;
      bf16x8 a = *(const bf16x8*)(reln_hi + (size_t)srow*1024 + k0);
#pragma unroll
      for (int nf=0; nf<4; nf++){
        int n = ntile*64 + nf*16 + li;
        bf16x8 b = *(const bf16x8*)(W_hi + (size_t)n*1024 + k0);
        acc[nf] = mfma16(a, b, acc[nf]);
      }
    }
#pragma unroll
    for (int nf=0;nf<4;nf++){
      int n = ntile*64 + nf*16 + li;
      float bn = bias[n];
      int h = n >> 6, hd = n & 63;
#pragma unroll
      for (int j=0;j<4;j++){
        int s = w*16 + lg*4 + j;
        out_hi[(size_t)h*4096 + s*64 + hd] = f2bf(acc[nf][j] + bn);
      }
    }
    return;
  }

  // ---- QKV classes: uniform NKT=32, each class spread over all XCDs (256 consecutive bids)
  int cls = bid >> 8;                          // 0:Q 1:K 2:Vhi 3:Vlo
  int u = bid & 255;
  int tile = (u & 7) * 32 + (u >> 3);          // XCD-contiguous tile chunk within class
  int mt = tile >> 3, nt = tile & 7;
  int m0 = mt * 128, n0 = nt * 128;
  const us* A = (cls == 0) ? Xq : Xkv;
  const us* Bbase = wt + (size_t)(cls < 2 ? cls : 2) * 2097152;
  const us* Bp = (cls == 3) ? Bbase + 1048576 : Bbase;
  int wm = w >> 1, wn = w & 1;
  f32x4 acc[4][4];
#pragma unroll
  for (int i=0;i<4;i++)
#pragma unroll
    for (int j=0;j<4;j++) acc[i][j] = fzero();

  auto stage = [&](int buf, int kt){
    int k0 = kt * 32;
#pragma unroll
    for (int c = 0; c < 2; c++){
      int slot = c*256 + t;
      int g = slot ^ ((slot >> 3) & 7);
      int r = g >> 2, kc = g & 3;
      gload_lds16(A  + (size_t)(m0 + r)*1024 + k0 + kc*8, (char*)&a_lds[buf][0] + slot*16);
      gload_lds16(Bp + (size_t)(n0 + r)*1024 + k0 + kc*8, (char*)&b_lds[buf][0] + slot*16);
    }
  };

  stage(0, 0);
  __syncthreads();
  int buf = 0;
  for (int kt = 0; kt < 32; kt++){
    if (kt + 1 < 32) stage(buf ^ 1, kt + 1);
    bf16x8 af[4], bfv[4];
#pragma unroll
    for (int mi=0;mi<4;mi++){
      int r = wm*64 + mi*16 + li;
      int s = (r*4 + lg); s ^= ((s >> 3) & 7);
      af[mi] = *(const bf16x8*)((char*)&a_lds[buf][0] + s*16);
    }
#pragma unroll
    for (int ni=0;ni<4;ni++){
      int r = wn*64 + ni*16 + li;
      int s = (r*4 + lg); s ^= ((s >> 3) & 7);
      bfv[ni] = *(const bf16x8*)((char*)&b_lds[buf][0] + s*16);
    }
#pragma unroll
    for (int mi=0;mi<4;mi++)
#pragma unroll
      for (int ni=0;ni<4;ni++)
        acc[mi][ni] = mfma16(af[mi], bfv[ni], acc[mi][ni]);
    __syncthreads();
    buf ^= 1;
  }

#pragma unroll
  for (int ni=0;ni<4;ni++){
    int n = n0 + wn*64 + ni*16 + li;
    float bn = (cls == 0) ? bq[n] : (cls == 1) ? bk[n] : 0.f;
    int hh = n >> 6, hd = n & 63;
#pragma unroll
    for (int mi=0;mi<4;mi++){
      int mb = m0 + wm*64 + mi*16 + lg*4;
#pragma unroll
      for (int j=0;j<4;j++){
        int m = mb + j;
        float val = acc[mi][ni][j] + bn;
        int bb = m >> 10, tp = m & 1023;
        if (cls >= 2){
          float* dst = (cls == 2) ? vtb_p0 : vtb_p1;
          dst[(((size_t)(bb*16 + hh))*64 + hd)*1024 + tp] = val;
        } else {
          us* out = cls ? kbuf : qbuf;
          out[(((size_t)(bb*16 + hh))*1024 + tp)*64 + hd] = f2bf(val);
        }
      }
    }
  }
}

// ---------------- 3: O GEMM: 3 products, BM=128, BN=64, fp32 out ----------------
__global__ __launch_bounds__(256, 2) void k_gemmo(const us* __restrict__ A_hi, const us* __restrict__ A_lo,
                                                  const us* __restrict__ B_hi, const us* __restrict__ B_lo,
                                                  const float* __restrict__ bias,
                                                  float* __restrict__ out_f)
{
  __shared__ __align__(16) us a_lds[2][4096];
  __shared__ __align__(16) us b_lds[2][2048];
  int bid = blockIdx.x;
  int wg = (bid & 7) * 64 + (bid >> 3);        // 512 % 8 == 0
  int mt = wg >> 4, nt = wg & 15;
  int m0 = mt * 128, n0 = nt * 64;
  int t = threadIdx.x, w = t >> 6, lane = t & 63, lg = lane >> 4, li = lane & 15;
  int wm = w >> 1, wn = w & 1;
  f32x4 acc[4][2];
#pragma unroll
  for (int i=0;i<4;i++){ acc[i][0]=fzero(); acc[i][1]=fzero(); }

  auto stage = [&](int buf, int kt){
    int seg = kt >> 5, k0 = (kt & 31) * 32;
    const us* Ap = (seg == 2) ? A_lo : A_hi;
    const us* Bp = (seg == 1) ? B_lo : B_hi;
#pragma unroll
    for (int c = 0; c < 2; c++){
      int slot = c*256 + t;
      int g = slot ^ ((slot >> 3) & 7);
      int r = g >> 2, kc = g & 3;
      gload_lds16(Ap + (size_t)(m0 + r)*1024 + k0 + kc*8, (char*)&a_lds[buf][0] + slot*16);
    }
    {
      int slot = t;
      int g = slot ^ ((slot >> 3) & 7);
      int r = g >> 2, kc = g & 3;
      gload_lds16(Bp + (size_t)(n0 + r)*1024 + k0 + kc*8, (char*)&b_lds[buf][0] + slot*16);
    }
  };

  stage(0, 0);
  __syncthreads();
  int buf = 0;
  for (int kt = 0; kt < 96; kt++){
    if (kt + 1 < 96) stage(buf ^ 1, kt + 1);
    bf16x8 af[4], bfv[2];
#pragma unroll
    for (int mi=0;mi<4;mi++){
      int r = wm*64 + mi*16 + li;
      int s = (r*4 + lg); s ^= ((s >> 3) & 7);
      af[mi] = *(const bf16x8*)((char*)&a_lds[buf][0] + s*16);
    }
#pragma unroll
    for (int ni=0;ni<2;ni++){
      int r = wn*32 + ni*16 + li;
      int s = (r*4 + lg); s ^= ((s >> 3) & 7);
      bfv[ni] = *(const bf16x8*)((char*)&b_lds[buf][0] + s*16);
    }
#pragma unroll
    for (int mi=0;mi<4;mi++)
#pragma unroll
      for (int ni=0;ni<2;ni++)
        acc[mi][ni] = mfma16(af[mi], bfv[ni], acc[mi][ni]);
    __syncthreads();
    buf ^= 1;
  }

#pragma unroll
  for (int ni=0;ni<2;ni++){
    int n = n0 + wn*32 + ni*16 + li;
    float bn = bias[n];
#pragma unroll
    for (int mi=0;mi<4;mi++){
      int mb = m0 + wm*64 + mi*16 + lg*4;
#pragma unroll
      for (int j=0;j<4;j++)
        out_f[(size_t)(mb + j)*1024 + n] = acc[mi][ni][j] + bn;
    }
  }
}

// ---------------- 4: c2p/p2c (z=0,1) + V-partial combine (z=2) ----------------
__global__ __launch_bounds__(256) void k_cp(const us* __restrict__ q_hi,
                                            const us* __restrict__ k_hi,
                                            const us* __restrict__ pk_hi,
                                            const us* __restrict__ pq_hi,
                                            const float* __restrict__ vtb_p0,
                                            const float* __restrict__ vtb_p1,
                                            const float* __restrict__ bv,
                                            us* __restrict__ c2p, us* __restrict__ p2c,
                                            us* __restrict__ vtb)
{
  int qt = blockIdx.x, bh = blockIdx.y, z = blockIdx.z;
  int t = threadIdx.x;
  if (z == 2){                          // ---- combine: vtb = bf16(p0 + p1 + bias)
    int bx = qt + (bh << 4);            // 0..1023
    size_t base = (size_t)bx*4096 + t*16;
    int n = ((int)(base >> 16) & 15) * 64 + ((int)(base >> 10) & 63);  // hh*64+hd
    float bn = bv[n];
    us outv[16];
#pragma unroll
    for (int c = 0; c < 4; c++){
      f32x4 a = *(const f32x4*)(vtb_p0 + base + c*4);
      f32x4 b = *(const f32x4*)(vtb_p1 + base + c*4);
      outv[c*4+0] = f2bf(a.x + b.x + bn);
      outv[c*4+1] = f2bf(a.y + b.y + bn);
      outv[c*4+2] = f2bf(a.z + b.z + bn);
      outv[c*4+3] = f2bf(a.w + b.w + bn);
    }
    *(ushort8*)(vtb + base)     = *(ushort8*)&outv[0];
    *(ushort8*)(vtb + base + 8) = *(ushort8*)&outv[8];
    return;
  }
  const us* X_hi = z ? k_hi : q_hi;
  const us* P_hi = z ? pq_hi : pk_hi;
  us* out = z ? p2c : c2p;
  int h = bh & 15;
  int w = t >> 6, lane = t & 63, lg = lane >> 4, li = lane & 15;
  f32x4 acc[4];
#pragma unroll
  for (int i=0;i<4;i++) acc[i] = fzero();
  size_t row = (size_t)bh*1024 + qt*64 + w*16 + li;
#pragma unroll
  for (int kk=0;kk<2;kk++){
    int k = kk*32 + lg*8;
    bf16x8 ah = *(const bf16x8*)(X_hi + row*64 + k);
#pragma unroll
    for (int nf=0;nf<4;nf++){
      int s = nf*16 + li;
      bf16x8 bh_ = *(const bf16x8*)(P_hi + (size_t)h*4096 + s*64 + k);
      acc[nf] = mfma16(ah, bh_, acc[nf]);
    }
  }
  size_t obase = ((size_t)bh*1024 + qt*64 + w*16 + lg*4) * 64;
#pragma unroll
  for (int nf=0;nf<4;nf++)
#pragma unroll
    for (int j=0;j<4;j++)
      out[obase + (size_t)j*64 + nf*16 + li] = f2bf(acc[nf][j] * BS);
}

// ---------------- 5: fused attention: 8 waves, QBLK=128, far fast path ----------------
__global__ __launch_bounds__(512) void k_attn(const us* __restrict__ qhi,
                                              const us* __restrict__ khi,
                                              const us* __restrict__ vhi,
                                              const us* __restrict__ c2p, const us* __restrict__ p2c,
                                              const signed char* __restrict__ idxt,
                                              const unsigned char* __restrict__ mask,
                                              us* __restrict__ ctx_hi, us* __restrict__ ctx_lo)
{
  __shared__ __align__(16) us khi_lds[4096], vhi_lds[4096];
  __shared__ __align__(16) us c2p_lds[128*72], p2c_lds[64*72];   // padded rows: 144B stride
  __shared__ __align__(16) us p_lds[8][1024];
  __shared__ signed char idx_lds[2048];

  const int qt = blockIdx.x, bh = blockIdx.y;   // qt: 0..7
  const int b = bh >> 4, h = bh & 15;
  const int t = threadIdx.x, w = t >> 6, lane = t & 63, lg = lane >> 4, li = lane & 15;
  const int q0 = qt * 128;

  for (int i = t; i < 2047; i += 512) idx_lds[i] = idxt[i];
  {
    const us* src = c2p + ((size_t)bh*1024 + q0) * 64;
#pragma unroll
    for (int c = 0; c < 2; c++){
      int f = c*512 + t, r = f >> 3, kc = f & 7;
      *(ushort8*)&c2p_lds[r*72 + kc*8] = *(const ushort8*)(src + r*64 + kc*8);
    }
  }
  bf16x8 qfh[2];
  {
    const us* qph = qhi + ((size_t)bh*1024 + q0 + w*16 + li)*64 + lg*8;
    qfh[0] = *(const bf16x8*)(qph); qfh[1] = *(const bf16x8*)(qph + 32);
  }
  __syncthreads();
  // far-path per-row bias (scaled) for idx=0 / idx=63
  float cq0[4], cq63[4];
#pragma unroll
  for (int j=0;j<4;j++){
    int qloc = w*16 + lg*4 + j;
    cq0[j]  = b2f(c2p_lds[qloc*72 + 0]);
    cq63[j] = b2f(c2p_lds[qloc*72 + 63]);
  }

  float lrow[4];
  f32x4 accO[4];
#pragma unroll
  for (int j=0;j<4;j++){ lrow[j] = 0.f; accO[j] = fzero(); }
  const unsigned char* mptr = mask + b*1024;

  for (int kt = 0; kt < 16; kt++){
    const int k0 = kt * 64;
    const bool far = (q0 - k0 >= 192) || (k0 - q0 >= 256);
    __syncthreads();
    {  // stage K,V: one 16B chunk each per thread
      int r = t >> 3, kc = t & 7;
      *(ushort8*)&khi_lds[r*64 + ((kc ^ (r & 7))*8)] =
          *(const ushort8*)(khi + ((size_t)bh*1024 + k0 + r)*64 + kc*8);
      *(ushort8*)&vhi_lds[r*64 + ((kc ^ (r & 7))*8)] =
          *(const ushort8*)(vhi + ((size_t)bh*64 + r)*1024 + k0 + kc*8);
      if (!far)
        *(ushort8*)&p2c_lds[r*72 + kc*8] =
            *(const ushort8*)(p2c + ((size_t)bh*1024 + k0 + r)*64 + kc*8);
    }
    __syncthreads();

    // QK^T single product
    f32x4 sfr[4];
#pragma unroll
    for (int nf=0;nf<4;nf++) sfr[nf] = fzero();
#pragma unroll
    for (int kk=0; kk<2; kk++){
      int kc = kk*4 + lg;
#pragma unroll
      for (int nf=0; nf<4; nf++){
        int r = nf*16 + li;
        bf16x8 bh_ = *(const bf16x8*)&khi_lds[r*64 + ((kc ^ (r & 7))*8)];
        sfr[nf] = mfma16(qfh[kk], bh_, sfr[nf]);
      }
    }
    us* pl = &p_lds[w][0];
    if (far){
      const int cidx = (q0 > k0) ? 63 : 0;
      float cq[4];
#pragma unroll
      for (int j=0;j<4;j++) cq[j] = (q0 > k0) ? cq63[j] : cq0[j];
#pragma unroll
      for (int nf=0; nf<4; nf++){
        int kloc = nf*16 + li;
        bool mk = mptr[k0 + kloc] != 0;
        float ck = b2f(p2c[((size_t)bh*1024 + k0 + kloc)*64 + cidx]);
        int col = kloc;
#pragma unroll
        for (int j=0;j<4;j++){
          float p = mk ? 0.f : exp2f(fmaf(sfr[nf][j], QS2, cq[j] + ck));
          lrow[j] += p;
          int row = lg*4 + j;
          pl[row*64 + ((col & 7) | ((((col >> 3) ^ (row & 7))) << 3))] = f2bf(p);
        }
      }
    } else {
#pragma unroll
      for (int nf=0; nf<4; nf++){
        int kloc = nf*16 + li;
        bool mk = mptr[k0 + kloc] != 0;
        int col = kloc;
#pragma unroll
        for (int j=0;j<4;j++){
          int qloc = w*16 + lg*4 + j;
          int d = (q0 + qloc) - (k0 + kloc);
          int idx = (int)idx_lds[d + 1023];
          float s2 = fmaf(sfr[nf][j], QS2,
                          b2f(c2p_lds[qloc*72 + idx]) + b2f(p2c_lds[kloc*72 + idx]));
          float p = mk ? 0.f : exp2f(s2);
          lrow[j] += p;
          int row = lg*4 + j;
          pl[row*64 + ((col & 7) | ((((col >> 3) ^ (row & 7))) << 3))] = f2bf(p);
        }
      }
    }
    // PV single product (p_lds wave-private; same-wave DS ordering)
#pragma unroll
    for (int kk=0;kk<2;kk++){
      int kc = kk*4 + lg;
      bf16x8 af = *(const bf16x8*)((char*)pl + li*128 + ((kc ^ (li & 7)) * 16));
#pragma unroll
      for (int nf=0;nf<4;nf++){
        int r = nf*16 + li;
        bf16x8 bh_ = *(const bf16x8*)&vhi_lds[r*64 + ((kc ^ (r & 7))*8)];
        accO[nf] = mfma16(af, bh_, accO[nf]);
      }
    }
  }

  for (int o=1;o<16;o<<=1)
#pragma unroll
    for (int j=0;j<4;j++)
      lrow[j] += __shfl_xor(lrow[j], o);
#pragma unroll
  for (int nf=0;nf<4;nf++)
#pragma unroll
    for (int j=0;j<4;j++){
      int qloc = w*16 + lg*4 + j;
      float o = accO[nf][j] / lrow[j];
      size_t idx = ((size_t)(b*1024 + q0 + qloc))*1024 + h*64 + nf*16 + li;
      us hh,ll; split2(o,hh,ll);
      ctx_hi[idx] = hh; ctx_lo[idx] = ll;
    }
}

// ---------------- launch ----------------
extern "C" void kernel_launch(void* const* d_in, const int* in_sizes, int n_in,
                              void* d_out, int out_size, void* d_ws, size_t ws_size,
                              hipStream_t stream)
{
  (void)in_sizes; (void)n_in; (void)out_size; (void)ws_size;
  const float* query = (const float*)d_in[0];
  const float* kvst  = (const float*)d_in[1];
  const unsigned char* mask = (const unsigned char*)d_in[2];
  const float* Wq = (const float*)d_in[3];  const float* bq = (const float*)d_in[4];
  const float* Wk = (const float*)d_in[5];  const float* bk = (const float*)d_in[6];
  const float* Wv = (const float*)d_in[7];  const float* bv = (const float*)d_in[8];
  const float* Wo = (const float*)d_in[9];  const float* bo = (const float*)d_in[10];
  const float* rel = (const float*)d_in[11];
  const float* lng = (const float*)d_in[12]; const float* lnb = (const float*)d_in[13];
  const float* Wpk = (const float*)d_in[14]; const float* bpk = (const float*)d_in[15];
  const float* Wpq = (const float*)d_in[16]; const float* bpq = (const float*)d_in[17];

  char* ws = (char*)d_ws;
  const size_t MB = 1024*1024;
  // layout (89MB, no live overlaps; fp32 V-partials are 16MB each):
  us*    Xq_hi   = (us*)(ws + 0);        // [0,8)   dead after k_qkvp
  us*    c2p     = (us*)(ws + 0);        //         k_cp z=0 writes (after k_qkvp)
  us*    Xkv_hi  = (us*)(ws + 8*MB);     // [8,16)  dead after k_qkvp
  us*    p2c     = (us*)(ws + 8*MB);     //         k_cp z=1 writes
  us*    Wt      = (us*)(ws + 16*MB);    // [16,40) 6 slots x 4MB; slots0-1 dead after k_qkvp
  us*    vtb     = (us*)(ws + 16*MB);    //         k_cp z=2 writes over Wq/Wk slots
  us*    reln_hi = (us*)(ws + 40*MB);
  us*    posk_hi = (us*)(ws + 40*MB + 256*1024);
  us*    posq_hi = (us*)(ws + 40*MB + 512*1024);
  signed char* idxt = (signed char*)(ws + 40*MB + 768*1024);
  us*    qbuf_hi = (us*)(ws + 41*MB);    // [41,49)
  us*    kbuf_hi = (us*)(ws + 49*MB);    // [49,57)
  float* vtb_p0  = (float*)(ws + 57*MB); // [57,73) fp32, dead after k_cp z=2
  us*    ctx_hi  = (us*)(ws + 57*MB);    //         k_attn writes (after k_cp)
  us*    ctx_lo  = (us*)(ws + 65*MB);    // [65,73)
  float* vtb_p1  = (float*)(ws + 73*MB); // [73,89) fp32, dead after k_cp z=2

  k_prep<<<14409, 256, 0, stream>>>(query, kvst, Wq, Wk, Wv, Wpk, Wpq, Wo,
                                    rel, lng, lnb,
                                    Xq_hi, Xkv_hi, Wt, reln_hi, idxt);

  k_qkvp<<<1056, 256, 0, stream>>>(Xq_hi, Xkv_hi, Wt, bq, bk,
                                   reln_hi, bpk, bpq,
                                   qbuf_hi, kbuf_hi, vtb_p0, vtb_p1, posk_hi, posq_hi);

  k_cp<<<dim3(16,64,3), 256, 0, stream>>>(qbuf_hi, kbuf_hi, posk_hi, posq_hi,
                                          vtb_p0, vtb_p1, bv, c2p, p2c, vtb);

  k_attn<<<dim3(8,64), 512, 0, stream>>>(qbuf_hi, kbuf_hi, vtb,
                                         c2p, p2c, idxt, mask, ctx_hi, ctx_lo);

  k_gemmo<<<512, 256, 0, stream>>>(ctx_hi, ctx_lo, Wt + 5*2097152, Wt + 5*2097152 + 1048576, bo, (float*)d_out);
}

// Round 12
// 203.607 us; speedup vs baseline: 1.0460x; 1.0460x over previous
//
#include <hip/hip_runtime.h>
#include <cstdint>
#include <math.h>

typedef unsigned short us;
typedef __attribute__((ext_vector_type(8))) __bf16 bf16x8;
typedef __attribute__((ext_vector_type(8))) unsigned short ushort8;
typedef __attribute__((ext_vector_type(4))) float f32x4;

__device__ __forceinline__ us f2bf(float x){
  union { float f; unsigned int u; } v; v.f = x;
  unsigned int r = v.u + 0x7FFFu + ((v.u >> 16) & 1u);   // RNE
  return (us)(r >> 16);
}
__device__ __forceinline__ float b2f(us u){
  union { unsigned int u; float f; } v; v.u = ((unsigned int)u) << 16; return v.f;
}
__device__ __forceinline__ void split2(float x, us& hi, us& lo){
  hi = f2bf(x); lo = f2bf(x - b2f(hi));
}
__device__ __forceinline__ f32x4 fzero(){ f32x4 v; v.x=0.f; v.y=0.f; v.z=0.f; v.w=0.f; return v; }
__device__ __forceinline__ f32x4 mfma16(bf16x8 a, bf16x8 b, f32x4 c){
  return __builtin_amdgcn_mfma_f32_16x16x32_bf16(a, b, c, 0, 0, 0);
}
__device__ __forceinline__ void gload_lds16(const void* g, void* l){
  __builtin_amdgcn_global_load_lds(
      (const __attribute__((address_space(1))) unsigned int*)(uintptr_t)g,
      (__attribute__((address_space(3))) unsigned int*)(uintptr_t)l,
      16, 0, 0);
}

// exp2-folded scales
#define QS2 (0.07216878364870322f * 1.4426950408889634f)   // 1/sqrt(192) * log2(e)
#define BS  (0.08838834764831845f * 1.4426950408889634f)   // 1/sqrt(128) * log2(e)

// ---------------- 1: fused prep: convx | convw | lnrel | bucket ----------------
__global__ __launch_bounds__(256) void k_prep(const float* __restrict__ xq,
                                              const float* __restrict__ xkv,
                                              const float* __restrict__ w0, const float* __restrict__ w1,
                                              const float* __restrict__ w2, const float* __restrict__ w3,
                                              const float* __restrict__ w4, const float* __restrict__ w5,
                                              const float* __restrict__ rel,
                                              const float* __restrict__ g, const float* __restrict__ bLN,
                                              us* __restrict__ qhi, us* __restrict__ kvhi,
                                              us* __restrict__ wt, us* __restrict__ reln_hi,
                                              signed char* __restrict__ idxt)
{
  __shared__ float tile[32][33];
  __shared__ float sm[8];
  const int bid = blockIdx.x, t = threadIdx.x;

  if (bid < 8192){                      // ---- convx (hi only)
    int i = bid * 256 + t;
    const float* src; us* dh;
    if (i < 1048576){ src = xq  + (size_t)i*4;           dh = qhi  + (size_t)i*4; }
    else            { src = xkv + (size_t)(i-1048576)*4; dh = kvhi + (size_t)(i-1048576)*4; }
    f32x4 v = *(const f32x4*)src;
    dh[0]=f2bf(v.x); dh[1]=f2bf(v.y); dh[2]=f2bf(v.z); dh[3]=f2bf(v.w);
    return;
  }
  if (bid < 14336){                     // ---- convw: transpose + hi/lo split
    int rem = bid - 8192;
    int z = rem >> 10, r2 = rem & 1023;
    const float* W = (z==0)?w0:(z==1)?w1:(z==2)?w2:(z==3)?w3:(z==4)?w4:w5;
    us* dst_hi = wt + (size_t)z * 2097152;
    us* dst_lo = dst_hi + 1048576;
    bool wlo = (z == 2) || (z == 5);
    int n0 = (r2 & 31) * 32, k0 = (r2 >> 5) * 32;
    int c = t & 31, r = t >> 5;
#pragma unroll
    for (int i = 0; i < 4; i++)
      tile[r + i*8][c] = W[(size_t)(k0 + r + i*8)*1024 + n0 + c];
    __syncthreads();
#pragma unroll
    for (int i = 0; i < 4; i++){
      int nn = r + i*8;
      us h,l; split2(tile[c][nn], h, l);
      dst_hi[(size_t)(n0 + nn)*1024 + k0 + c] = h;
      if (wlo) dst_lo[(size_t)(n0 + nn)*1024 + k0 + c] = l;
    }
    return;
  }
  if (bid < 14400){                     // ---- lnrel
    int row = bid - 14336;
    const float* x = rel + (size_t)row * 1024;
    float v[4]; float s = 0.f, ss = 0.f;
#pragma unroll
    for (int i=0;i<4;i++){ v[i] = x[t + 256*i]; s += v[i]; ss += v[i]*v[i]; }
    for (int o=32;o;o>>=1){ s += __shfl_xor(s,o); ss += __shfl_xor(ss,o); }
    int w = t >> 6;
    if ((t & 63) == 0){ sm[w] = s; sm[4+w] = ss; }
    __syncthreads();
    s  = sm[0]+sm[1]+sm[2]+sm[3];
    ss = sm[4]+sm[5]+sm[6]+sm[7];
    float mu  = s  * (1.0f/1024.0f);
    float var = ss * (1.0f/1024.0f) - mu*mu;
    float rs  = rsqrtf(var + 1e-5f);
#pragma unroll
    for (int i=0;i<4;i++){
      int cc = t + 256*i;
      reln_hi[(size_t)row*1024 + cc] = f2bf((v[i]-mu)*rs*g[cc] + bLN[cc]);
    }
    return;
  }
  {                                     // ---- bucket table
    int i = (bid - 14400) * 256 + t;
    if (i >= 2052) return;
    int d = i - 1023;
    int ad = d < 0 ? -d : d;
    int abspos = (d < 16 && d > -16) ? 15 : ad;
    int bucket;
    if (abspos <= 16) bucket = d;
    else {
      float num = (float)log((double)abspos * 0.0625);
      float den = (float)log(7.9375);
      float lp = ceilf(num / den * 15.0f) + 16.0f;
      bucket = (int)lp * (d > 0 ? 1 : -1);
    }
    int s = bucket + 32;
    s = s < 0 ? 0 : (s > 63 ? 63 : s);
    idxt[i] = (signed char)s;
  }
}

// ---------------- 2: merged QKV GEMM + pos projections ----------------
// bids [0,256): Q BM=128/BN=128 NKT=32 -> qbuf bf16
// bids [256,512): K same -> kbuf bf16
// bids [512,1024): V BM=64/BN=128 NKT=64 (hi+lo accumulated) -> vtb bf16  (2 blocks/CU tail)
// bids [1024,1056): pos_k / pos_q projections
__global__ __launch_bounds__(256) void k_qkvp(const us* __restrict__ Xq, const us* __restrict__ Xkv,
                                              const us* __restrict__ wt,
                                              const float* __restrict__ bq, const float* __restrict__ bk,
                                              const float* __restrict__ bv,
                                              const us* __restrict__ reln_hi,
                                              const float* __restrict__ bpk, const float* __restrict__ bpq,
                                              us* __restrict__ qbuf, us* __restrict__ kbuf,
                                              us* __restrict__ vtb,
                                              us* __restrict__ posk_hi, us* __restrict__ posq_hi)
{
  __shared__ __align__(16) us a_lds[2][4096];   // Q/K: 128x32 ; V: 64x32 (first half)
  __shared__ __align__(16) us b_lds[2][4096];   // 128 x 32
  const int bid = blockIdx.x;
  const int t = threadIdx.x, w = t >> 6, lane = t & 63, lg = lane >> 4, li = lane & 15;

  if (bid >= 1024){                     // ---- pos projections (32 blocks)
    int wg2 = bid - 1024;
    int ntile = wg2 & 15, z = wg2 >> 4;
    const us* W_hi = wt + (size_t)(3 + z) * 2097152;
    const float* bias = z ? bpq : bpk;
    us* out_hi = z ? posq_hi : posk_hi;
    f32x4 acc[4];
#pragma unroll
    for (int i=0;i<4;i++) acc[i] = fzero();
    int srow = w*16 + li;
    for (int kt = 0; kt < 32; kt++){
      int k0 = kt*32 + lg*8;
      bf16x8 a = *(const bf16x8*)(reln_hi + (size_t)srow*1024 + k0);
#pragma unroll
      for (int nf=0; nf<4; nf++){
        int n = ntile*64 + nf*16 + li;
        bf16x8 b = *(const bf16x8*)(W_hi + (size_t)n*1024 + k0);
        acc[nf] = mfma16(a, b, acc[nf]);
      }
    }
#pragma unroll
    for (int nf=0;nf<4;nf++){
      int n = ntile*64 + nf*16 + li;
      float bn = bias[n];
      int h = n >> 6, hd = n & 63;
#pragma unroll
      for (int j=0;j<4;j++){
        int s = w*16 + lg*4 + j;
        out_hi[(size_t)h*4096 + s*64 + hd] = f2bf(acc[nf][j] + bn);
      }
    }
    return;
  }

  if (bid < 512){                       // ---- Q / K classes (r9-proven geometry)
    int cls = bid >> 8;                 // 0:Q 1:K
    int u = bid & 255;
    int tile = (u & 7) * 32 + (u >> 3); // XCD-contiguous chunk within class
    int mt = tile >> 3, nt = tile & 7;
    int m0 = mt * 128, n0 = nt * 128;
    const us* A  = cls ? Xkv : Xq;
    const us* Bp = wt + (size_t)cls * 2097152;
    const float* bias = cls ? bk : bq;
    us* out = cls ? kbuf : qbuf;
    int wm = w >> 1, wn = w & 1;
    f32x4 acc[4][4];
#pragma unroll
    for (int i=0;i<4;i++)
#pragma unroll
      for (int j=0;j<4;j++) acc[i][j] = fzero();

    auto stage = [&](int buf, int kt){
      int k0 = kt * 32;
#pragma unroll
      for (int c = 0; c < 2; c++){
        int slot = c*256 + t;
        int g = slot ^ ((slot >> 3) & 7);
        int r = g >> 2, kc = g & 3;
        gload_lds16(A  + (size_t)(m0 + r)*1024 + k0 + kc*8, (char*)&a_lds[buf][0] + slot*16);
        gload_lds16(Bp + (size_t)(n0 + r)*1024 + k0 + kc*8, (char*)&b_lds[buf][0] + slot*16);
      }
    };

    stage(0, 0);
    __syncthreads();
    int buf = 0;
    for (int kt = 0; kt < 32; kt++){
      if (kt + 1 < 32) stage(buf ^ 1, kt + 1);
      bf16x8 af[4], bfv[4];
#pragma unroll
      for (int mi=0;mi<4;mi++){
        int r = wm*64 + mi*16 + li;
        int s = (r*4 + lg); s ^= ((s >> 3) & 7);
        af[mi] = *(const bf16x8*)((char*)&a_lds[buf][0] + s*16);
      }
#pragma unroll
      for (int ni=0;ni<4;ni++){
        int r = wn*64 + ni*16 + li;
        int s = (r*4 + lg); s ^= ((s >> 3) & 7);
        bfv[ni] = *(const bf16x8*)((char*)&b_lds[buf][0] + s*16);
      }
#pragma unroll
      for (int mi=0;mi<4;mi++)
#pragma unroll
        for (int ni=0;ni<4;ni++)
          acc[mi][ni] = mfma16(af[mi], bfv[ni], acc[mi][ni]);
      __syncthreads();
      buf ^= 1;
    }

#pragma unroll
    for (int ni=0;ni<4;ni++){
      int n = n0 + wn*64 + ni*16 + li;
      float bn = bias[n];
      int hh = n >> 6, hd = n & 63;
#pragma unroll
      for (int mi=0;mi<4;mi++){
        int mb = m0 + wm*64 + mi*16 + lg*4;
#pragma unroll
        for (int j=0;j<4;j++){
          int m = mb + j;
          int bb = m >> 10, tp = m & 1023;
          out[(((size_t)(bb*16 + hh))*1024 + tp)*64 + hd] = f2bf(acc[mi][ni][j] + bn);
        }
      }
    }
    return;
  }

  // ---- V class: BM=64, BN=128, NKT=64 (seg 0: Wv_hi, seg 1: Wv_lo), 512 blocks
  {
    int u = bid - 512;
    int tile = (u & 7) * 64 + (u >> 3); // XCD-contiguous chunk
    int mt = tile >> 3, nt = tile & 7;  // mt: 0..63, nt: 0..7
    int m0 = mt * 64, n0 = nt * 128;
    const us* Bh = wt + (size_t)2 * 2097152;
    const us* Bl = Bh + 1048576;
    int wm = w >> 1, wn = w & 1;
    f32x4 acc[2][4];
#pragma unroll
    for (int i=0;i<2;i++)
#pragma unroll
      for (int j=0;j<4;j++) acc[i][j] = fzero();

    auto stage = [&](int buf, int kt){
      int seg = kt >> 5, k0 = (kt & 31) * 32;
      const us* Bp = seg ? Bl : Bh;
      {
        int slot = t;                    // 256 chunks: A 64x32
        int g = slot ^ ((slot >> 3) & 7);
        int r = g >> 2, kc = g & 3;
        gload_lds16(Xkv + (size_t)(m0 + r)*1024 + k0 + kc*8, (char*)&a_lds[buf][0] + slot*16);
      }
#pragma unroll
      for (int c = 0; c < 2; c++){
        int slot = c*256 + t;            // 512 chunks: B 128x32
        int g = slot ^ ((slot >> 3) & 7);
        int r = g >> 2, kc = g & 3;
        gload_lds16(Bp + (size_t)(n0 + r)*1024 + k0 + kc*8, (char*)&b_lds[buf][0] + slot*16);
      }
    };

    stage(0, 0);
    __syncthreads();
    int buf = 0;
    for (int kt = 0; kt < 64; kt++){
      if (kt + 1 < 64) stage(buf ^ 1, kt + 1);
      bf16x8 af[2], bfv[4];
#pragma unroll
      for (int mi=0;mi<2;mi++){
        int r = wm*32 + mi*16 + li;
        int s = (r*4 + lg); s ^= ((s >> 3) & 7);
        af[mi] = *(const bf16x8*)((char*)&a_lds[buf][0] + s*16);
      }
#pragma unroll
      for (int ni=0;ni<4;ni++){
        int r = wn*64 + ni*16 + li;
        int s = (r*4 + lg); s ^= ((s >> 3) & 7);
        bfv[ni] = *(const bf16x8*)((char*)&b_lds[buf][0] + s*16);
      }
#pragma unroll
      for (int mi=0;mi<2;mi++)
#pragma unroll
        for (int ni=0;ni<4;ni++)
          acc[mi][ni] = mfma16(af[mi], bfv[ni], acc[mi][ni]);
      __syncthreads();
      buf ^= 1;
    }

#pragma unroll
    for (int ni=0;ni<4;ni++){
      int n = n0 + wn*64 + ni*16 + li;
      float bn = bv[n];
      int hh = n >> 6, hd = n & 63;
#pragma unroll
      for (int mi=0;mi<2;mi++){
        int mb = m0 + wm*32 + mi*16 + lg*4;
#pragma unroll
        for (int j=0;j<4;j++){
          int m = mb + j;
          int bb = m >> 10, tp = m & 1023;
          vtb[(((size_t)(bb*16 + hh))*64 + hd)*1024 + tp] = f2bf(acc[mi][ni][j] + bn);
        }
      }
    }
  }
}

// ---------------- 3: O GEMM: 3 products, BM=128, BN=64, fp32 out ----------------
__global__ __launch_bounds__(256, 2) void k_gemmo(const us* __restrict__ A_hi, const us* __restrict__ A_lo,
                                                  const us* __restrict__ B_hi, const us* __restrict__ B_lo,
                                                  const float* __restrict__ bias,
                                                  float* __restrict__ out_f)
{
  __shared__ __align__(16) us a_lds[2][4096];
  __shared__ __align__(16) us b_lds[2][2048];
  int bid = blockIdx.x;
  int wg = (bid & 7) * 64 + (bid >> 3);        // 512 % 8 == 0
  int mt = wg >> 4, nt = wg & 15;
  int m0 = mt * 128, n0 = nt * 64;
  int t = threadIdx.x, w = t >> 6, lane = t & 63, lg = lane >> 4, li = lane & 15;
  int wm = w >> 1, wn = w & 1;
  f32x4 acc[4][2];
#pragma unroll
  for (int i=0;i<4;i++){ acc[i][0]=fzero(); acc[i][1]=fzero(); }

  auto stage = [&](int buf, int kt){
    int seg = kt >> 5, k0 = (kt & 31) * 32;
    const us* Ap = (seg == 2) ? A_lo : A_hi;
    const us* Bp = (seg == 1) ? B_lo : B_hi;
#pragma unroll
    for (int c = 0; c < 2; c++){
      int slot = c*256 + t;
      int g = slot ^ ((slot >> 3) & 7);
      int r = g >> 2, kc = g & 3;
      gload_lds16(Ap + (size_t)(m0 + r)*1024 + k0 + kc*8, (char*)&a_lds[buf][0] + slot*16);
    }
    {
      int slot = t;
      int g = slot ^ ((slot >> 3) & 7);
      int r = g >> 2, kc = g & 3;
      gload_lds16(Bp + (size_t)(n0 + r)*1024 + k0 + kc*8, (char*)&b_lds[buf][0] + slot*16);
    }
  };

  stage(0, 0);
  __syncthreads();
  int buf = 0;
  for (int kt = 0; kt < 96; kt++){
    if (kt + 1 < 96) stage(buf ^ 1, kt + 1);
    bf16x8 af[4], bfv[2];
#pragma unroll
    for (int mi=0;mi<4;mi++){
      int r = wm*64 + mi*16 + li;
      int s = (r*4 + lg); s ^= ((s >> 3) & 7);
      af[mi] = *(const bf16x8*)((char*)&a_lds[buf][0] + s*16);
    }
#pragma unroll
    for (int ni=0;ni<2;ni++){
      int r = wn*32 + ni*16 + li;
      int s = (r*4 + lg); s ^= ((s >> 3) & 7);
      bfv[ni] = *(const bf16x8*)((char*)&b_lds[buf][0] + s*16);
    }
#pragma unroll
    for (int mi=0;mi<4;mi++)
#pragma unroll
      for (int ni=0;ni<2;ni++)
        acc[mi][ni] = mfma16(af[mi], bfv[ni], acc[mi][ni]);
    __syncthreads();
    buf ^= 1;
  }

#pragma unroll
  for (int ni=0;ni<2;ni++){
    int n = n0 + wn*32 + ni*16 + li;
    float bn = bias[n];
#pragma unroll
    for (int mi=0;mi<4;mi++){
      int mb = m0 + wm*64 + mi*16 + lg*4;
#pragma unroll
      for (int j=0;j<4;j++)
        out_f[(size_t)(mb + j)*1024 + n] = acc[mi][ni][j] + bn;
    }
  }
}

// ---------------- 4: c2p/p2c (single product, pre-scaled by BS for exp2) ----------------
__global__ __launch_bounds__(256) void k_cp(const us* __restrict__ q_hi,
                                            const us* __restrict__ k_hi,
                                            const us* __restrict__ pk_hi,
                                            const us* __restrict__ pq_hi,
                                            us* __restrict__ c2p, us* __restrict__ p2c)
{
  int qt = blockIdx.x, bh = blockIdx.y, z = blockIdx.z;
  const us* X_hi = z ? k_hi : q_hi;
  const us* P_hi = z ? pq_hi : pk_hi;
  us* out = z ? p2c : c2p;
  int h = bh & 15;
  int t = threadIdx.x, w = t >> 6, lane = t & 63, lg = lane >> 4, li = lane & 15;
  f32x4 acc[4];
#pragma unroll
  for (int i=0;i<4;i++) acc[i] = fzero();
  size_t row = (size_t)bh*1024 + qt*64 + w*16 + li;
#pragma unroll
  for (int kk=0;kk<2;kk++){
    int k = kk*32 + lg*8;
    bf16x8 ah = *(const bf16x8*)(X_hi + row*64 + k);
#pragma unroll
    for (int nf=0;nf<4;nf++){
      int s = nf*16 + li;
      bf16x8 bh_ = *(const bf16x8*)(P_hi + (size_t)h*4096 + s*64 + k);
      acc[nf] = mfma16(ah, bh_, acc[nf]);
    }
  }
  size_t obase = ((size_t)bh*1024 + qt*64 + w*16 + lg*4) * 64;
#pragma unroll
  for (int nf=0;nf<4;nf++)
#pragma unroll
    for (int j=0;j<4;j++)
      out[obase + (size_t)j*64 + nf*16 + li] = f2bf(acc[nf][j] * BS);
}

// ---------------- 5: fused attention: 8 waves, QBLK=128, far fast path ----------------
__global__ __launch_bounds__(512) void k_attn(const us* __restrict__ qhi,
                                              const us* __restrict__ khi,
                                              const us* __restrict__ vhi,
                                              const us* __restrict__ c2p, const us* __restrict__ p2c,
                                              const signed char* __restrict__ idxt,
                                              const unsigned char* __restrict__ mask,
                                              us* __restrict__ ctx_hi, us* __restrict__ ctx_lo)
{
  __shared__ __align__(16) us khi_lds[4096], vhi_lds[4096];
  __shared__ __align__(16) us c2p_lds[128*72], p2c_lds[64*72];   // padded rows: 144B stride
  __shared__ __align__(16) us p_lds[8][1024];
  __shared__ signed char idx_lds[2048];

  const int qt = blockIdx.x, bh = blockIdx.y;   // qt: 0..7
  const int b = bh >> 4, h = bh & 15;
  const int t = threadIdx.x, w = t >> 6, lane = t & 63, lg = lane >> 4, li = lane & 15;
  const int q0 = qt * 128;

  for (int i = t; i < 2047; i += 512) idx_lds[i] = idxt[i];
  {
    const us* src = c2p + ((size_t)bh*1024 + q0) * 64;
#pragma unroll
    for (int c = 0; c < 2; c++){
      int f = c*512 + t, r = f >> 3, kc = f & 7;
      *(ushort8*)&c2p_lds[r*72 + kc*8] = *(const ushort8*)(src + r*64 + kc*8);
    }
  }
  bf16x8 qfh[2];
  {
    const us* qph = qhi + ((size_t)bh*1024 + q0 + w*16 + li)*64 + lg*8;
    qfh[0] = *(const bf16x8*)(qph); qfh[1] = *(const bf16x8*)(qph + 32);
  }
  __syncthreads();
  // far-path per-row bias (scaled) for idx=0 / idx=63
  float cq0[4], cq63[4];
#pragma unroll
  for (int j=0;j<4;j++){
    int qloc = w*16 + lg*4 + j;
    cq0[j]  = b2f(c2p_lds[qloc*72 + 0]);
    cq63[j] = b2f(c2p_lds[qloc*72 + 63]);
  }

  float lrow[4];
  f32x4 accO[4];
#pragma unroll
  for (int j=0;j<4;j++){ lrow[j] = 0.f; accO[j] = fzero(); }
  const unsigned char* mptr = mask + b*1024;

  for (int kt = 0; kt < 16; kt++){
    const int k0 = kt * 64;
    const bool far = (q0 - k0 >= 192) || (k0 - q0 >= 256);
    __syncthreads();
    {  // stage K,V: one 16B chunk each per thread
      int r = t >> 3, kc = t & 7;
      *(ushort8*)&khi_lds[r*64 + ((kc ^ (r & 7))*8)] =
          *(const ushort8*)(khi + ((size_t)bh*1024 + k0 + r)*64 + kc*8);
      *(ushort8*)&vhi_lds[r*64 + ((kc ^ (r & 7))*8)] =
          *(const ushort8*)(vhi + ((size_t)bh*64 + r)*1024 + k0 + kc*8);
      if (!far)
        *(ushort8*)&p2c_lds[r*72 + kc*8] =
            *(const ushort8*)(p2c + ((size_t)bh*1024 + k0 + r)*64 + kc*8);
    }
    __syncthreads();

    // QK^T single product
    f32x4 sfr[4];
#pragma unroll
    for (int nf=0;nf<4;nf++) sfr[nf] = fzero();
#pragma unroll
    for (int kk=0; kk<2; kk++){
      int kc = kk*4 + lg;
#pragma unroll
      for (int nf=0; nf<4; nf++){
        int r = nf*16 + li;
        bf16x8 bh_ = *(const bf16x8*)&khi_lds[r*64 + ((kc ^ (r & 7))*8)];
        sfr[nf] = mfma16(qfh[kk], bh_, sfr[nf]);
      }
    }
    us* pl = &p_lds[w][0];
    if (far){
      const int cidx = (q0 > k0) ? 63 : 0;
      float cq[4];
#pragma unroll
      for (int j=0;j<4;j++) cq[j] = (q0 > k0) ? cq63[j] : cq0[j];
#pragma unroll
      for (int nf=0; nf<4; nf++){
        int kloc = nf*16 + li;
        bool mk = mptr[k0 + kloc] != 0;
        float ck = b2f(p2c[((size_t)bh*1024 + k0 + kloc)*64 + cidx]);
        int col = kloc;
#pragma unroll
        for (int j=0;j<4;j++){
          float p = mk ? 0.f : exp2f(fmaf(sfr[nf][j], QS2, cq[j] + ck));
          lrow[j] += p;
          int row = lg*4 + j;
          pl[row*64 + ((col & 7) | ((((col >> 3) ^ (row & 7))) << 3))] = f2bf(p);
        }
      }
    } else {
#pragma unroll
      for (int nf=0; nf<4; nf++){
        int kloc = nf*16 + li;
        bool mk = mptr[k0 + kloc] != 0;
        int col = kloc;
#pragma unroll
        for (int j=0;j<4;j++){
          int qloc = w*16 + lg*4 + j;
          int d = (q0 + qloc) - (k0 + kloc);
          int idx = (int)idx_lds[d + 1023];
          float s2 = fmaf(sfr[nf][j], QS2,
                          b2f(c2p_lds[qloc*72 + idx]) + b2f(p2c_lds[kloc*72 + idx]));
          float p = mk ? 0.f : exp2f(s2);
          lrow[j] += p;
          int row = lg*4 + j;
          pl[row*64 + ((col & 7) | ((((col >> 3) ^ (row & 7))) << 3))] = f2bf(p);
        }
      }
    }
    // PV single product (p_lds wave-private; same-wave DS ordering)
#pragma unroll
    for (int kk=0;kk<2;kk++){
      int kc = kk*4 + lg;
      bf16x8 af = *(const bf16x8*)((char*)pl + li*128 + ((kc ^ (li & 7)) * 16));
#pragma unroll
      for (int nf=0;nf<4;nf++){
        int r = nf*16 + li;
        bf16x8 bh_ = *(const bf16x8*)&vhi_lds[r*64 + ((kc ^ (r & 7))*8)];
        accO[nf] = mfma16(af, bh_, accO[nf]);
      }
    }
  }

  for (int o=1;o<16;o<<=1)
#pragma unroll
    for (int j=0;j<4;j++)
      lrow[j] += __shfl_xor(lrow[j], o);
#pragma unroll
  for (int nf=0;nf<4;nf++)
#pragma unroll
    for (int j=0;j<4;j++){
      int qloc = w*16 + lg*4 + j;
      float o = accO[nf][j] / lrow[j];
      size_t idx = ((size_t)(b*1024 + q0 + qloc))*1024 + h*64 + nf*16 + li;
      us hh,ll; split2(o,hh,ll);
      ctx_hi[idx] = hh; ctx_lo[idx] = ll;
    }
}

// ---------------- launch ----------------
extern "C" void kernel_launch(void* const* d_in, const int* in_sizes, int n_in,
                              void* d_out, int out_size, void* d_ws, size_t ws_size,
                              hipStream_t stream)
{
  (void)in_sizes; (void)n_in; (void)out_size; (void)ws_size;
  const float* query = (const float*)d_in[0];
  const float* kvst  = (const float*)d_in[1];
  const unsigned char* mask = (const unsigned char*)d_in[2];
  const float* Wq = (const float*)d_in[3];  const float* bq = (const float*)d_in[4];
  const float* Wk = (const float*)d_in[5];  const float* bk = (const float*)d_in[6];
  const float* Wv = (const float*)d_in[7];  const float* bv = (const float*)d_in[8];
  const float* Wo = (const float*)d_in[9];  const float* bo = (const float*)d_in[10];
  const float* rel = (const float*)d_in[11];
  const float* lng = (const float*)d_in[12]; const float* lnb = (const float*)d_in[13];
  const float* Wpk = (const float*)d_in[14]; const float* bpk = (const float*)d_in[15];
  const float* Wpq = (const float*)d_in[16]; const float* bpq = (const float*)d_in[17];

  char* ws = (char*)d_ws;
  const size_t MB = 1024*1024;
  // r9-proven layout (alias-safe by execution order):
  us* Xq_hi  = (us*)(ws + 0);        // [0,8)   dead after k_qkvp
  us* p2c    = (us*)(ws + 8*MB);     // [8,16)  k_cp z=1 writes (after k_qkvp)
  us* Xkv_hi = (us*)(ws + 16*MB);    // [16,24) dead after k_qkvp
  us* c2p    = (us*)(ws + 16*MB);    //         k_cp z=0 writes
  us* vtb    = (us*)(ws + 24*MB);    // [24,32) k_qkvp V writes; k_attn reads
  us* Wt     = (us*)(ws + 32*MB);    // [32,56) 6 slots x 4MB
  us* ctx_hi = (us*)(ws + 32*MB);    //         k_attn writes over Wq/Wk slots (dead)
  us* ctx_lo = (us*)(ws + 40*MB);    //         over Wv/Wpk slots (dead after k_qkvp)
  us* reln_hi = (us*)(ws + 56*MB);
  us* posk_hi = (us*)(ws + 56*MB + 256*1024);
  us* posq_hi = (us*)(ws + 56*MB + 512*1024);
  signed char* idxt = (signed char*)(ws + 56*MB + 768*1024);
  us* qbuf_hi = (us*)(ws + 57*MB);   // [57,65)
  us* kbuf_hi = (us*)(ws + 65*MB);   // [65,73)

  k_prep<<<14409, 256, 0, stream>>>(query, kvst, Wq, Wk, Wv, Wpk, Wpq, Wo,
                                    rel, lng, lnb,
                                    Xq_hi, Xkv_hi, Wt, reln_hi, idxt);

  k_qkvp<<<1056, 256, 0, stream>>>(Xq_hi, Xkv_hi, Wt, bq, bk, bv,
                                   reln_hi, bpk, bpq,
                                   qbuf_hi, kbuf_hi, vtb, posk_hi, posq_hi);

  k_cp<<<dim3(16,64,2), 256, 0, stream>>>(qbuf_hi, kbuf_hi, posk_hi, posq_hi, c2p, p2c);

  k_attn<<<dim3(8,64), 512, 0, stream>>>(qbuf_hi, kbuf_hi, vtb,
                                         c2p, p2c, idxt, mask, ctx_hi, ctx_lo);

  k_gemmo<<<512, 256, 0, stream>>>(ctx_hi, ctx_lo, Wt + 5*2097152, Wt + 5*2097152 + 1048576, bo, (float*)d_out);
}

// Round 13
// 198.068 us; speedup vs baseline: 1.0752x; 1.0280x over previous
//
#include <hip/hip_runtime.h>
#include <cstdint>
#include <math.h>

typedef unsigned short us;
typedef __attribute__((ext_vector_type(8))) __bf16 bf16x8;
typedef __attribute__((ext_vector_type(8))) unsigned short ushort8;
typedef __attribute__((ext_vector_type(4))) float f32x4;

__device__ __forceinline__ us f2bf(float x){
  union { float f; unsigned int u; } v; v.f = x;
  unsigned int r = v.u + 0x7FFFu + ((v.u >> 16) & 1u);   // RNE
  return (us)(r >> 16);
}
__device__ __forceinline__ float b2f(us u){
  union { unsigned int u; float f; } v; v.u = ((unsigned int)u) << 16; return v.f;
}
__device__ __forceinline__ void split2(float x, us& hi, us& lo){
  hi = f2bf(x); lo = f2bf(x - b2f(hi));
}
__device__ __forceinline__ f32x4 fzero(){ f32x4 v; v.x=0.f; v.y=0.f; v.z=0.f; v.w=0.f; return v; }
__device__ __forceinline__ f32x4 mfma16(bf16x8 a, bf16x8 b, f32x4 c){
  return __builtin_amdgcn_mfma_f32_16x16x32_bf16(a, b, c, 0, 0, 0);
}
__device__ __forceinline__ void gload_lds16(const void* g, void* l){
  __builtin_amdgcn_global_load_lds(
      (const __attribute__((address_space(1))) unsigned int*)(uintptr_t)g,
      (__attribute__((address_space(3))) unsigned int*)(uintptr_t)l,
      16, 0, 0);
}

// exp2-folded scales
#define QS2 (0.07216878364870322f * 1.4426950408889634f)   // 1/sqrt(192) * log2(e)
#define BS  (0.08838834764831845f * 1.4426950408889634f)   // 1/sqrt(128) * log2(e)

// ---------------- 1: fused prep: convx | convw | lnrel | bucket ----------------
__global__ __launch_bounds__(256) void k_prep(const float* __restrict__ xq,
                                              const float* __restrict__ xkv,
                                              const float* __restrict__ w0, const float* __restrict__ w1,
                                              const float* __restrict__ w2, const float* __restrict__ w3,
                                              const float* __restrict__ w4, const float* __restrict__ w5,
                                              const float* __restrict__ rel,
                                              const float* __restrict__ g, const float* __restrict__ bLN,
                                              us* __restrict__ qhi, us* __restrict__ kvhi,
                                              us* __restrict__ wt, us* __restrict__ reln_hi,
                                              signed char* __restrict__ idxt)
{
  __shared__ float tile[32][33];
  __shared__ float sm[8];
  const int bid = blockIdx.x, t = threadIdx.x;

  if (bid < 8192){                      // ---- convx (hi only)
    int i = bid * 256 + t;
    const float* src; us* dh;
    if (i < 1048576){ src = xq  + (size_t)i*4;           dh = qhi  + (size_t)i*4; }
    else            { src = xkv + (size_t)(i-1048576)*4; dh = kvhi + (size_t)(i-1048576)*4; }
    f32x4 v = *(const f32x4*)src;
    dh[0]=f2bf(v.x); dh[1]=f2bf(v.y); dh[2]=f2bf(v.z); dh[3]=f2bf(v.w);
    return;
  }
  if (bid < 14336){                     // ---- convw: transpose + hi/lo split
    int rem = bid - 8192;
    int z = rem >> 10, r2 = rem & 1023;
    const float* W = (z==0)?w0:(z==1)?w1:(z==2)?w2:(z==3)?w3:(z==4)?w4:w5;
    us* dst_hi = wt + (size_t)z * 2097152;
    us* dst_lo = dst_hi + 1048576;
    bool wlo = (z == 2) || (z == 5);
    int n0 = (r2 & 31) * 32, k0 = (r2 >> 5) * 32;
    int c = t & 31, r = t >> 5;
#pragma unroll
    for (int i = 0; i < 4; i++)
      tile[r + i*8][c] = W[(size_t)(k0 + r + i*8)*1024 + n0 + c];
    __syncthreads();
#pragma unroll
    for (int i = 0; i < 4; i++){
      int nn = r + i*8;
      us h,l; split2(tile[c][nn], h, l);
      dst_hi[(size_t)(n0 + nn)*1024 + k0 + c] = h;
      if (wlo) dst_lo[(size_t)(n0 + nn)*1024 + k0 + c] = l;
    }
    return;
  }
  if (bid < 14400){                     // ---- lnrel
    int row = bid - 14336;
    const float* x = rel + (size_t)row * 1024;
    float v[4]; float s = 0.f, ss = 0.f;
#pragma unroll
    for (int i=0;i<4;i++){ v[i] = x[t + 256*i]; s += v[i]; ss += v[i]*v[i]; }
    for (int o=32;o;o>>=1){ s += __shfl_xor(s,o); ss += __shfl_xor(ss,o); }
    int w = t >> 6;
    if ((t & 63) == 0){ sm[w] = s; sm[4+w] = ss; }
    __syncthreads();
    s  = sm[0]+sm[1]+sm[2]+sm[3];
    ss = sm[4]+sm[5]+sm[6]+sm[7];
    float mu  = s  * (1.0f/1024.0f);
    float var = ss * (1.0f/1024.0f) - mu*mu;
    float rs  = rsqrtf(var + 1e-5f);
#pragma unroll
    for (int i=0;i<4;i++){
      int cc = t + 256*i;
      reln_hi[(size_t)row*1024 + cc] = f2bf((v[i]-mu)*rs*g[cc] + bLN[cc]);
    }
    return;
  }
  {                                     // ---- bucket table
    int i = (bid - 14400) * 256 + t;
    if (i >= 2052) return;
    int d = i - 1023;
    int ad = d < 0 ? -d : d;
    int abspos = (d < 16 && d > -16) ? 15 : ad;
    int bucket;
    if (abspos <= 16) bucket = d;
    else {
      float num = (float)log((double)abspos * 0.0625);
      float den = (float)log(7.9375);
      float lp = ceilf(num / den * 15.0f) + 16.0f;
      bucket = (int)lp * (d > 0 ? 1 : -1);
    }
    int s = bucket + 32;
    s = s < 0 ? 0 : (s > 63 ? 63 : s);
    idxt[i] = (signed char)s;
  }
}

// ---------------- 2: merged QKV GEMM + pos projections ----------------
// bids [0,256): Q BM=128/BN=128 NKT=32 -> qbuf bf16
// bids [256,512): K same -> kbuf bf16
// bids [512,1024): V BM=64/BN=128, 32 iters, BOTH products per iter (A x Bhi + A x Blo)
//                  XCD-pinned B panel: n0 = (u&7)*128 (0.5MB hi+lo resident in L2)
// bids [1024,1056): pos_k / pos_q projections
__global__ __launch_bounds__(256) void k_qkvp(const us* __restrict__ Xq, const us* __restrict__ Xkv,
                                              const us* __restrict__ wt,
                                              const float* __restrict__ bq, const float* __restrict__ bk,
                                              const float* __restrict__ bv,
                                              const us* __restrict__ reln_hi,
                                              const float* __restrict__ bpk, const float* __restrict__ bpq,
                                              us* __restrict__ qbuf, us* __restrict__ kbuf,
                                              us* __restrict__ vtb,
                                              us* __restrict__ posk_hi, us* __restrict__ posq_hi)
{
  __shared__ __align__(16) us a_lds[2][4096];   // Q/K: 128x32 ; V: 64x32 (first 4KB)
  __shared__ __align__(16) us b_lds[2][8192];   // Q/K: 128x32 (first 8KB) ; V: Bhi 128x32 + Blo 128x32
  const int bid = blockIdx.x;
  const int t = threadIdx.x, w = t >> 6, lane = t & 63, lg = lane >> 4, li = lane & 15;

  if (bid >= 1024){                     // ---- pos projections (32 blocks)
    int wg2 = bid - 1024;
    int ntile = wg2 & 15, z = wg2 >> 4;
    const us* W_hi = wt + (size_t)(3 + z) * 2097152;
    const float* bias = z ? bpq : bpk;
    us* out_hi = z ? posq_hi : posk_hi;
    f32x4 acc[4];
#pragma unroll
    for (int i=0;i<4;i++) acc[i] = fzero();
    int srow = w*16 + li;
    for (int kt = 0; kt < 32; kt++){
      int k0 = kt*32 + lg*8;
      bf16x8 a = *(const bf16x8*)(reln_hi + (size_t)srow*1024 + k0);
#pragma unroll
      for (int nf=0; nf<4; nf++){
        int n = ntile*64 + nf*16 + li;
        bf16x8 b = *(const bf16x8*)(W_hi + (size_t)n*1024 + k0);
        acc[nf] = mfma16(a, b, acc[nf]);
      }
    }
#pragma unroll
    for (int nf=0;nf<4;nf++){
      int n = ntile*64 + nf*16 + li;
      float bn = bias[n];
      int h = n >> 6, hd = n & 63;
#pragma unroll
      for (int j=0;j<4;j++){
        int s = w*16 + lg*4 + j;
        out_hi[(size_t)h*4096 + s*64 + hd] = f2bf(acc[nf][j] + bn);
      }
    }
    return;
  }

  if (bid < 512){                       // ---- Q / K classes (r9-proven geometry)
    int cls = bid >> 8;                 // 0:Q 1:K
    int u = bid & 255;
    int tile = (u & 7) * 32 + (u >> 3); // XCD-contiguous chunk within class
    int mt = tile >> 3, nt = tile & 7;
    int m0 = mt * 128, n0 = nt * 128;
    const us* A  = cls ? Xkv : Xq;
    const us* Bp = wt + (size_t)cls * 2097152;
    const float* bias = cls ? bk : bq;
    us* out = cls ? kbuf : qbuf;
    int wm = w >> 1, wn = w & 1;
    f32x4 acc[4][4];
#pragma unroll
    for (int i=0;i<4;i++)
#pragma unroll
      for (int j=0;j<4;j++) acc[i][j] = fzero();

    auto stage = [&](int buf, int kt){
      int k0 = kt * 32;
#pragma unroll
      for (int c = 0; c < 2; c++){
        int slot = c*256 + t;
        int g = slot ^ ((slot >> 3) & 7);
        int r = g >> 2, kc = g & 3;
        gload_lds16(A  + (size_t)(m0 + r)*1024 + k0 + kc*8, (char*)&a_lds[buf][0] + slot*16);
        gload_lds16(Bp + (size_t)(n0 + r)*1024 + k0 + kc*8, (char*)&b_lds[buf][0] + slot*16);
      }
    };

    stage(0, 0);
    __syncthreads();
    int buf = 0;
    for (int kt = 0; kt < 32; kt++){
      if (kt + 1 < 32) stage(buf ^ 1, kt + 1);
      bf16x8 af[4], bfv[4];
#pragma unroll
      for (int mi=0;mi<4;mi++){
        int r = wm*64 + mi*16 + li;
        int s = (r*4 + lg); s ^= ((s >> 3) & 7);
        af[mi] = *(const bf16x8*)((char*)&a_lds[buf][0] + s*16);
      }
#pragma unroll
      for (int ni=0;ni<4;ni++){
        int r = wn*64 + ni*16 + li;
        int s = (r*4 + lg); s ^= ((s >> 3) & 7);
        bfv[ni] = *(const bf16x8*)((char*)&b_lds[buf][0] + s*16);
      }
#pragma unroll
      for (int mi=0;mi<4;mi++)
#pragma unroll
        for (int ni=0;ni<4;ni++)
          acc[mi][ni] = mfma16(af[mi], bfv[ni], acc[mi][ni]);
      __syncthreads();
      buf ^= 1;
    }

#pragma unroll
    for (int ni=0;ni<4;ni++){
      int n = n0 + wn*64 + ni*16 + li;
      float bn = bias[n];
      int hh = n >> 6, hd = n & 63;
#pragma unroll
      for (int mi=0;mi<4;mi++){
        int mb = m0 + wm*64 + mi*16 + lg*4;
#pragma unroll
        for (int j=0;j<4;j++){
          int m = mb + j;
          int bb = m >> 10, tp = m & 1023;
          out[(((size_t)(bb*16 + hh))*1024 + tp)*64 + hd] = f2bf(acc[mi][ni][j] + bn);
        }
      }
    }
    return;
  }

  // ---- V class: BM=64, BN=128, 32 iters, both products per iter; B panel pinned to XCD
  {
    int u = bid - 512;                  // 0..511; XCD = bid&7 = u&7
    int m0 = (u >> 3) * 64;             // 64 mt tiles stream over rows
    int n0 = (u & 7) * 128;             // B panel fixed per XCD -> L2-resident (0.5MB hi+lo)
    const us* Bh = wt + (size_t)2 * 2097152;
    const us* Bl = Bh + 1048576;
    int wm = w >> 1, wn = w & 1;
    f32x4 acc[2][4];
#pragma unroll
    for (int i=0;i<2;i++)
#pragma unroll
      for (int j=0;j<4;j++) acc[i][j] = fzero();

    auto stage = [&](int buf, int kt){
      int k0 = kt * 32;
      {
        int slot = t;                    // A: 64x32 = 256 chunks
        int g = slot ^ ((slot >> 3) & 7);
        int r = g >> 2, kc = g & 3;
        gload_lds16(Xkv + (size_t)(m0 + r)*1024 + k0 + kc*8, (char*)&a_lds[buf][0] + slot*16);
      }
#pragma unroll
      for (int c = 0; c < 2; c++){       // Bhi: 128x32 = 512 chunks -> b_lds[buf][0..4095]
        int slot = c*256 + t;
        int g = slot ^ ((slot >> 3) & 7);
        int r = g >> 2, kc = g & 3;
        gload_lds16(Bh + (size_t)(n0 + r)*1024 + k0 + kc*8, (char*)&b_lds[buf][0] + slot*16);
        gload_lds16(Bl + (size_t)(n0 + r)*1024 + k0 + kc*8, (char*)&b_lds[buf][4096] + slot*16);
      }
    };

    stage(0, 0);
    __syncthreads();
    int buf = 0;
    for (int kt = 0; kt < 32; kt++){
      if (kt + 1 < 32) stage(buf ^ 1, kt + 1);
      bf16x8 af[2], bh_[4], bl_[4];
#pragma unroll
      for (int mi=0;mi<2;mi++){
        int r = wm*32 + mi*16 + li;
        int s = (r*4 + lg); s ^= ((s >> 3) & 7);
        af[mi] = *(const bf16x8*)((char*)&a_lds[buf][0] + s*16);
      }
#pragma unroll
      for (int ni=0;ni<4;ni++){
        int r = wn*64 + ni*16 + li;
        int s = (r*4 + lg); s ^= ((s >> 3) & 7);
        bh_[ni] = *(const bf16x8*)((char*)&b_lds[buf][0] + s*16);
        bl_[ni] = *(const bf16x8*)((char*)&b_lds[buf][4096] + s*16);
      }
#pragma unroll
      for (int mi=0;mi<2;mi++)
#pragma unroll
        for (int ni=0;ni<4;ni++){
          acc[mi][ni] = mfma16(af[mi], bh_[ni], acc[mi][ni]);
          acc[mi][ni] = mfma16(af[mi], bl_[ni], acc[mi][ni]);
        }
      __syncthreads();
      buf ^= 1;
    }

#pragma unroll
    for (int ni=0;ni<4;ni++){
      int n = n0 + wn*64 + ni*16 + li;
      float bn = bv[n];
      int hh = n >> 6, hd = n & 63;
#pragma unroll
      for (int mi=0;mi<2;mi++){
        int mb = m0 + wm*32 + mi*16 + lg*4;
#pragma unroll
        for (int j=0;j<4;j++){
          int m = mb + j;
          int bb = m >> 10, tp = m & 1023;
          vtb[(((size_t)(bb*16 + hh))*64 + hd)*1024 + tp] = f2bf(acc[mi][ni][j] + bn);
        }
      }
    }
  }
}

// ---------------- 3: O GEMM: 3 products, BM=128, BN=64, fp32 out ----------------
__global__ __launch_bounds__(256, 2) void k_gemmo(const us* __restrict__ A_hi, const us* __restrict__ A_lo,
                                                  const us* __restrict__ B_hi, const us* __restrict__ B_lo,
                                                  const float* __restrict__ bias,
                                                  float* __restrict__ out_f)
{
  __shared__ __align__(16) us a_lds[2][4096];
  __shared__ __align__(16) us b_lds[2][2048];
  int bid = blockIdx.x;
  int wg = (bid & 7) * 64 + (bid >> 3);        // 512 % 8 == 0
  int mt = wg >> 4, nt = wg & 15;
  int m0 = mt * 128, n0 = nt * 64;
  int t = threadIdx.x, w = t >> 6, lane = t & 63, lg = lane >> 4, li = lane & 15;
  int wm = w >> 1, wn = w & 1;
  f32x4 acc[4][2];
#pragma unroll
  for (int i=0;i<4;i++){ acc[i][0]=fzero(); acc[i][1]=fzero(); }

  auto stage = [&](int buf, int kt){
    int seg = kt >> 5, k0 = (kt & 31) * 32;
    const us* Ap = (seg == 2) ? A_lo : A_hi;
    const us* Bp = (seg == 1) ? B_lo : B_hi;
#pragma unroll
    for (int c = 0; c < 2; c++){
      int slot = c*256 + t;
      int g = slot ^ ((slot >> 3) & 7);
      int r = g >> 2, kc = g & 3;
      gload_lds16(Ap + (size_t)(m0 + r)*1024 + k0 + kc*8, (char*)&a_lds[buf][0] + slot*16);
    }
    {
      int slot = t;
      int g = slot ^ ((slot >> 3) & 7);
      int r = g >> 2, kc = g & 3;
      gload_lds16(Bp + (size_t)(n0 + r)*1024 + k0 + kc*8, (char*)&b_lds[buf][0] + slot*16);
    }
  };

  stage(0, 0);
  __syncthreads();
  int buf = 0;
  for (int kt = 0; kt < 96; kt++){
    if (kt + 1 < 96) stage(buf ^ 1, kt + 1);
    bf16x8 af[4], bfv[2];
#pragma unroll
    for (int mi=0;mi<4;mi++){
      int r = wm*64 + mi*16 + li;
      int s = (r*4 + lg); s ^= ((s >> 3) & 7);
      af[mi] = *(const bf16x8*)((char*)&a_lds[buf][0] + s*16);
    }
#pragma unroll
    for (int ni=0;ni<2;ni++){
      int r = wn*32 + ni*16 + li;
      int s = (r*4 + lg); s ^= ((s >> 3) & 7);
      bfv[ni] = *(const bf16x8*)((char*)&b_lds[buf][0] + s*16);
    }
#pragma unroll
    for (int mi=0;mi<4;mi++)
#pragma unroll
      for (int ni=0;ni<2;ni++)
        acc[mi][ni] = mfma16(af[mi], bfv[ni], acc[mi][ni]);
    __syncthreads();
    buf ^= 1;
  }

#pragma unroll
  for (int ni=0;ni<2;ni++){
    int n = n0 + wn*32 + ni*16 + li;
    float bn = bias[n];
#pragma unroll
    for (int mi=0;mi<4;mi++){
      int mb = m0 + wm*64 + mi*16 + lg*4;
#pragma unroll
      for (int j=0;j<4;j++)
        out_f[(size_t)(mb + j)*1024 + n] = acc[mi][ni][j] + bn;
    }
  }
}

// ---------------- 4: c2p/p2c (single product, pre-scaled by BS for exp2) ----------------
__global__ __launch_bounds__(256) void k_cp(const us* __restrict__ q_hi,
                                            const us* __restrict__ k_hi,
                                            const us* __restrict__ pk_hi,
                                            const us* __restrict__ pq_hi,
                                            us* __restrict__ c2p, us* __restrict__ p2c)
{
  int qt = blockIdx.x, bh = blockIdx.y, z = blockIdx.z;
  const us* X_hi = z ? k_hi : q_hi;
  const us* P_hi = z ? pq_hi : pk_hi;
  us* out = z ? p2c : c2p;
  int h = bh & 15;
  int t = threadIdx.x, w = t >> 6, lane = t & 63, lg = lane >> 4, li = lane & 15;
  f32x4 acc[4];
#pragma unroll
  for (int i=0;i<4;i++) acc[i] = fzero();
  size_t row = (size_t)bh*1024 + qt*64 + w*16 + li;
#pragma unroll
  for (int kk=0;kk<2;kk++){
    int k = kk*32 + lg*8;
    bf16x8 ah = *(const bf16x8*)(X_hi + row*64 + k);
#pragma unroll
    for (int nf=0;nf<4;nf++){
      int s = nf*16 + li;
      bf16x8 bh_ = *(const bf16x8*)(P_hi + (size_t)h*4096 + s*64 + k);
      acc[nf] = mfma16(ah, bh_, acc[nf]);
    }
  }
  size_t obase = ((size_t)bh*1024 + qt*64 + w*16 + lg*4) * 64;
#pragma unroll
  for (int nf=0;nf<4;nf++)
#pragma unroll
    for (int j=0;j<4;j++)
      out[obase + (size_t)j*64 + nf*16 + li] = f2bf(acc[nf][j] * BS);
}

// ---------------- 5: fused attention: 8 waves, QBLK=128, far fast path ----------------
__global__ __launch_bounds__(512) void k_attn(const us* __restrict__ qhi,
                                              const us* __restrict__ khi,
                                              const us* __restrict__ vhi,
                                              const us* __restrict__ c2p, const us* __restrict__ p2c,
                                              const signed char* __restrict__ idxt,
                                              const unsigned char* __restrict__ mask,
                                              us* __restrict__ ctx_hi, us* __restrict__ ctx_lo)
{
  __shared__ __align__(16) us khi_lds[4096], vhi_lds[4096];
  __shared__ __align__(16) us c2p_lds[128*72], p2c_lds[64*72];   // padded rows: 144B stride
  __shared__ __align__(16) us p_lds[8][1024];
  __shared__ signed char idx_lds[2048];

  const int qt = blockIdx.x, bh = blockIdx.y;   // qt: 0..7
  const int b = bh >> 4, h = bh & 15;
  const int t = threadIdx.x, w = t >> 6, lane = t & 63, lg = lane >> 4, li = lane & 15;
  const int q0 = qt * 128;

  for (int i = t; i < 2047; i += 512) idx_lds[i] = idxt[i];
  {
    const us* src = c2p + ((size_t)bh*1024 + q0) * 64;
#pragma unroll
    for (int c = 0; c < 2; c++){
      int f = c*512 + t, r = f >> 3, kc = f & 7;
      *(ushort8*)&c2p_lds[r*72 + kc*8] = *(const ushort8*)(src + r*64 + kc*8);
    }
  }
  bf16x8 qfh[2];
  {
    const us* qph = qhi + ((size_t)bh*1024 + q0 + w*16 + li)*64 + lg*8;
    qfh[0] = *(const bf16x8*)(qph); qfh[1] = *(const bf16x8*)(qph + 32);
  }
  __syncthreads();
  // far-path per-row bias (scaled) for idx=0 / idx=63
  float cq0[4], cq63[4];
#pragma unroll
  for (int j=0;j<4;j++){
    int qloc = w*16 + lg*4 + j;
    cq0[j]  = b2f(c2p_lds[qloc*72 + 0]);
    cq63[j] = b2f(c2p_lds[qloc*72 + 63]);
  }

  float lrow[4];
  f32x4 accO[4];
#pragma unroll
  for (int j=0;j<4;j++){ lrow[j] = 0.f; accO[j] = fzero(); }
  const unsigned char* mptr = mask + b*1024;

  for (int kt = 0; kt < 16; kt++){
    const int k0 = kt * 64;
    const bool far = (q0 - k0 >= 192) || (k0 - q0 >= 256);
    __syncthreads();
    {  // stage K,V: one 16B chunk each per thread
      int r = t >> 3, kc = t & 7;
      *(ushort8*)&khi_lds[r*64 + ((kc ^ (r & 7))*8)] =
          *(const ushort8*)(khi + ((size_t)bh*1024 + k0 + r)*64 + kc*8);
      *(ushort8*)&vhi_lds[r*64 + ((kc ^ (r & 7))*8)] =
          *(const ushort8*)(vhi + ((size_t)bh*64 + r)*1024 + k0 + kc*8);
      if (!far)
        *(ushort8*)&p2c_lds[r*72 + kc*8] =
            *(const ushort8*)(p2c + ((size_t)bh*1024 + k0 + r)*64 + kc*8);
    }
    __syncthreads();

    // QK^T single product
    f32x4 sfr[4];
#pragma unroll
    for (int nf=0;nf<4;nf++) sfr[nf] = fzero();
#pragma unroll
    for (int kk=0; kk<2; kk++){
      int kc = kk*4 + lg;
#pragma unroll
      for (int nf=0; nf<4; nf++){
        int r = nf*16 + li;
        bf16x8 bh_ = *(const bf16x8*)&khi_lds[r*64 + ((kc ^ (r & 7))*8)];
        sfr[nf] = mfma16(qfh[kk], bh_, sfr[nf]);
      }
    }
    us* pl = &p_lds[w][0];
    if (far){
      const int cidx = (q0 > k0) ? 63 : 0;
      float cq[4];
#pragma unroll
      for (int j=0;j<4;j++) cq[j] = (q0 > k0) ? cq63[j] : cq0[j];
#pragma unroll
      for (int nf=0; nf<4; nf++){
        int kloc = nf*16 + li;
        bool mk = mptr[k0 + kloc] != 0;
        float ck = b2f(p2c[((size_t)bh*1024 + k0 + kloc)*64 + cidx]);
        int col = kloc;
#pragma unroll
        for (int j=0;j<4;j++){
          float p = mk ? 0.f : exp2f(fmaf(sfr[nf][j], QS2, cq[j] + ck));
          lrow[j] += p;
          int row = lg*4 + j;
          pl[row*64 + ((col & 7) | ((((col >> 3) ^ (row & 7))) << 3))] = f2bf(p);
        }
      }
    } else {
#pragma unroll
      for (int nf=0; nf<4; nf++){
        int kloc = nf*16 + li;
        bool mk = mptr[k0 + kloc] != 0;
        int col = kloc;
#pragma unroll
        for (int j=0;j<4;j++){
          int qloc = w*16 + lg*4 + j;
          int d = (q0 + qloc) - (k0 + kloc);
          int idx = (int)idx_lds[d + 1023];
          float s2 = fmaf(sfr[nf][j], QS2,
                          b2f(c2p_lds[qloc*72 + idx]) + b2f(p2c_lds[kloc*72 + idx]));
          float p = mk ? 0.f : exp2f(s2);
          lrow[j] += p;
          int row = lg*4 + j;
          pl[row*64 + ((col & 7) | ((((col >> 3) ^ (row & 7))) << 3))] = f2bf(p);
        }
      }
    }
    // PV single product (p_lds wave-private; same-wave DS ordering)
#pragma unroll
    for (int kk=0;kk<2;kk++){
      int kc = kk*4 + lg;
      bf16x8 af = *(const bf16x8*)((char*)pl + li*128 + ((kc ^ (li & 7)) * 16));
#pragma unroll
      for (int nf=0;nf<4;nf++){
        int r = nf*16 + li;
        bf16x8 bh_ = *(const bf16x8*)&vhi_lds[r*64 + ((kc ^ (r & 7))*8)];
        accO[nf] = mfma16(af, bh_, accO[nf]);
      }
    }
  }

  for (int o=1;o<16;o<<=1)
#pragma unroll
    for (int j=0;j<4;j++)
      lrow[j] += __shfl_xor(lrow[j], o);
#pragma unroll
  for (int nf=0;nf<4;nf++)
#pragma unroll
    for (int j=0;j<4;j++){
      int qloc = w*16 + lg*4 + j;
      float o = accO[nf][j] / lrow[j];
      size_t idx = ((size_t)(b*1024 + q0 + qloc))*1024 + h*64 + nf*16 + li;
      us hh,ll; split2(o,hh,ll);
      ctx_hi[idx] = hh; ctx_lo[idx] = ll;
    }
}

// ---------------- launch ----------------
extern "C" void kernel_launch(void* const* d_in, const int* in_sizes, int n_in,
                              void* d_out, int out_size, void* d_ws, size_t ws_size,
                              hipStream_t stream)
{
  (void)in_sizes; (void)n_in; (void)out_size; (void)ws_size;
  const float* query = (const float*)d_in[0];
  const float* kvst  = (const float*)d_in[1];
  const unsigned char* mask = (const unsigned char*)d_in[2];
  const float* Wq = (const float*)d_in[3];  const float* bq = (const float*)d_in[4];
  const float* Wk = (const float*)d_in[5];  const float* bk = (const float*)d_in[6];
  const float* Wv = (const float*)d_in[7];  const float* bv = (const float*)d_in[8];
  const float* Wo = (const float*)d_in[9];  const float* bo = (const float*)d_in[10];
  const float* rel = (const float*)d_in[11];
  const float* lng = (const float*)d_in[12]; const float* lnb = (const float*)d_in[13];
  const float* Wpk = (const float*)d_in[14]; const float* bpk = (const float*)d_in[15];
  const float* Wpq = (const float*)d_in[16]; const float* bpq = (const float*)d_in[17];

  char* ws = (char*)d_ws;
  const size_t MB = 1024*1024;
  // r9-proven layout (alias-safe by execution order):
  us* Xq_hi  = (us*)(ws + 0);        // [0,8)   dead after k_qkvp
  us* p2c    = (us*)(ws + 8*MB);     // [8,16)  k_cp z=1 writes (after k_qkvp)
  us* Xkv_hi = (us*)(ws + 16*MB);    // [16,24) dead after k_qkvp
  us* c2p    = (us*)(ws + 16*MB);    //         k_cp z=0 writes
  us* vtb    = (us*)(ws + 24*MB);    // [24,32) k_qkvp V writes; k_attn reads
  us* Wt     = (us*)(ws + 32*MB);    // [32,56) 6 slots x 4MB
  us* ctx_hi = (us*)(ws + 32*MB);    //         k_attn writes over Wq/Wk slots (dead)
  us* ctx_lo = (us*)(ws + 40*MB);    //         over Wv/Wpk slots (dead after k_qkvp)
  us* reln_hi = (us*)(ws + 56*MB);
  us* posk_hi = (us*)(ws + 56*MB + 256*1024);
  us* posq_hi = (us*)(ws + 56*MB + 512*1024);
  signed char* idxt = (signed char*)(ws + 56*MB + 768*1024);
  us* qbuf_hi = (us*)(ws + 57*MB);   // [57,65)
  us* kbuf_hi = (us*)(ws + 65*MB);   // [65,73)

  k_prep<<<14409, 256, 0, stream>>>(query, kvst, Wq, Wk, Wv, Wpk, Wpq, Wo,
                                    rel, lng, lnb,
                                    Xq_hi, Xkv_hi, Wt, reln_hi, idxt);

  k_qkvp<<<1056, 256, 0, stream>>>(Xq_hi, Xkv_hi, Wt, bq, bk, bv,
                                   reln_hi, bpk, bpq,
                                   qbuf_hi, kbuf_hi, vtb, posk_hi, posq_hi);

  k_cp<<<dim3(16,64,2), 256, 0, stream>>>(qbuf_hi, kbuf_hi, posk_hi, posq_hi, c2p, p2c);

  k_attn<<<dim3(8,64), 512, 0, stream>>>(qbuf_hi, kbuf_hi, vtb,
                                         c2p, p2c, idxt, mask, ctx_hi, ctx_lo);

  k_gemmo<<<512, 256, 0, stream>>>(ctx_hi, ctx_lo, Wt + 5*2097152, Wt + 5*2097152 + 1048576, bo, (float*)d_out);
}

// Round 14
// 188.722 us; speedup vs baseline: 1.1285x; 1.0495x over previous
//
#include <hip/hip_runtime.h>
#include <cstdint>
#include <math.h>

typedef unsigned short us;
typedef __attribute__((ext_vector_type(8))) __bf16 bf16x8;
typedef __attribute__((ext_vector_type(8))) unsigned short ushort8;
typedef __attribute__((ext_vector_type(4))) float f32x4;

__device__ __forceinline__ us f2bf(float x){
  union { float f; unsigned int u; } v; v.f = x;
  unsigned int r = v.u + 0x7FFFu + ((v.u >> 16) & 1u);   // RNE
  return (us)(r >> 16);
}
__device__ __forceinline__ float b2f(us u){
  union { unsigned int u; float f; } v; v.u = ((unsigned int)u) << 16; return v.f;
}
__device__ __forceinline__ void split2(float x, us& hi, us& lo){
  hi = f2bf(x); lo = f2bf(x - b2f(hi));
}
__device__ __forceinline__ f32x4 fzero(){ f32x4 v; v.x=0.f; v.y=0.f; v.z=0.f; v.w=0.f; return v; }
__device__ __forceinline__ f32x4 mfma16(bf16x8 a, bf16x8 b, f32x4 c){
  return __builtin_amdgcn_mfma_f32_16x16x32_bf16(a, b, c, 0, 0, 0);
}
__device__ __forceinline__ void gload_lds16(const void* g, void* l){
  __builtin_amdgcn_global_load_lds(
      (const __attribute__((address_space(1))) unsigned int*)(uintptr_t)g,
      (__attribute__((address_space(3))) unsigned int*)(uintptr_t)l,
      16, 0, 0);
}

// exp2-folded scales
#define QS2 (0.07216878364870322f * 1.4426950408889634f)   // 1/sqrt(192) * log2(e)
#define BS  (0.08838834764831845f * 1.4426950408889634f)   // 1/sqrt(128) * log2(e)

// ---------------- 1: fused prep: convx | convw | lnrel | bucket ----------------
__global__ __launch_bounds__(256) void k_prep(const float* __restrict__ xq,
                                              const float* __restrict__ xkv,
                                              const float* __restrict__ w0, const float* __restrict__ w1,
                                              const float* __restrict__ w2, const float* __restrict__ w3,
                                              const float* __restrict__ w4, const float* __restrict__ w5,
                                              const float* __restrict__ rel,
                                              const float* __restrict__ g, const float* __restrict__ bLN,
                                              us* __restrict__ qhi, us* __restrict__ kvhi,
                                              us* __restrict__ wt, us* __restrict__ reln_hi,
                                              signed char* __restrict__ idxt)
{
  __shared__ float tile[32][33];
  __shared__ float sm[8];
  const int bid = blockIdx.x, t = threadIdx.x;

  if (bid < 8192){                      // ---- convx (hi only)
    int i = bid * 256 + t;
    const float* src; us* dh;
    if (i < 1048576){ src = xq  + (size_t)i*4;           dh = qhi  + (size_t)i*4; }
    else            { src = xkv + (size_t)(i-1048576)*4; dh = kvhi + (size_t)(i-1048576)*4; }
    f32x4 v = *(const f32x4*)src;
    dh[0]=f2bf(v.x); dh[1]=f2bf(v.y); dh[2]=f2bf(v.z); dh[3]=f2bf(v.w);
    return;
  }
  if (bid < 14336){                     // ---- convw: transpose + hi/lo split
    int rem = bid - 8192;
    int z = rem >> 10, r2 = rem & 1023;
    const float* W = (z==0)?w0:(z==1)?w1:(z==2)?w2:(z==3)?w3:(z==4)?w4:w5;
    us* dst_hi = wt + (size_t)z * 2097152;
    us* dst_lo = dst_hi + 1048576;
    bool wlo = (z == 2) || (z == 5);
    int n0 = (r2 & 31) * 32, k0 = (r2 >> 5) * 32;
    int c = t & 31, r = t >> 5;
#pragma unroll
    for (int i = 0; i < 4; i++)
      tile[r + i*8][c] = W[(size_t)(k0 + r + i*8)*1024 + n0 + c];
    __syncthreads();
#pragma unroll
    for (int i = 0; i < 4; i++){
      int nn = r + i*8;
      us h,l; split2(tile[c][nn], h, l);
      dst_hi[(size_t)(n0 + nn)*1024 + k0 + c] = h;
      if (wlo) dst_lo[(size_t)(n0 + nn)*1024 + k0 + c] = l;
    }
    return;
  }
  if (bid < 14400){                     // ---- lnrel
    int row = bid - 14336;
    const float* x = rel + (size_t)row * 1024;
    float v[4]; float s = 0.f, ss = 0.f;
#pragma unroll
    for (int i=0;i<4;i++){ v[i] = x[t + 256*i]; s += v[i]; ss += v[i]*v[i]; }
    for (int o=32;o;o>>=1){ s += __shfl_xor(s,o); ss += __shfl_xor(ss,o); }
    int w = t >> 6;
    if ((t & 63) == 0){ sm[w] = s; sm[4+w] = ss; }
    __syncthreads();
    s  = sm[0]+sm[1]+sm[2]+sm[3];
    ss = sm[4]+sm[5]+sm[6]+sm[7];
    float mu  = s  * (1.0f/1024.0f);
    float var = ss * (1.0f/1024.0f) - mu*mu;
    float rs  = rsqrtf(var + 1e-5f);
#pragma unroll
    for (int i=0;i<4;i++){
      int cc = t + 256*i;
      reln_hi[(size_t)row*1024 + cc] = f2bf((v[i]-mu)*rs*g[cc] + bLN[cc]);
    }
    return;
  }
  {                                     // ---- bucket table
    int i = (bid - 14400) * 256 + t;
    if (i >= 2052) return;
    int d = i - 1023;
    int ad = d < 0 ? -d : d;
    int abspos = (d < 16 && d > -16) ? 15 : ad;
    int bucket;
    if (abspos <= 16) bucket = d;
    else {
      float num = (float)log((double)abspos * 0.0625);
      float den = (float)log(7.9375);
      float lp = ceilf(num / den * 15.0f) + 16.0f;
      bucket = (int)lp * (d > 0 ? 1 : -1);
    }
    int s = bucket + 32;
    s = s < 0 ? 0 : (s > 63 ? 63 : s);
    idxt[i] = (signed char)s;
  }
}

// ---------------- 2: merged QKV GEMM + pos projections, grid=800 ----------------
// bids [0,32): pos_k/pos_q (short, finish early)
// bids [32,288): Q BM=128/BN=128 NKT=32 -> qbuf
// bids [288,544): K same -> kbuf
// bids [544,800): V BM=128/BN=128, 32 iters, fused hi+lo (32 MFMA/interval) -> vtb
__global__ __launch_bounds__(256) void k_qkvp(const us* __restrict__ Xq, const us* __restrict__ Xkv,
                                              const us* __restrict__ wt,
                                              const float* __restrict__ bq, const float* __restrict__ bk,
                                              const float* __restrict__ bv,
                                              const us* __restrict__ reln_hi,
                                              const float* __restrict__ bpk, const float* __restrict__ bpq,
                                              us* __restrict__ qbuf, us* __restrict__ kbuf,
                                              us* __restrict__ vtb,
                                              us* __restrict__ posk_hi, us* __restrict__ posq_hi)
{
  __shared__ __align__(16) us a_lds[2][4096];   // 128 x 32
  __shared__ __align__(16) us b_lds[2][8192];   // Q/K: first 4096 used ; V: hi [0,4096) + lo [4096,8192)
  const int bid = blockIdx.x;
  const int t = threadIdx.x, w = t >> 6, lane = t & 63, lg = lane >> 4, li = lane & 15;

  if (bid < 32){                        // ---- pos projections
    int ntile = bid & 15, z = bid >> 4;
    const us* W_hi = wt + (size_t)(3 + z) * 2097152;
    const float* bias = z ? bpq : bpk;
    us* out_hi = z ? posq_hi : posk_hi;
    f32x4 acc[4];
#pragma unroll
    for (int i=0;i<4;i++) acc[i] = fzero();
    int srow = w*16 + li;
    for (int kt = 0; kt < 32; kt++){
      int k0 = kt*32 + lg*8;
      bf16x8 a = *(const bf16x8*)(reln_hi + (size_t)srow*1024 + k0);
#pragma unroll
      for (int nf=0; nf<4; nf++){
        int n = ntile*64 + nf*16 + li;
        bf16x8 b = *(const bf16x8*)(W_hi + (size_t)n*1024 + k0);
        acc[nf] = mfma16(a, b, acc[nf]);
      }
    }
#pragma unroll
    for (int nf=0;nf<4;nf++){
      int n = ntile*64 + nf*16 + li;
      float bn = bias[n];
      int h = n >> 6, hd = n & 63;
#pragma unroll
      for (int j=0;j<4;j++){
        int s = w*16 + lg*4 + j;
        out_hi[(size_t)h*4096 + s*64 + hd] = f2bf(acc[nf][j] + bn);
      }
    }
    return;
  }

  if (bid < 544){                       // ---- Q / K classes (proven geometry)
    int cls = (bid - 32) >> 8;          // 0:Q 1:K
    int u = (bid - 32) & 255;
    int tile = (u & 7) * 32 + (u >> 3); // XCD-contiguous chunk within class
    int mt = tile >> 3, nt = tile & 7;
    int m0 = mt * 128, n0 = nt * 128;
    const us* A  = cls ? Xkv : Xq;
    const us* Bp = wt + (size_t)cls * 2097152;
    const float* bias = cls ? bk : bq;
    us* out = cls ? kbuf : qbuf;
    int wm = w >> 1, wn = w & 1;
    f32x4 acc[4][4];
#pragma unroll
    for (int i=0;i<4;i++)
#pragma unroll
      for (int j=0;j<4;j++) acc[i][j] = fzero();

    auto stage = [&](int buf, int kt){
      int k0 = kt * 32;
#pragma unroll
      for (int c = 0; c < 2; c++){
        int slot = c*256 + t;
        int g = slot ^ ((slot >> 3) & 7);
        int r = g >> 2, kc = g & 3;
        gload_lds16(A  + (size_t)(m0 + r)*1024 + k0 + kc*8, (char*)&a_lds[buf][0] + slot*16);
        gload_lds16(Bp + (size_t)(n0 + r)*1024 + k0 + kc*8, (char*)&b_lds[buf][0] + slot*16);
      }
    };

    stage(0, 0);
    __syncthreads();
    int buf = 0;
    for (int kt = 0; kt < 32; kt++){
      if (kt + 1 < 32) stage(buf ^ 1, kt + 1);
      bf16x8 af[4], bfv[4];
#pragma unroll
      for (int mi=0;mi<4;mi++){
        int r = wm*64 + mi*16 + li;
        int s = (r*4 + lg); s ^= ((s >> 3) & 7);
        af[mi] = *(const bf16x8*)((char*)&a_lds[buf][0] + s*16);
      }
#pragma unroll
      for (int ni=0;ni<4;ni++){
        int r = wn*64 + ni*16 + li;
        int s = (r*4 + lg); s ^= ((s >> 3) & 7);
        bfv[ni] = *(const bf16x8*)((char*)&b_lds[buf][0] + s*16);
      }
#pragma unroll
      for (int mi=0;mi<4;mi++)
#pragma unroll
        for (int ni=0;ni<4;ni++)
          acc[mi][ni] = mfma16(af[mi], bfv[ni], acc[mi][ni]);
      __syncthreads();
      buf ^= 1;
    }

#pragma unroll
    for (int ni=0;ni<4;ni++){
      int n = n0 + wn*64 + ni*16 + li;
      float bn = bias[n];
      int hh = n >> 6, hd = n & 63;
#pragma unroll
      for (int mi=0;mi<4;mi++){
        int mb = m0 + wm*64 + mi*16 + lg*4;
#pragma unroll
        for (int j=0;j<4;j++){
          int m = mb + j;
          int bb = m >> 10, tp = m & 1023;
          out[(((size_t)(bb*16 + hh))*1024 + tp)*64 + hd] = f2bf(acc[mi][ni][j] + bn);
        }
      }
    }
    return;
  }

  // ---- V class: BM=128, BN=128, 32 iters, fused hi+lo (32 MFMA/interval), 256 blocks
  {
    int u = bid - 544;
    int tile = (u & 7) * 32 + (u >> 3);
    int mt = tile >> 3, nt = tile & 7;
    int m0 = mt * 128, n0 = nt * 128;
    const us* Bh = wt + (size_t)2 * 2097152;
    const us* Bl = Bh + 1048576;
    int wm = w >> 1, wn = w & 1;
    f32x4 acc[4][4];
#pragma unroll
    for (int i=0;i<4;i++)
#pragma unroll
      for (int j=0;j<4;j++) acc[i][j] = fzero();

    auto stage = [&](int buf, int kt){
      int k0 = kt * 32;
#pragma unroll
      for (int c = 0; c < 2; c++){
        int slot = c*256 + t;
        int g = slot ^ ((slot >> 3) & 7);
        int r = g >> 2, kc = g & 3;
        gload_lds16(Xkv + (size_t)(m0 + r)*1024 + k0 + kc*8, (char*)&a_lds[buf][0] + slot*16);
        gload_lds16(Bh  + (size_t)(n0 + r)*1024 + k0 + kc*8, (char*)&b_lds[buf][0] + slot*16);
        gload_lds16(Bl  + (size_t)(n0 + r)*1024 + k0 + kc*8, (char*)&b_lds[buf][0] + 8192 + slot*16);
      }
    };

    stage(0, 0);
    __syncthreads();
    int buf = 0;
    for (int kt = 0; kt < 32; kt++){
      if (kt + 1 < 32) stage(buf ^ 1, kt + 1);
      bf16x8 af[4], bh_[4], bl_[4];
#pragma unroll
      for (int mi=0;mi<4;mi++){
        int r = wm*64 + mi*16 + li;
        int s = (r*4 + lg); s ^= ((s >> 3) & 7);
        af[mi] = *(const bf16x8*)((char*)&a_lds[buf][0] + s*16);
      }
#pragma unroll
      for (int ni=0;ni<4;ni++){
        int r = wn*64 + ni*16 + li;
        int s = (r*4 + lg); s ^= ((s >> 3) & 7);
        bh_[ni] = *(const bf16x8*)((char*)&b_lds[buf][0] + s*16);
        bl_[ni] = *(const bf16x8*)((char*)&b_lds[buf][0] + 8192 + s*16);
      }
#pragma unroll
      for (int mi=0;mi<4;mi++)
#pragma unroll
        for (int ni=0;ni<4;ni++){
          acc[mi][ni] = mfma16(af[mi], bh_[ni], acc[mi][ni]);
          acc[mi][ni] = mfma16(af[mi], bl_[ni], acc[mi][ni]);
        }
      __syncthreads();
      buf ^= 1;
    }

#pragma unroll
    for (int ni=0;ni<4;ni++){
      int n = n0 + wn*64 + ni*16 + li;
      float bn = bv[n];
      int hh = n >> 6, hd = n & 63;
#pragma unroll
      for (int mi=0;mi<4;mi++){
        int mb = m0 + wm*64 + mi*16 + lg*4;
#pragma unroll
        for (int j=0;j<4;j++){
          int m = mb + j;
          int bb = m >> 10, tp = m & 1023;
          vtb[(((size_t)(bb*16 + hh))*64 + hd)*1024 + tp] = f2bf(acc[mi][ni][j] + bn);
        }
      }
    }
  }
}

// ---------------- 3: O GEMM: 3 products, BM=128, BN=64, fp32 out ----------------
__global__ __launch_bounds__(256, 2) void k_gemmo(const us* __restrict__ A_hi, const us* __restrict__ A_lo,
                                                  const us* __restrict__ B_hi, const us* __restrict__ B_lo,
                                                  const float* __restrict__ bias,
                                                  float* __restrict__ out_f)
{
  __shared__ __align__(16) us a_lds[2][4096];
  __shared__ __align__(16) us b_lds[2][2048];
  int bid = blockIdx.x;
  int wg = (bid & 7) * 64 + (bid >> 3);        // 512 % 8 == 0
  int mt = wg >> 4, nt = wg & 15;
  int m0 = mt * 128, n0 = nt * 64;
  int t = threadIdx.x, w = t >> 6, lane = t & 63, lg = lane >> 4, li = lane & 15;
  int wm = w >> 1, wn = w & 1;
  f32x4 acc[4][2];
#pragma unroll
  for (int i=0;i<4;i++){ acc[i][0]=fzero(); acc[i][1]=fzero(); }

  auto stage = [&](int buf, int kt){
    int seg = kt >> 5, k0 = (kt & 31) * 32;
    const us* Ap = (seg == 2) ? A_lo : A_hi;
    const us* Bp = (seg == 1) ? B_lo : B_hi;
#pragma unroll
    for (int c = 0; c < 2; c++){
      int slot = c*256 + t;
      int g = slot ^ ((slot >> 3) & 7);
      int r = g >> 2, kc = g & 3;
      gload_lds16(Ap + (size_t)(m0 + r)*1024 + k0 + kc*8, (char*)&a_lds[buf][0] + slot*16);
    }
    {
      int slot = t;
      int g = slot ^ ((slot >> 3) & 7);
      int r = g >> 2, kc = g & 3;
      gload_lds16(Bp + (size_t)(n0 + r)*1024 + k0 + kc*8, (char*)&b_lds[buf][0] + slot*16);
    }
  };

  stage(0, 0);
  __syncthreads();
  int buf = 0;
  for (int kt = 0; kt < 96; kt++){
    if (kt + 1 < 96) stage(buf ^ 1, kt + 1);
    bf16x8 af[4], bfv[2];
#pragma unroll
    for (int mi=0;mi<4;mi++){
      int r = wm*64 + mi*16 + li;
      int s = (r*4 + lg); s ^= ((s >> 3) & 7);
      af[mi] = *(const bf16x8*)((char*)&a_lds[buf][0] + s*16);
    }
#pragma unroll
    for (int ni=0;ni<2;ni++){
      int r = wn*32 + ni*16 + li;
      int s = (r*4 + lg); s ^= ((s >> 3) & 7);
      bfv[ni] = *(const bf16x8*)((char*)&b_lds[buf][0] + s*16);
    }
#pragma unroll
    for (int mi=0;mi<4;mi++)
#pragma unroll
      for (int ni=0;ni<2;ni++)
        acc[mi][ni] = mfma16(af[mi], bfv[ni], acc[mi][ni]);
    __syncthreads();
    buf ^= 1;
  }

#pragma unroll
  for (int ni=0;ni<2;ni++){
    int n = n0 + wn*32 + ni*16 + li;
    float bn = bias[n];
#pragma unroll
    for (int mi=0;mi<4;mi++){
      int mb = m0 + wm*64 + mi*16 + lg*4;
#pragma unroll
      for (int j=0;j<4;j++)
        out_f[(size_t)(mb + j)*1024 + n] = acc[mi][ni][j] + bn;
    }
  }
}

// ---------------- 4: c2p/p2c (single product, pre-scaled by BS for exp2) ----------------
__global__ __launch_bounds__(256) void k_cp(const us* __restrict__ q_hi,
                                            const us* __restrict__ k_hi,
                                            const us* __restrict__ pk_hi,
                                            const us* __restrict__ pq_hi,
                                            us* __restrict__ c2p, us* __restrict__ p2c)
{
  int qt = blockIdx.x, bh = blockIdx.y, z = blockIdx.z;
  const us* X_hi = z ? k_hi : q_hi;
  const us* P_hi = z ? pq_hi : pk_hi;
  us* out = z ? p2c : c2p;
  int h = bh & 15;
  int t = threadIdx.x, w = t >> 6, lane = t & 63, lg = lane >> 4, li = lane & 15;
  f32x4 acc[4];
#pragma unroll
  for (int i=0;i<4;i++) acc[i] = fzero();
  size_t row = (size_t)bh*1024 + qt*64 + w*16 + li;
#pragma unroll
  for (int kk=0;kk<2;kk++){
    int k = kk*32 + lg*8;
    bf16x8 ah = *(const bf16x8*)(X_hi + row*64 + k);
#pragma unroll
    for (int nf=0;nf<4;nf++){
      int s = nf*16 + li;
      bf16x8 bh_ = *(const bf16x8*)(P_hi + (size_t)h*4096 + s*64 + k);
      acc[nf] = mfma16(ah, bh_, acc[nf]);
    }
  }
  size_t obase = ((size_t)bh*1024 + qt*64 + w*16 + lg*4) * 64;
#pragma unroll
  for (int nf=0;nf<4;nf++)
#pragma unroll
    for (int j=0;j<4;j++)
      out[obase + (size_t)j*64 + nf*16 + li] = f2bf(acc[nf][j] * BS);
}

// ---------------- 5: fused attention: 8 waves, QBLK=128, far fast path ----------------
__global__ __launch_bounds__(512) void k_attn(const us* __restrict__ qhi,
                                              const us* __restrict__ khi,
                                              const us* __restrict__ vhi,
                                              const us* __restrict__ c2p, const us* __restrict__ p2c,
                                              const signed char* __restrict__ idxt,
                                              const unsigned char* __restrict__ mask,
                                              us* __restrict__ ctx_hi, us* __restrict__ ctx_lo)
{
  __shared__ __align__(16) us khi_lds[4096], vhi_lds[4096];
  __shared__ __align__(16) us c2p_lds[128*72], p2c_lds[64*72];   // padded rows: 144B stride
  __shared__ __align__(16) us p_lds[8][1024];
  __shared__ signed char idx_lds[2048];

  const int qt = blockIdx.x, bh = blockIdx.y;   // qt: 0..7
  const int b = bh >> 4, h = bh & 15;
  const int t = threadIdx.x, w = t >> 6, lane = t & 63, lg = lane >> 4, li = lane & 15;
  const int q0 = qt * 128;

  for (int i = t; i < 2047; i += 512) idx_lds[i] = idxt[i];
  {
    const us* src = c2p + ((size_t)bh*1024 + q0) * 64;
#pragma unroll
    for (int c = 0; c < 2; c++){
      int f = c*512 + t, r = f >> 3, kc = f & 7;
      *(ushort8*)&c2p_lds[r*72 + kc*8] = *(const ushort8*)(src + r*64 + kc*8);
    }
  }
  bf16x8 qfh[2];
  {
    const us* qph = qhi + ((size_t)bh*1024 + q0 + w*16 + li)*64 + lg*8;
    qfh[0] = *(const bf16x8*)(qph); qfh[1] = *(const bf16x8*)(qph + 32);
  }
  __syncthreads();
  // far-path per-row bias (scaled) for idx=0 / idx=63
  float cq0[4], cq63[4];
#pragma unroll
  for (int j=0;j<4;j++){
    int qloc = w*16 + lg*4 + j;
    cq0[j]  = b2f(c2p_lds[qloc*72 + 0]);
    cq63[j] = b2f(c2p_lds[qloc*72 + 63]);
  }

  float lrow[4];
  f32x4 accO[4];
#pragma unroll
  for (int j=0;j<4;j++){ lrow[j] = 0.f; accO[j] = fzero(); }
  const unsigned char* mptr = mask + b*1024;

  for (int kt = 0; kt < 16; kt++){
    const int k0 = kt * 64;
    const bool far = (q0 - k0 >= 192) || (k0 - q0 >= 256);
    __syncthreads();
    {  // stage K,V: one 16B chunk each per thread
      int r = t >> 3, kc = t & 7;
      *(ushort8*)&khi_lds[r*64 + ((kc ^ (r & 7))*8)] =
          *(const ushort8*)(khi + ((size_t)bh*1024 + k0 + r)*64 + kc*8);
      *(ushort8*)&vhi_lds[r*64 + ((kc ^ (r & 7))*8)] =
          *(const ushort8*)(vhi + ((size_t)bh*64 + r)*1024 + k0 + kc*8);
      if (!far)
        *(ushort8*)&p2c_lds[r*72 + kc*8] =
            *(const ushort8*)(p2c + ((size_t)bh*1024 + k0 + r)*64 + kc*8);
    }
    __syncthreads();

    // QK^T single product
    f32x4 sfr[4];
#pragma unroll
    for (int nf=0;nf<4;nf++) sfr[nf] = fzero();
#pragma unroll
    for (int kk=0; kk<2; kk++){
      int kc = kk*4 + lg;
#pragma unroll
      for (int nf=0; nf<4; nf++){
        int r = nf*16 + li;
        bf16x8 bh_ = *(const bf16x8*)&khi_lds[r*64 + ((kc ^ (r & 7))*8)];
        sfr[nf] = mfma16(qfh[kk], bh_, sfr[nf]);
      }
    }
    us* pl = &p_lds[w][0];
    if (far){
      const int cidx = (q0 > k0) ? 63 : 0;
      float cq[4];
#pragma unroll
      for (int j=0;j<4;j++) cq[j] = (q0 > k0) ? cq63[j] : cq0[j];
#pragma unroll
      for (int nf=0; nf<4; nf++){
        int kloc = nf*16 + li;
        bool mk = mptr[k0 + kloc] != 0;
        float ck = b2f(p2c[((size_t)bh*1024 + k0 + kloc)*64 + cidx]);
        int col = kloc;
#pragma unroll
        for (int j=0;j<4;j++){
          float p = mk ? 0.f : exp2f(fmaf(sfr[nf][j], QS2, cq[j] + ck));
          lrow[j] += p;
          int row = lg*4 + j;
          pl[row*64 + ((col & 7) | ((((col >> 3) ^ (row & 7))) << 3))] = f2bf(p);
        }
      }
    } else {
#pragma unroll
      for (int nf=0; nf<4; nf++){
        int kloc = nf*16 + li;
        bool mk = mptr[k0 + kloc] != 0;
        int col = kloc;
#pragma unroll
        for (int j=0;j<4;j++){
          int qloc = w*16 + lg*4 + j;
          int d = (q0 + qloc) - (k0 + kloc);
          int idx = (int)idx_lds[d + 1023];
          float s2 = fmaf(sfr[nf][j], QS2,
                          b2f(c2p_lds[qloc*72 + idx]) + b2f(p2c_lds[kloc*72 + idx]));
          float p = mk ? 0.f : exp2f(s2);
          lrow[j] += p;
          int row = lg*4 + j;
          pl[row*64 + ((col & 7) | ((((col >> 3) ^ (row & 7))) << 3))] = f2bf(p);
        }
      }
    }
    // PV single product (p_lds wave-private; same-wave DS ordering)
#pragma unroll
    for (int kk=0;kk<2;kk++){
      int kc = kk*4 + lg;
      bf16x8 af = *(const bf16x8*)((char*)pl + li*128 + ((kc ^ (li & 7)) * 16));
#pragma unroll
      for (int nf=0;nf<4;nf++){
        int r = nf*16 + li;
        bf16x8 bh_ = *(const bf16x8*)&vhi_lds[r*64 + ((kc ^ (r & 7))*8)];
        accO[nf] = mfma16(af, bh_, accO[nf]);
      }
    }
  }

  for (int o=1;o<16;o<<=1)
#pragma unroll
    for (int j=0;j<4;j++)
      lrow[j] += __shfl_xor(lrow[j], o);
#pragma unroll
  for (int nf=0;nf<4;nf++)
#pragma unroll
    for (int j=0;j<4;j++){
      int qloc = w*16 + lg*4 + j;
      float o = accO[nf][j] / lrow[j];
      size_t idx = ((size_t)(b*1024 + q0 + qloc))*1024 + h*64 + nf*16 + li;
      us hh,ll; split2(o,hh,ll);
      ctx_hi[idx] = hh; ctx_lo[idx] = ll;
    }
}

// ---------------- launch ----------------
extern "C" void kernel_launch(void* const* d_in, const int* in_sizes, int n_in,
                              void* d_out, int out_size, void* d_ws, size_t ws_size,
                              hipStream_t stream)
{
  (void)in_sizes; (void)n_in; (void)out_size; (void)ws_size;
  const float* query = (const float*)d_in[0];
  const float* kvst  = (const float*)d_in[1];
  const unsigned char* mask = (const unsigned char*)d_in[2];
  const float* Wq = (const float*)d_in[3];  const float* bq = (const float*)d_in[4];
  const float* Wk = (const float*)d_in[5];  const float* bk = (const float*)d_in[6];
  const float* Wv = (const float*)d_in[7];  const float* bv = (const float*)d_in[8];
  const float* Wo = (const float*)d_in[9];  const float* bo = (const float*)d_in[10];
  const float* rel = (const float*)d_in[11];
  const float* lng = (const float*)d_in[12]; const float* lnb = (const float*)d_in[13];
  const float* Wpk = (const float*)d_in[14]; const float* bpk = (const float*)d_in[15];
  const float* Wpq = (const float*)d_in[16]; const float* bpq = (const float*)d_in[17];

  char* ws = (char*)d_ws;
  const size_t MB = 1024*1024;
  // r9-proven layout (alias-safe by execution order):
  us* Xq_hi  = (us*)(ws + 0);        // [0,8)   dead after k_qkvp
  us* p2c    = (us*)(ws + 8*MB);     // [8,16)  k_cp z=1 writes (after k_qkvp)
  us* Xkv_hi = (us*)(ws + 16*MB);    // [16,24) dead after k_qkvp
  us* c2p    = (us*)(ws + 16*MB);    //         k_cp z=0 writes
  us* vtb    = (us*)(ws + 24*MB);    // [24,32) k_qkvp V writes; k_attn reads
  us* Wt     = (us*)(ws + 32*MB);    // [32,56) 6 slots x 4MB
  us* ctx_hi = (us*)(ws + 32*MB);    //         k_attn writes over Wq/Wk slots (dead)
  us* ctx_lo = (us*)(ws + 40*MB);    //         over Wv/Wpk slots (dead after k_qkvp)
  us* reln_hi = (us*)(ws + 56*MB);
  us* posk_hi = (us*)(ws + 56*MB + 256*1024);
  us* posq_hi = (us*)(ws + 56*MB + 512*1024);
  signed char* idxt = (signed char*)(ws + 56*MB + 768*1024);
  us* qbuf_hi = (us*)(ws + 57*MB);   // [57,65)
  us* kbuf_hi = (us*)(ws + 65*MB);   // [65,73)

  k_prep<<<14409, 256, 0, stream>>>(query, kvst, Wq, Wk, Wv, Wpk, Wpq, Wo,
                                    rel, lng, lnb,
                                    Xq_hi, Xkv_hi, Wt, reln_hi, idxt);

  k_qkvp<<<800, 256, 0, stream>>>(Xq_hi, Xkv_hi, Wt, bq, bk, bv,
                                  reln_hi, bpk, bpq,
                                  qbuf_hi, kbuf_hi, vtb, posk_hi, posq_hi);

  k_cp<<<dim3(16,64,2), 256, 0, stream>>>(qbuf_hi, kbuf_hi, posk_hi, posq_hi, c2p, p2c);

  k_attn<<<dim3(8,64), 512, 0, stream>>>(qbuf_hi, kbuf_hi, vtb,
                                         c2p, p2c, idxt, mask, ctx_hi, ctx_lo);

  k_gemmo<<<512, 256, 0, stream>>>(ctx_hi, ctx_lo, Wt + 5*2097152, Wt + 5*2097152 + 1048576, bo, (float*)d_out);
}

// Round 15
// 185.222 us; speedup vs baseline: 1.1498x; 1.0189x over previous
//
#include <hip/hip_runtime.h>
#include <cstdint>
#include <math.h>

typedef unsigned short us;
typedef __attribute__((ext_vector_type(8))) __bf16 bf16x8;
typedef __attribute__((ext_vector_type(8))) unsigned short ushort8;
typedef __attribute__((ext_vector_type(4))) float f32x4;

__device__ __forceinline__ us f2bf(float x){
  union { float f; unsigned int u; } v; v.f = x;
  unsigned int r = v.u + 0x7FFFu + ((v.u >> 16) & 1u);   // RNE
  return (us)(r >> 16);
}
__device__ __forceinline__ float b2f(us u){
  union { unsigned int u; float f; } v; v.u = ((unsigned int)u) << 16; return v.f;
}
__device__ __forceinline__ void split2(float x, us& hi, us& lo){
  hi = f2bf(x); lo = f2bf(x - b2f(hi));
}
__device__ __forceinline__ f32x4 fzero(){ f32x4 v; v.x=0.f; v.y=0.f; v.z=0.f; v.w=0.f; return v; }
__device__ __forceinline__ f32x4 mfma16(bf16x8 a, bf16x8 b, f32x4 c){
  return __builtin_amdgcn_mfma_f32_16x16x32_bf16(a, b, c, 0, 0, 0);
}
__device__ __forceinline__ void gload_lds16(const void* g, void* l){
  __builtin_amdgcn_global_load_lds(
      (const __attribute__((address_space(1))) unsigned int*)(uintptr_t)g,
      (__attribute__((address_space(3))) unsigned int*)(uintptr_t)l,
      16, 0, 0);
}

// exp2-folded scales
#define QS2 (0.07216878364870322f * 1.4426950408889634f)   // 1/sqrt(192) * log2(e)
#define BS  (0.08838834764831845f * 1.4426950408889634f)   // 1/sqrt(128) * log2(e)

// ---------------- 1: fused prep: convx | convw | lnrel | bucket ----------------
__global__ __launch_bounds__(256) void k_prep(const float* __restrict__ xq,
                                              const float* __restrict__ xkv,
                                              const float* __restrict__ w0, const float* __restrict__ w1,
                                              const float* __restrict__ w2, const float* __restrict__ w3,
                                              const float* __restrict__ w4, const float* __restrict__ w5,
                                              const float* __restrict__ rel,
                                              const float* __restrict__ g, const float* __restrict__ bLN,
                                              us* __restrict__ qhi, us* __restrict__ kvhi,
                                              us* __restrict__ wt, us* __restrict__ reln_hi,
                                              signed char* __restrict__ idxt)
{
  __shared__ float tile[32][33];
  __shared__ float sm[8];
  const int bid = blockIdx.x, t = threadIdx.x;

  if (bid < 8192){                      // ---- convx (hi only)
    int i = bid * 256 + t;
    const float* src; us* dh;
    if (i < 1048576){ src = xq  + (size_t)i*4;           dh = qhi  + (size_t)i*4; }
    else            { src = xkv + (size_t)(i-1048576)*4; dh = kvhi + (size_t)(i-1048576)*4; }
    f32x4 v = *(const f32x4*)src;
    dh[0]=f2bf(v.x); dh[1]=f2bf(v.y); dh[2]=f2bf(v.z); dh[3]=f2bf(v.w);
    return;
  }
  if (bid < 14336){                     // ---- convw: transpose + hi/lo split
    int rem = bid - 8192;
    int z = rem >> 10, r2 = rem & 1023;
    const float* W = (z==0)?w0:(z==1)?w1:(z==2)?w2:(z==3)?w3:(z==4)?w4:w5;
    us* dst_hi = wt + (size_t)z * 2097152;
    us* dst_lo = dst_hi + 1048576;
    bool wlo = (z == 2) || (z == 5);
    int n0 = (r2 & 31) * 32, k0 = (r2 >> 5) * 32;
    int c = t & 31, r = t >> 5;
#pragma unroll
    for (int i = 0; i < 4; i++)
      tile[r + i*8][c] = W[(size_t)(k0 + r + i*8)*1024 + n0 + c];
    __syncthreads();
#pragma unroll
    for (int i = 0; i < 4; i++){
      int nn = r + i*8;
      us h,l; split2(tile[c][nn], h, l);
      dst_hi[(size_t)(n0 + nn)*1024 + k0 + c] = h;
      if (wlo) dst_lo[(size_t)(n0 + nn)*1024 + k0 + c] = l;
    }
    return;
  }
  if (bid < 14400){                     // ---- lnrel
    int row = bid - 14336;
    const float* x = rel + (size_t)row * 1024;
    float v[4]; float s = 0.f, ss = 0.f;
#pragma unroll
    for (int i=0;i<4;i++){ v[i] = x[t + 256*i]; s += v[i]; ss += v[i]*v[i]; }
    for (int o=32;o;o>>=1){ s += __shfl_xor(s,o); ss += __shfl_xor(ss,o); }
    int w = t >> 6;
    if ((t & 63) == 0){ sm[w] = s; sm[4+w] = ss; }
    __syncthreads();
    s  = sm[0]+sm[1]+sm[2]+sm[3];
    ss = sm[4]+sm[5]+sm[6]+sm[7];
    float mu  = s  * (1.0f/1024.0f);
    float var = ss * (1.0f/1024.0f) - mu*mu;
    float rs  = rsqrtf(var + 1e-5f);
#pragma unroll
    for (int i=0;i<4;i++){
      int cc = t + 256*i;
      reln_hi[(size_t)row*1024 + cc] = f2bf((v[i]-mu)*rs*g[cc] + bLN[cc]);
    }
    return;
  }
  {                                     // ---- bucket table
    int i = (bid - 14400) * 256 + t;
    if (i >= 2052) return;
    int d = i - 1023;
    int ad = d < 0 ? -d : d;
    int abspos = (d < 16 && d > -16) ? 15 : ad;
    int bucket;
    if (abspos <= 16) bucket = d;
    else {
      float num = (float)log((double)abspos * 0.0625);
      float den = (float)log(7.9375);
      float lp = ceilf(num / den * 15.0f) + 16.0f;
      bucket = (int)lp * (d > 0 ? 1 : -1);
    }
    int s = bucket + 32;
    s = s < 0 ? 0 : (s > 63 ? 63 : s);
    idxt[i] = (signed char)s;
  }
}

// ---------------- 2: merged QKV GEMM + pos projections, grid=800 ----------------
// bids [0,32): pos_k/pos_q (short, finish early)
// bids [32,288): Q BM=128/BN=128 NKT=32 -> qbuf
// bids [288,544): K same -> kbuf
// bids [544,800): V BM=128/BN=128, 32 iters, fused hi+lo (32 MFMA/interval) -> vtb
__global__ __launch_bounds__(256) void k_qkvp(const us* __restrict__ Xq, const us* __restrict__ Xkv,
                                              const us* __restrict__ wt,
                                              const float* __restrict__ bq, const float* __restrict__ bk,
                                              const float* __restrict__ bv,
                                              const us* __restrict__ reln_hi,
                                              const float* __restrict__ bpk, const float* __restrict__ bpq,
                                              us* __restrict__ qbuf, us* __restrict__ kbuf,
                                              us* __restrict__ vtb,
                                              us* __restrict__ posk_hi, us* __restrict__ posq_hi)
{
  __shared__ __align__(16) us a_lds[2][4096];   // 128 x 32
  __shared__ __align__(16) us b_lds[2][8192];   // Q/K: first 4096 used ; V: hi [0,4096) + lo [4096,8192)
  const int bid = blockIdx.x;
  const int t = threadIdx.x, w = t >> 6, lane = t & 63, lg = lane >> 4, li = lane & 15;

  if (bid < 32){                        // ---- pos projections
    int ntile = bid & 15, z = bid >> 4;
    const us* W_hi = wt + (size_t)(3 + z) * 2097152;
    const float* bias = z ? bpq : bpk;
    us* out_hi = z ? posq_hi : posk_hi;
    f32x4 acc[4];
#pragma unroll
    for (int i=0;i<4;i++) acc[i] = fzero();
    int srow = w*16 + li;
    for (int kt = 0; kt < 32; kt++){
      int k0 = kt*32 + lg*8;
      bf16x8 a = *(const bf16x8*)(reln_hi + (size_t)srow*1024 + k0);
#pragma unroll
      for (int nf=0; nf<4; nf++){
        int n = ntile*64 + nf*16 + li;
        bf16x8 b = *(const bf16x8*)(W_hi + (size_t)n*1024 + k0);
        acc[nf] = mfma16(a, b, acc[nf]);
      }
    }
#pragma unroll
    for (int nf=0;nf<4;nf++){
      int n = ntile*64 + nf*16 + li;
      float bn = bias[n];
      int h = n >> 6, hd = n & 63;
#pragma unroll
      for (int j=0;j<4;j++){
        int s = w*16 + lg*4 + j;
        out_hi[(size_t)h*4096 + s*64 + hd] = f2bf(acc[nf][j] + bn);
      }
    }
    return;
  }

  if (bid < 544){                       // ---- Q / K classes (proven geometry)
    int cls = (bid - 32) >> 8;          // 0:Q 1:K
    int u = (bid - 32) & 255;
    int tile = (u & 7) * 32 + (u >> 3); // XCD-contiguous chunk within class
    int mt = tile >> 3, nt = tile & 7;
    int m0 = mt * 128, n0 = nt * 128;
    const us* A  = cls ? Xkv : Xq;
    const us* Bp = wt + (size_t)cls * 2097152;
    const float* bias = cls ? bk : bq;
    us* out = cls ? kbuf : qbuf;
    int wm = w >> 1, wn = w & 1;
    f32x4 acc[4][4];
#pragma unroll
    for (int i=0;i<4;i++)
#pragma unroll
      for (int j=0;j<4;j++) acc[i][j] = fzero();

    auto stage = [&](int buf, int kt){
      int k0 = kt * 32;
#pragma unroll
      for (int c = 0; c < 2; c++){
        int slot = c*256 + t;
        int g = slot ^ ((slot >> 3) & 7);
        int r = g >> 2, kc = g & 3;
        gload_lds16(A  + (size_t)(m0 + r)*1024 + k0 + kc*8, (char*)&a_lds[buf][0] + slot*16);
        gload_lds16(Bp + (size_t)(n0 + r)*1024 + k0 + kc*8, (char*)&b_lds[buf][0] + slot*16);
      }
    };

    stage(0, 0);
    __syncthreads();
    int buf = 0;
    for (int kt = 0; kt < 32; kt++){
      if (kt + 1 < 32) stage(buf ^ 1, kt + 1);
      bf16x8 af[4], bfv[4];
#pragma unroll
      for (int mi=0;mi<4;mi++){
        int r = wm*64 + mi*16 + li;
        int s = (r*4 + lg); s ^= ((s >> 3) & 7);
        af[mi] = *(const bf16x8*)((char*)&a_lds[buf][0] + s*16);
      }
#pragma unroll
      for (int ni=0;ni<4;ni++){
        int r = wn*64 + ni*16 + li;
        int s = (r*4 + lg); s ^= ((s >> 3) & 7);
        bfv[ni] = *(const bf16x8*)((char*)&b_lds[buf][0] + s*16);
      }
#pragma unroll
      for (int mi=0;mi<4;mi++)
#pragma unroll
        for (int ni=0;ni<4;ni++)
          acc[mi][ni] = mfma16(af[mi], bfv[ni], acc[mi][ni]);
      __syncthreads();
      buf ^= 1;
    }

#pragma unroll
    for (int ni=0;ni<4;ni++){
      int n = n0 + wn*64 + ni*16 + li;
      float bn = bias[n];
      int hh = n >> 6, hd = n & 63;
#pragma unroll
      for (int mi=0;mi<4;mi++){
        int mb = m0 + wm*64 + mi*16 + lg*4;
#pragma unroll
        for (int j=0;j<4;j++){
          int m = mb + j;
          int bb = m >> 10, tp = m & 1023;
          out[(((size_t)(bb*16 + hh))*1024 + tp)*64 + hd] = f2bf(acc[mi][ni][j] + bn);
        }
      }
    }
    return;
  }

  // ---- V class: BM=128, BN=128, 32 iters, fused hi+lo (32 MFMA/interval), 256 blocks
  {
    int u = bid - 544;
    int tile = (u & 7) * 32 + (u >> 3);
    int mt = tile >> 3, nt = tile & 7;
    int m0 = mt * 128, n0 = nt * 128;
    const us* Bh = wt + (size_t)2 * 2097152;
    const us* Bl = Bh + 1048576;
    int wm = w >> 1, wn = w & 1;
    f32x4 acc[4][4];
#pragma unroll
    for (int i=0;i<4;i++)
#pragma unroll
      for (int j=0;j<4;j++) acc[i][j] = fzero();

    auto stage = [&](int buf, int kt){
      int k0 = kt * 32;
#pragma unroll
      for (int c = 0; c < 2; c++){
        int slot = c*256 + t;
        int g = slot ^ ((slot >> 3) & 7);
        int r = g >> 2, kc = g & 3;
        gload_lds16(Xkv + (size_t)(m0 + r)*1024 + k0 + kc*8, (char*)&a_lds[buf][0] + slot*16);
        gload_lds16(Bh  + (size_t)(n0 + r)*1024 + k0 + kc*8, (char*)&b_lds[buf][0] + slot*16);
        gload_lds16(Bl  + (size_t)(n0 + r)*1024 + k0 + kc*8, (char*)&b_lds[buf][0] + 8192 + slot*16);
      }
    };

    stage(0, 0);
    __syncthreads();
    int buf = 0;
    for (int kt = 0; kt < 32; kt++){
      if (kt + 1 < 32) stage(buf ^ 1, kt + 1);
      bf16x8 af[4], bh_[4], bl_[4];
#pragma unroll
      for (int mi=0;mi<4;mi++){
        int r = wm*64 + mi*16 + li;
        int s = (r*4 + lg); s ^= ((s >> 3) & 7);
        af[mi] = *(const bf16x8*)((char*)&a_lds[buf][0] + s*16);
      }
#pragma unroll
      for (int ni=0;ni<4;ni++){
        int r = wn*64 + ni*16 + li;
        int s = (r*4 + lg); s ^= ((s >> 3) & 7);
        bh_[ni] = *(const bf16x8*)((char*)&b_lds[buf][0] + s*16);
        bl_[ni] = *(const bf16x8*)((char*)&b_lds[buf][0] + 8192 + s*16);
      }
#pragma unroll
      for (int mi=0;mi<4;mi++)
#pragma unroll
        for (int ni=0;ni<4;ni++){
          acc[mi][ni] = mfma16(af[mi], bh_[ni], acc[mi][ni]);
          acc[mi][ni] = mfma16(af[mi], bl_[ni], acc[mi][ni]);
        }
      __syncthreads();
      buf ^= 1;
    }

#pragma unroll
    for (int ni=0;ni<4;ni++){
      int n = n0 + wn*64 + ni*16 + li;
      float bn = bv[n];
      int hh = n >> 6, hd = n & 63;
#pragma unroll
      for (int mi=0;mi<4;mi++){
        int mb = m0 + wm*64 + mi*16 + lg*4;
#pragma unroll
        for (int j=0;j<4;j++){
          int m = mb + j;
          int bb = m >> 10, tp = m & 1023;
          vtb[(((size_t)(bb*16 + hh))*64 + hd)*1024 + tp] = f2bf(acc[mi][ni][j] + bn);
        }
      }
    }
  }
}

// ---------------- 3: O GEMM: 3 products, BM=128, BN=64, fp32 out ----------------
__global__ __launch_bounds__(256, 2) void k_gemmo(const us* __restrict__ A_hi, const us* __restrict__ A_lo,
                                                  const us* __restrict__ B_hi, const us* __restrict__ B_lo,
                                                  const float* __restrict__ bias,
                                                  float* __restrict__ out_f)
{
  __shared__ __align__(16) us a_lds[2][4096];
  __shared__ __align__(16) us b_lds[2][2048];
  int bid = blockIdx.x;
  int wg = (bid & 7) * 64 + (bid >> 3);        // 512 % 8 == 0
  int mt = wg >> 4, nt = wg & 15;
  int m0 = mt * 128, n0 = nt * 64;
  int t = threadIdx.x, w = t >> 6, lane = t & 63, lg = lane >> 4, li = lane & 15;
  int wm = w >> 1, wn = w & 1;
  f32x4 acc[4][2];
#pragma unroll
  for (int i=0;i<4;i++){ acc[i][0]=fzero(); acc[i][1]=fzero(); }

  auto stage = [&](int buf, int kt){
    int seg = kt >> 5, k0 = (kt & 31) * 32;
    const us* Ap = (seg == 2) ? A_lo : A_hi;
    const us* Bp = (seg == 1) ? B_lo : B_hi;
#pragma unroll
    for (int c = 0; c < 2; c++){
      int slot = c*256 + t;
      int g = slot ^ ((slot >> 3) & 7);
      int r = g >> 2, kc = g & 3;
      gload_lds16(Ap + (size_t)(m0 + r)*1024 + k0 + kc*8, (char*)&a_lds[buf][0] + slot*16);
    }
    {
      int slot = t;
      int g = slot ^ ((slot >> 3) & 7);
      int r = g >> 2, kc = g & 3;
      gload_lds16(Bp + (size_t)(n0 + r)*1024 + k0 + kc*8, (char*)&b_lds[buf][0] + slot*16);
    }
  };

  stage(0, 0);
  __syncthreads();
  int buf = 0;
  for (int kt = 0; kt < 96; kt++){
    if (kt + 1 < 96) stage(buf ^ 1, kt + 1);
    bf16x8 af[4], bfv[2];
#pragma unroll
    for (int mi=0;mi<4;mi++){
      int r = wm*64 + mi*16 + li;
      int s = (r*4 + lg); s ^= ((s >> 3) & 7);
      af[mi] = *(const bf16x8*)((char*)&a_lds[buf][0] + s*16);
    }
#pragma unroll
    for (int ni=0;ni<2;ni++){
      int r = wn*32 + ni*16 + li;
      int s = (r*4 + lg); s ^= ((s >> 3) & 7);
      bfv[ni] = *(const bf16x8*)((char*)&b_lds[buf][0] + s*16);
    }
#pragma unroll
    for (int mi=0;mi<4;mi++)
#pragma unroll
      for (int ni=0;ni<2;ni++)
        acc[mi][ni] = mfma16(af[mi], bfv[ni], acc[mi][ni]);
    __syncthreads();
    buf ^= 1;
  }

#pragma unroll
  for (int ni=0;ni<2;ni++){
    int n = n0 + wn*32 + ni*16 + li;
    float bn = bias[n];
#pragma unroll
    for (int mi=0;mi<4;mi++){
      int mb = m0 + wm*64 + mi*16 + lg*4;
#pragma unroll
      for (int j=0;j<4;j++)
        out_f[(size_t)(mb + j)*1024 + n] = acc[mi][ni][j] + bn;
    }
  }
}

// ---------------- 4: c2p/p2c (single product, pre-scaled by BS for exp2) ----------------
__global__ __launch_bounds__(256) void k_cp(const us* __restrict__ q_hi,
                                            const us* __restrict__ k_hi,
                                            const us* __restrict__ pk_hi,
                                            const us* __restrict__ pq_hi,
                                            us* __restrict__ c2p, us* __restrict__ p2c)
{
  int qt = blockIdx.x, bh = blockIdx.y, z = blockIdx.z;
  const us* X_hi = z ? k_hi : q_hi;
  const us* P_hi = z ? pq_hi : pk_hi;
  us* out = z ? p2c : c2p;
  int h = bh & 15;
  int t = threadIdx.x, w = t >> 6, lane = t & 63, lg = lane >> 4, li = lane & 15;
  f32x4 acc[4];
#pragma unroll
  for (int i=0;i<4;i++) acc[i] = fzero();
  size_t row = (size_t)bh*1024 + qt*64 + w*16 + li;
#pragma unroll
  for (int kk=0;kk<2;kk++){
    int k = kk*32 + lg*8;
    bf16x8 ah = *(const bf16x8*)(X_hi + row*64 + k);
#pragma unroll
    for (int nf=0;nf<4;nf++){
      int s = nf*16 + li;
      bf16x8 bh_ = *(const bf16x8*)(P_hi + (size_t)h*4096 + s*64 + k);
      acc[nf] = mfma16(ah, bh_, acc[nf]);
    }
  }
  size_t obase = ((size_t)bh*1024 + qt*64 + w*16 + lg*4) * 64;
#pragma unroll
  for (int nf=0;nf<4;nf++)
#pragma unroll
    for (int j=0;j<4;j++)
      out[obase + (size_t)j*64 + nf*16 + li] = f2bf(acc[nf][j] * BS);
}

// ---------------- 5: fused attention: 8 waves, QBLK=128, bh-pinned XCD swizzle ----------------
// grid = 512 (1D): bid = (bh&7) + 8*(qt + 8*(bh>>3)) -> XCD = bh&7; all 8 qt of a bh share one XCD's L2.
__global__ __launch_bounds__(512) void k_attn(const us* __restrict__ qhi,
                                              const us* __restrict__ khi,
                                              const us* __restrict__ vhi,
                                              const us* __restrict__ c2p, const us* __restrict__ p2c,
                                              const signed char* __restrict__ idxt,
                                              const unsigned char* __restrict__ mask,
                                              us* __restrict__ ctx_hi, us* __restrict__ ctx_lo)
{
  __shared__ __align__(16) us khi_lds[4096], vhi_lds[4096];
  __shared__ __align__(16) us c2p_lds[128*72], p2c_lds[64*72];   // padded rows: 144B stride
  __shared__ __align__(16) us p_lds[8][1024];
  __shared__ signed char idx_lds[2048];

  const int bid = blockIdx.x;
  const int xg = bid & 7, rest = bid >> 3;
  const int qt = rest & 7;
  const int bh = xg + ((rest >> 3) << 3);
  const int b = bh >> 4, h = bh & 15;
  const int t = threadIdx.x, w = t >> 6, lane = t & 63, lg = lane >> 4, li = lane & 15;
  const int q0 = qt * 128;

  for (int i = t; i < 2047; i += 512) idx_lds[i] = idxt[i];
  {
    const us* src = c2p + ((size_t)bh*1024 + q0) * 64;
#pragma unroll
    for (int c = 0; c < 2; c++){
      int f = c*512 + t, r = f >> 3, kc = f & 7;
      *(ushort8*)&c2p_lds[r*72 + kc*8] = *(const ushort8*)(src + r*64 + kc*8);
    }
  }
  bf16x8 qfh[2];
  {
    const us* qph = qhi + ((size_t)bh*1024 + q0 + w*16 + li)*64 + lg*8;
    qfh[0] = *(const bf16x8*)(qph); qfh[1] = *(const bf16x8*)(qph + 32);
  }
  __syncthreads();
  // far-path per-row bias (scaled) for idx=0 / idx=63
  float cq0[4], cq63[4];
#pragma unroll
  for (int j=0;j<4;j++){
    int qloc = w*16 + lg*4 + j;
    cq0[j]  = b2f(c2p_lds[qloc*72 + 0]);
    cq63[j] = b2f(c2p_lds[qloc*72 + 63]);
  }

  float lrow[4];
  f32x4 accO[4];
#pragma unroll
  for (int j=0;j<4;j++){ lrow[j] = 0.f; accO[j] = fzero(); }
  const unsigned char* mptr = mask + b*1024;

  for (int kt = 0; kt < 16; kt++){
    const int k0 = kt * 64;
    const bool far = (q0 - k0 >= 192) || (k0 - q0 >= 256);
    __syncthreads();
    {  // stage K,V: one 16B chunk each per thread
      int r = t >> 3, kc = t & 7;
      *(ushort8*)&khi_lds[r*64 + ((kc ^ (r & 7))*8)] =
          *(const ushort8*)(khi + ((size_t)bh*1024 + k0 + r)*64 + kc*8);
      *(ushort8*)&vhi_lds[r*64 + ((kc ^ (r & 7))*8)] =
          *(const ushort8*)(vhi + ((size_t)bh*64 + r)*1024 + k0 + kc*8);
      if (!far)
        *(ushort8*)&p2c_lds[r*72 + kc*8] =
            *(const ushort8*)(p2c + ((size_t)bh*1024 + k0 + r)*64 + kc*8);
    }
    __syncthreads();

    // QK^T single product
    f32x4 sfr[4];
#pragma unroll
    for (int nf=0;nf<4;nf++) sfr[nf] = fzero();
#pragma unroll
    for (int kk=0; kk<2; kk++){
      int kc = kk*4 + lg;
#pragma unroll
      for (int nf=0; nf<4; nf++){
        int r = nf*16 + li;
        bf16x8 bh_ = *(const bf16x8*)&khi_lds[r*64 + ((kc ^ (r & 7))*8)];
        sfr[nf] = mfma16(qfh[kk], bh_, sfr[nf]);
      }
    }
    us* pl = &p_lds[w][0];
    if (far){
      const int cidx = (q0 > k0) ? 63 : 0;
      float cq[4];
#pragma unroll
      for (int j=0;j<4;j++) cq[j] = (q0 > k0) ? cq63[j] : cq0[j];
#pragma unroll
      for (int nf=0; nf<4; nf++){
        int kloc = nf*16 + li;
        bool mk = mptr[k0 + kloc] != 0;
        float ck = b2f(p2c[((size_t)bh*1024 + k0 + kloc)*64 + cidx]);
        int col = kloc;
#pragma unroll
        for (int j=0;j<4;j++){
          float p = mk ? 0.f : exp2f(fmaf(sfr[nf][j], QS2, cq[j] + ck));
          lrow[j] += p;
          int row = lg*4 + j;
          pl[row*64 + ((col & 7) | ((((col >> 3) ^ (row & 7))) << 3))] = f2bf(p);
        }
      }
    } else {
#pragma unroll
      for (int nf=0; nf<4; nf++){
        int kloc = nf*16 + li;
        bool mk = mptr[k0 + kloc] != 0;
        int col = kloc;
#pragma unroll
        for (int j=0;j<4;j++){
          int qloc = w*16 + lg*4 + j;
          int d = (q0 + qloc) - (k0 + kloc);
          int idx = (int)idx_lds[d + 1023];
          float s2 = fmaf(sfr[nf][j], QS2,
                          b2f(c2p_lds[qloc*72 + idx]) + b2f(p2c_lds[kloc*72 + idx]));
          float p = mk ? 0.f : exp2f(s2);
          lrow[j] += p;
          int row = lg*4 + j;
          pl[row*64 + ((col & 7) | ((((col >> 3) ^ (row & 7))) << 3))] = f2bf(p);
        }
      }
    }
    // PV single product (p_lds wave-private; same-wave DS ordering)
#pragma unroll
    for (int kk=0;kk<2;kk++){
      int kc = kk*4 + lg;
      bf16x8 af = *(const bf16x8*)((char*)pl + li*128 + ((kc ^ (li & 7)) * 16));
#pragma unroll
      for (int nf=0;nf<4;nf++){
        int r = nf*16 + li;
        bf16x8 bh_ = *(const bf16x8*)&vhi_lds[r*64 + ((kc ^ (r & 7))*8)];
        accO[nf] = mfma16(af, bh_, accO[nf]);
      }
    }
  }

  for (int o=1;o<16;o<<=1)
#pragma unroll
    for (int j=0;j<4;j++)
      lrow[j] += __shfl_xor(lrow[j], o);
#pragma unroll
  for (int nf=0;nf<4;nf++)
#pragma unroll
    for (int j=0;j<4;j++){
      int qloc = w*16 + lg*4 + j;
      float o = accO[nf][j] / lrow[j];
      size_t idx = ((size_t)(b*1024 + q0 + qloc))*1024 + h*64 + nf*16 + li;
      us hh,ll; split2(o,hh,ll);
      ctx_hi[idx] = hh; ctx_lo[idx] = ll;
    }
}

// ---------------- launch ----------------
extern "C" void kernel_launch(void* const* d_in, const int* in_sizes, int n_in,
                              void* d_out, int out_size, void* d_ws, size_t ws_size,
                              hipStream_t stream)
{
  (void)in_sizes; (void)n_in; (void)out_size; (void)ws_size;
  const float* query = (const float*)d_in[0];
  const float* kvst  = (const float*)d_in[1];
  const unsigned char* mask = (const unsigned char*)d_in[2];
  const float* Wq = (const float*)d_in[3];  const float* bq = (const float*)d_in[4];
  const float* Wk = (const float*)d_in[5];  const float* bk = (const float*)d_in[6];
  const float* Wv = (const float*)d_in[7];  const float* bv = (const float*)d_in[8];
  const float* Wo = (const float*)d_in[9];  const float* bo = (const float*)d_in[10];
  const float* rel = (const float*)d_in[11];
  const float* lng = (const float*)d_in[12]; const float* lnb = (const float*)d_in[13];
  const float* Wpk = (const float*)d_in[14]; const float* bpk = (const float*)d_in[15];
  const float* Wpq = (const float*)d_in[16]; const float* bpq = (const float*)d_in[17];

  char* ws = (char*)d_ws;
  const size_t MB = 1024*1024;
  // r9-proven layout (alias-safe by execution order):
  us* Xq_hi  = (us*)(ws + 0);        // [0,8)   dead after k_qkvp
  us* p2c    = (us*)(ws + 8*MB);     // [8,16)  k_cp z=1 writes (after k_qkvp)
  us* Xkv_hi = (us*)(ws + 16*MB);    // [16,24) dead after k_qkvp
  us* c2p    = (us*)(ws + 16*MB);    //         k_cp z=0 writes
  us* vtb    = (us*)(ws + 24*MB);    // [24,32) k_qkvp V writes; k_attn reads
  us* Wt     = (us*)(ws + 32*MB);    // [32,56) 6 slots x 4MB
  us* ctx_hi = (us*)(ws + 32*MB);    //         k_attn writes over Wq/Wk slots (dead)
  us* ctx_lo = (us*)(ws + 40*MB);    //         over Wv/Wpk slots (dead after k_qkvp)
  us* reln_hi = (us*)(ws + 56*MB);
  us* posk_hi = (us*)(ws + 56*MB + 256*1024);
  us* posq_hi = (us*)(ws + 56*MB + 512*1024);
  signed char* idxt = (signed char*)(ws + 56*MB + 768*1024);
  us* qbuf_hi = (us*)(ws + 57*MB);   // [57,65)
  us* kbuf_hi = (us*)(ws + 65*MB);   // [65,73)

  k_prep<<<14409, 256, 0, stream>>>(query, kvst, Wq, Wk, Wv, Wpk, Wpq, Wo,
                                    rel, lng, lnb,
                                    Xq_hi, Xkv_hi, Wt, reln_hi, idxt);

  k_qkvp<<<800, 256, 0, stream>>>(Xq_hi, Xkv_hi, Wt, bq, bk, bv,
                                  reln_hi, bpk, bpq,
                                  qbuf_hi, kbuf_hi, vtb, posk_hi, posq_hi);

  k_cp<<<dim3(16,64,2), 256, 0, stream>>>(qbuf_hi, kbuf_hi, posk_hi, posq_hi, c2p, p2c);

  k_attn<<<512, 512, 0, stream>>>(qbuf_hi, kbuf_hi, vtb,
                                  c2p, p2c, idxt, mask, ctx_hi, ctx_lo);

  k_gemmo<<<512, 256, 0, stream>>>(ctx_hi, ctx_lo, Wt + 5*2097152, Wt + 5*2097152 + 1048576, bo, (float*)d_out);
}

// Round 16
// 169.130 us; speedup vs baseline: 1.2592x; 1.0951x over previous
//
#include <hip/hip_runtime.h>
#include <cstdint>
#include <math.h>

typedef unsigned short us;
typedef __attribute__((ext_vector_type(8))) __bf16 bf16x8;
typedef __attribute__((ext_vector_type(8))) unsigned short ushort8;
typedef __attribute__((ext_vector_type(4))) float f32x4;

__device__ __forceinline__ us f2bf(float x){
  union { float f; unsigned int u; } v; v.f = x;
  unsigned int r = v.u + 0x7FFFu + ((v.u >> 16) & 1u);   // RNE
  return (us)(r >> 16);
}
__device__ __forceinline__ float b2f(us u){
  union { unsigned int u; float f; } v; v.u = ((unsigned int)u) << 16; return v.f;
}
__device__ __forceinline__ void split2(float x, us& hi, us& lo){
  hi = f2bf(x); lo = f2bf(x - b2f(hi));
}
__device__ __forceinline__ f32x4 fzero(){ f32x4 v; v.x=0.f; v.y=0.f; v.z=0.f; v.w=0.f; return v; }
__device__ __forceinline__ f32x4 mfma16(bf16x8 a, bf16x8 b, f32x4 c){
  return __builtin_amdgcn_mfma_f32_16x16x32_bf16(a, b, c, 0, 0, 0);
}
__device__ __forceinline__ void gload_lds16(const void* g, void* l){
  __builtin_amdgcn_global_load_lds(
      (const __attribute__((address_space(1))) unsigned int*)(uintptr_t)g,
      (__attribute__((address_space(3))) unsigned int*)(uintptr_t)l,
      16, 0, 0);
}

// exp2-folded scales
#define QS2 (0.07216878364870322f * 1.4426950408889634f)   // 1/sqrt(192) * log2(e)
#define BS  (0.08838834764831845f * 1.4426950408889634f)   // 1/sqrt(128) * log2(e)

// ---------------- 1: fused prep: convx | convw | lnrel | bucket ----------------
__global__ __launch_bounds__(256) void k_prep(const float* __restrict__ xq,
                                              const float* __restrict__ xkv,
                                              const float* __restrict__ w0, const float* __restrict__ w1,
                                              const float* __restrict__ w2, const float* __restrict__ w3,
                                              const float* __restrict__ w4, const float* __restrict__ w5,
                                              const float* __restrict__ rel,
                                              const float* __restrict__ g, const float* __restrict__ bLN,
                                              us* __restrict__ qhi, us* __restrict__ kvhi,
                                              us* __restrict__ wt, us* __restrict__ reln_hi,
                                              signed char* __restrict__ idxt)
{
  __shared__ float tile[32][33];
  __shared__ float sm[8];
  const int bid = blockIdx.x, t = threadIdx.x;

  if (bid < 8192){                      // ---- convx (hi only)
    int i = bid * 256 + t;
    const float* src; us* dh;
    if (i < 1048576){ src = xq  + (size_t)i*4;           dh = qhi  + (size_t)i*4; }
    else            { src = xkv + (size_t)(i-1048576)*4; dh = kvhi + (size_t)(i-1048576)*4; }
    f32x4 v = *(const f32x4*)src;
    dh[0]=f2bf(v.x); dh[1]=f2bf(v.y); dh[2]=f2bf(v.z); dh[3]=f2bf(v.w);
    return;
  }
  if (bid < 14336){                     // ---- convw: transpose + hi/lo split
    int rem = bid - 8192;
    int z = rem >> 10, r2 = rem & 1023;
    const float* W = (z==0)?w0:(z==1)?w1:(z==2)?w2:(z==3)?w3:(z==4)?w4:w5;
    us* dst_hi = wt + (size_t)z * 2097152;
    us* dst_lo = dst_hi + 1048576;
    bool wlo = (z == 2) || (z == 5);
    int n0 = (r2 & 31) * 32, k0 = (r2 >> 5) * 32;
    int c = t & 31, r = t >> 5;
#pragma unroll
    for (int i = 0; i < 4; i++)
      tile[r + i*8][c] = W[(size_t)(k0 + r + i*8)*1024 + n0 + c];
    __syncthreads();
#pragma unroll
    for (int i = 0; i < 4; i++){
      int nn = r + i*8;
      us h,l; split2(tile[c][nn], h, l);
      dst_hi[(size_t)(n0 + nn)*1024 + k0 + c] = h;
      if (wlo) dst_lo[(size_t)(n0 + nn)*1024 + k0 + c] = l;
    }
    return;
  }
  if (bid < 14400){                     // ---- lnrel
    int row = bid - 14336;
    const float* x = rel + (size_t)row * 1024;
    float v[4]; float s = 0.f, ss = 0.f;
#pragma unroll
    for (int i=0;i<4;i++){ v[i] = x[t + 256*i]; s += v[i]; ss += v[i]*v[i]; }
    for (int o=32;o;o>>=1){ s += __shfl_xor(s,o); ss += __shfl_xor(ss,o); }
    int w = t >> 6;
    if ((t & 63) == 0){ sm[w] = s; sm[4+w] = ss; }
    __syncthreads();
    s  = sm[0]+sm[1]+sm[2]+sm[3];
    ss = sm[4]+sm[5]+sm[6]+sm[7];
    float mu  = s  * (1.0f/1024.0f);
    float var = ss * (1.0f/1024.0f) - mu*mu;
    float rs  = rsqrtf(var + 1e-5f);
#pragma unroll
    for (int i=0;i<4;i++){
      int cc = t + 256*i;
      reln_hi[(size_t)row*1024 + cc] = f2bf((v[i]-mu)*rs*g[cc] + bLN[cc]);
    }
    return;
  }
  {                                     // ---- bucket table
    int i = (bid - 14400) * 256 + t;
    if (i >= 2052) return;
    int d = i - 1023;
    int ad = d < 0 ? -d : d;
    int abspos = (d < 16 && d > -16) ? 15 : ad;
    int bucket;
    if (abspos <= 16) bucket = d;
    else {
      float num = (float)log((double)abspos * 0.0625);
      float den = (float)log(7.9375);
      float lp = ceilf(num / den * 15.0f) + 16.0f;
      bucket = (int)lp * (d > 0 ? 1 : -1);
    }
    int s = bucket + 32;
    s = s < 0 ? 0 : (s > 63 ? 63 : s);
    idxt[i] = (signed char)s;
  }
}

// ---------------- 2: merged QKV GEMM + pos projections, grid=800 ----------------
__global__ __launch_bounds__(256) void k_qkvp(const us* __restrict__ Xq, const us* __restrict__ Xkv,
                                              const us* __restrict__ wt,
                                              const float* __restrict__ bq, const float* __restrict__ bk,
                                              const float* __restrict__ bv,
                                              const us* __restrict__ reln_hi,
                                              const float* __restrict__ bpk, const float* __restrict__ bpq,
                                              us* __restrict__ qbuf, us* __restrict__ kbuf,
                                              us* __restrict__ vtb,
                                              us* __restrict__ posk_hi, us* __restrict__ posq_hi)
{
  __shared__ __align__(16) us a_lds[2][4096];   // 128 x 32
  __shared__ __align__(16) us b_lds[2][8192];   // Q/K: first 4096 used ; V: hi [0,4096) + lo [4096,8192)
  const int bid = blockIdx.x;
  const int t = threadIdx.x, w = t >> 6, lane = t & 63, lg = lane >> 4, li = lane & 15;

  if (bid < 32){                        // ---- pos projections
    int ntile = bid & 15, z = bid >> 4;
    const us* W_hi = wt + (size_t)(3 + z) * 2097152;
    const float* bias = z ? bpq : bpk;
    us* out_hi = z ? posq_hi : posk_hi;
    f32x4 acc[4];
#pragma unroll
    for (int i=0;i<4;i++) acc[i] = fzero();
    int srow = w*16 + li;
    for (int kt = 0; kt < 32; kt++){
      int k0 = kt*32 + lg*8;
      bf16x8 a = *(const bf16x8*)(reln_hi + (size_t)srow*1024 + k0);
#pragma unroll
      for (int nf=0; nf<4; nf++){
        int n = ntile*64 + nf*16 + li;
        bf16x8 b = *(const bf16x8*)(W_hi + (size_t)n*1024 + k0);
        acc[nf] = mfma16(a, b, acc[nf]);
      }
    }
#pragma unroll
    for (int nf=0;nf<4;nf++){
      int n = ntile*64 + nf*16 + li;
      float bn = bias[n];
      int h = n >> 6, hd = n & 63;
#pragma unroll
      for (int j=0;j<4;j++){
        int s = w*16 + lg*4 + j;
        out_hi[(size_t)h*4096 + s*64 + hd] = f2bf(acc[nf][j] + bn);
      }
    }
    return;
  }

  if (bid < 544){                       // ---- Q / K classes (proven geometry)
    int cls = (bid - 32) >> 8;          // 0:Q 1:K
    int u = (bid - 32) & 255;
    int tile = (u & 7) * 32 + (u >> 3); // XCD-contiguous chunk within class
    int mt = tile >> 3, nt = tile & 7;
    int m0 = mt * 128, n0 = nt * 128;
    const us* A  = cls ? Xkv : Xq;
    const us* Bp = wt + (size_t)cls * 2097152;
    const float* bias = cls ? bk : bq;
    us* out = cls ? kbuf : qbuf;
    int wm = w >> 1, wn = w & 1;
    f32x4 acc[4][4];
#pragma unroll
    for (int i=0;i<4;i++)
#pragma unroll
      for (int j=0;j<4;j++) acc[i][j] = fzero();

    auto stage = [&](int buf, int kt){
      int k0 = kt * 32;
#pragma unroll
      for (int c = 0; c < 2; c++){
        int slot = c*256 + t;
        int g = slot ^ ((slot >> 3) & 7);
        int r = g >> 2, kc = g & 3;
        gload_lds16(A  + (size_t)(m0 + r)*1024 + k0 + kc*8, (char*)&a_lds[buf][0] + slot*16);
        gload_lds16(Bp + (size_t)(n0 + r)*1024 + k0 + kc*8, (char*)&b_lds[buf][0] + slot*16);
      }
    };

    stage(0, 0);
    __syncthreads();
    int buf = 0;
    for (int kt = 0; kt < 32; kt++){
      if (kt + 1 < 32) stage(buf ^ 1, kt + 1);
      bf16x8 af[4], bfv[4];
#pragma unroll
      for (int mi=0;mi<4;mi++){
        int r = wm*64 + mi*16 + li;
        int s = (r*4 + lg); s ^= ((s >> 3) & 7);
        af[mi] = *(const bf16x8*)((char*)&a_lds[buf][0] + s*16);
      }
#pragma unroll
      for (int ni=0;ni<4;ni++){
        int r = wn*64 + ni*16 + li;
        int s = (r*4 + lg); s ^= ((s >> 3) & 7);
        bfv[ni] = *(const bf16x8*)((char*)&b_lds[buf][0] + s*16);
      }
#pragma unroll
      for (int mi=0;mi<4;mi++)
#pragma unroll
        for (int ni=0;ni<4;ni++)
          acc[mi][ni] = mfma16(af[mi], bfv[ni], acc[mi][ni]);
      __syncthreads();
      buf ^= 1;
    }

#pragma unroll
    for (int ni=0;ni<4;ni++){
      int n = n0 + wn*64 + ni*16 + li;
      float bn = bias[n];
      int hh = n >> 6, hd = n & 63;
#pragma unroll
      for (int mi=0;mi<4;mi++){
        int mb = m0 + wm*64 + mi*16 + lg*4;
#pragma unroll
        for (int j=0;j<4;j++){
          int m = mb + j;
          int bb = m >> 10, tp = m & 1023;
          out[(((size_t)(bb*16 + hh))*1024 + tp)*64 + hd] = f2bf(acc[mi][ni][j] + bn);
        }
      }
    }
    return;
  }

  // ---- V class: BM=128, BN=128, 32 iters, fused hi+lo (32 MFMA/interval), 256 blocks
  {
    int u = bid - 544;
    int tile = (u & 7) * 32 + (u >> 3);
    int mt = tile >> 3, nt = tile & 7;
    int m0 = mt * 128, n0 = nt * 128;
    const us* Bh = wt + (size_t)2 * 2097152;
    const us* Bl = Bh + 1048576;
    int wm = w >> 1, wn = w & 1;
    f32x4 acc[4][4];
#pragma unroll
    for (int i=0;i<4;i++)
#pragma unroll
      for (int j=0;j<4;j++) acc[i][j] = fzero();

    auto stage = [&](int buf, int kt){
      int k0 = kt * 32;
#pragma unroll
      for (int c = 0; c < 2; c++){
        int slot = c*256 + t;
        int g = slot ^ ((slot >> 3) & 7);
        int r = g >> 2, kc = g & 3;
        gload_lds16(Xkv + (size_t)(m0 + r)*1024 + k0 + kc*8, (char*)&a_lds[buf][0] + slot*16);
        gload_lds16(Bh  + (size_t)(n0 + r)*1024 + k0 + kc*8, (char*)&b_lds[buf][0] + slot*16);
        gload_lds16(Bl  + (size_t)(n0 + r)*1024 + k0 + kc*8, (char*)&b_lds[buf][0] + 8192 + slot*16);
      }
    };

    stage(0, 0);
    __syncthreads();
    int buf = 0;
    for (int kt = 0; kt < 32; kt++){
      if (kt + 1 < 32) stage(buf ^ 1, kt + 1);
      bf16x8 af[4], bh_[4], bl_[4];
#pragma unroll
      for (int mi=0;mi<4;mi++){
        int r = wm*64 + mi*16 + li;
        int s = (r*4 + lg); s ^= ((s >> 3) & 7);
        af[mi] = *(const bf16x8*)((char*)&a_lds[buf][0] + s*16);
      }
#pragma unroll
      for (int ni=0;ni<4;ni++){
        int r = wn*64 + ni*16 + li;
        int s = (r*4 + lg); s ^= ((s >> 3) & 7);
        bh_[ni] = *(const bf16x8*)((char*)&b_lds[buf][0] + s*16);
        bl_[ni] = *(const bf16x8*)((char*)&b_lds[buf][0] + 8192 + s*16);
      }
#pragma unroll
      for (int mi=0;mi<4;mi++)
#pragma unroll
        for (int ni=0;ni<4;ni++){
          acc[mi][ni] = mfma16(af[mi], bh_[ni], acc[mi][ni]);
          acc[mi][ni] = mfma16(af[mi], bl_[ni], acc[mi][ni]);
        }
      __syncthreads();
      buf ^= 1;
    }

#pragma unroll
    for (int ni=0;ni<4;ni++){
      int n = n0 + wn*64 + ni*16 + li;
      float bn = bv[n];
      int hh = n >> 6, hd = n & 63;
#pragma unroll
      for (int mi=0;mi<4;mi++){
        int mb = m0 + wm*64 + mi*16 + lg*4;
#pragma unroll
        for (int j=0;j<4;j++){
          int m = mb + j;
          int bb = m >> 10, tp = m & 1023;
          vtb[(((size_t)(bb*16 + hh))*64 + hd)*1024 + tp] = f2bf(acc[mi][ni][j] + bn);
        }
      }
    }
  }
}

// ---------------- 3: O GEMM: 2 products (ctx_hi x [Wo_hi + Wo_lo]), BM=128, BN=64, fp32 out ----------------
__global__ __launch_bounds__(256, 2) void k_gemmo(const us* __restrict__ A_hi,
                                                  const us* __restrict__ B_hi, const us* __restrict__ B_lo,
                                                  const float* __restrict__ bias,
                                                  float* __restrict__ out_f)
{
  __shared__ __align__(16) us a_lds[2][4096];
  __shared__ __align__(16) us b_lds[2][2048];
  int bid = blockIdx.x;
  int wg = (bid & 7) * 64 + (bid >> 3);        // 512 % 8 == 0
  int mt = wg >> 4, nt = wg & 15;
  int m0 = mt * 128, n0 = nt * 64;
  int t = threadIdx.x, w = t >> 6, lane = t & 63, lg = lane >> 4, li = lane & 15;
  int wm = w >> 1, wn = w & 1;
  f32x4 acc[4][2];
#pragma unroll
  for (int i=0;i<4;i++){ acc[i][0]=fzero(); acc[i][1]=fzero(); }

  auto stage = [&](int buf, int kt){
    int seg = kt >> 5, k0 = (kt & 31) * 32;
    const us* Bp = seg ? B_lo : B_hi;
#pragma unroll
    for (int c = 0; c < 2; c++){
      int slot = c*256 + t;
      int g = slot ^ ((slot >> 3) & 7);
      int r = g >> 2, kc = g & 3;
      gload_lds16(A_hi + (size_t)(m0 + r)*1024 + k0 + kc*8, (char*)&a_lds[buf][0] + slot*16);
    }
    {
      int slot = t;
      int g = slot ^ ((slot >> 3) & 7);
      int r = g >> 2, kc = g & 3;
      gload_lds16(Bp + (size_t)(n0 + r)*1024 + k0 + kc*8, (char*)&b_lds[buf][0] + slot*16);
    }
  };

  stage(0, 0);
  __syncthreads();
  int buf = 0;
  for (int kt = 0; kt < 64; kt++){
    if (kt + 1 < 64) stage(buf ^ 1, kt + 1);
    bf16x8 af[4], bfv[2];
#pragma unroll
    for (int mi=0;mi<4;mi++){
      int r = wm*64 + mi*16 + li;
      int s = (r*4 + lg); s ^= ((s >> 3) & 7);
      af[mi] = *(const bf16x8*)((char*)&a_lds[buf][0] + s*16);
    }
#pragma unroll
    for (int ni=0;ni<2;ni++){
      int r = wn*32 + ni*16 + li;
      int s = (r*4 + lg); s ^= ((s >> 3) & 7);
      bfv[ni] = *(const bf16x8*)((char*)&b_lds[buf][0] + s*16);
    }
#pragma unroll
    for (int mi=0;mi<4;mi++)
#pragma unroll
      for (int ni=0;ni<2;ni++)
        acc[mi][ni] = mfma16(af[mi], bfv[ni], acc[mi][ni]);
    __syncthreads();
    buf ^= 1;
  }

#pragma unroll
  for (int ni=0;ni<2;ni++){
    int n = n0 + wn*32 + ni*16 + li;
    float bn = bias[n];
#pragma unroll
    for (int mi=0;mi<4;mi++){
      int mb = m0 + wm*64 + mi*16 + lg*4;
#pragma unroll
      for (int j=0;j<4;j++)
        out_f[(size_t)(mb + j)*1024 + n] = acc[mi][ni][j] + bn;
    }
  }
}

// ---------------- 4: c2p/p2c (single product, pre-scaled by BS for exp2) ----------------
__global__ __launch_bounds__(256) void k_cp(const us* __restrict__ q_hi,
                                            const us* __restrict__ k_hi,
                                            const us* __restrict__ pk_hi,
                                            const us* __restrict__ pq_hi,
                                            us* __restrict__ c2p, us* __restrict__ p2c)
{
  int qt = blockIdx.x, bh = blockIdx.y, z = blockIdx.z;
  const us* X_hi = z ? k_hi : q_hi;
  const us* P_hi = z ? pq_hi : pk_hi;
  us* out = z ? p2c : c2p;
  int h = bh & 15;
  int t = threadIdx.x, w = t >> 6, lane = t & 63, lg = lane >> 4, li = lane & 15;
  f32x4 acc[4];
#pragma unroll
  for (int i=0;i<4;i++) acc[i] = fzero();
  size_t row = (size_t)bh*1024 + qt*64 + w*16 + li;
#pragma unroll
  for (int kk=0;kk<2;kk++){
    int k = kk*32 + lg*8;
    bf16x8 ah = *(const bf16x8*)(X_hi + row*64 + k);
#pragma unroll
    for (int nf=0;nf<4;nf++){
      int s = nf*16 + li;
      bf16x8 bh_ = *(const bf16x8*)(P_hi + (size_t)h*4096 + s*64 + k);
      acc[nf] = mfma16(ah, bh_, acc[nf]);
    }
  }
  size_t obase = ((size_t)bh*1024 + qt*64 + w*16 + lg*4) * 64;
#pragma unroll
  for (int nf=0;nf<4;nf++)
#pragma unroll
    for (int j=0;j<4;j++)
      out[obase + (size_t)j*64 + nf*16 + li] = f2bf(acc[nf][j] * BS);
}

// ---------------- 5: fused attention: 8 waves, QBLK=128, bh-pinned XCD swizzle ----------------
// grid = 512 (1D): bid = (bh&7) + 8*(qt + 8*(bh>>3)) -> XCD = bh&7; all 8 qt of a bh share one XCD's L2.
__global__ __launch_bounds__(512) void k_attn(const us* __restrict__ qhi,
                                              const us* __restrict__ khi,
                                              const us* __restrict__ vhi,
                                              const us* __restrict__ c2p, const us* __restrict__ p2c,
                                              const signed char* __restrict__ idxt,
                                              const unsigned char* __restrict__ mask,
                                              us* __restrict__ ctx_hi)
{
  __shared__ __align__(16) us khi_lds[4096], vhi_lds[4096];
  __shared__ __align__(16) us c2p_lds[128*72], p2c_lds[64*72];   // padded rows: 144B stride
  __shared__ __align__(16) us p_lds[8][1024];
  __shared__ signed char idx_lds[2048];

  const int bid = blockIdx.x;
  const int xg = bid & 7, rest = bid >> 3;
  const int qt = rest & 7;
  const int bh = xg + ((rest >> 3) << 3);
  const int b = bh >> 4, h = bh & 15;
  const int t = threadIdx.x, w = t >> 6, lane = t & 63, lg = lane >> 4, li = lane & 15;
  const int q0 = qt * 128;

  for (int i = t; i < 2047; i += 512) idx_lds[i] = idxt[i];
  {
    const us* src = c2p + ((size_t)bh*1024 + q0) * 64;
#pragma unroll
    for (int c = 0; c < 2; c++){
      int f = c*512 + t, r = f >> 3, kc = f & 7;
      *(ushort8*)&c2p_lds[r*72 + kc*8] = *(const ushort8*)(src + r*64 + kc*8);
    }
  }
  bf16x8 qfh[2];
  {
    const us* qph = qhi + ((size_t)bh*1024 + q0 + w*16 + li)*64 + lg*8;
    qfh[0] = *(const bf16x8*)(qph); qfh[1] = *(const bf16x8*)(qph + 32);
  }
  __syncthreads();
  // far-path per-row bias (scaled) for idx=0 / idx=63
  float cq0[4], cq63[4];
#pragma unroll
  for (int j=0;j<4;j++){
    int qloc = w*16 + lg*4 + j;
    cq0[j]  = b2f(c2p_lds[qloc*72 + 0]);
    cq63[j] = b2f(c2p_lds[qloc*72 + 63]);
  }

  float lrow[4];
  f32x4 accO[4];
#pragma unroll
  for (int j=0;j<4;j++){ lrow[j] = 0.f; accO[j] = fzero(); }
  const unsigned char* mptr = mask + b*1024;

  for (int kt = 0; kt < 16; kt++){
    const int k0 = kt * 64;
    const bool far = (q0 - k0 >= 192) || (k0 - q0 >= 256);
    __syncthreads();
    {  // stage K,V: one 16B chunk each per thread
      int r = t >> 3, kc = t & 7;
      *(ushort8*)&khi_lds[r*64 + ((kc ^ (r & 7))*8)] =
          *(const ushort8*)(khi + ((size_t)bh*1024 + k0 + r)*64 + kc*8);
      *(ushort8*)&vhi_lds[r*64 + ((kc ^ (r & 7))*8)] =
          *(const ushort8*)(vhi + ((size_t)bh*64 + r)*1024 + k0 + kc*8);
      if (!far)
        *(ushort8*)&p2c_lds[r*72 + kc*8] =
            *(const ushort8*)(p2c + ((size_t)bh*1024 + k0 + r)*64 + kc*8);
    }
    __syncthreads();

    // QK^T single product
    f32x4 sfr[4];
#pragma unroll
    for (int nf=0;nf<4;nf++) sfr[nf] = fzero();
#pragma unroll
    for (int kk=0; kk<2; kk++){
      int kc = kk*4 + lg;
#pragma unroll
      for (int nf=0; nf<4; nf++){
        int r = nf*16 + li;
        bf16x8 bh_ = *(const bf16x8*)&khi_lds[r*64 + ((kc ^ (r & 7))*8)];
        sfr[nf] = mfma16(qfh[kk], bh_, sfr[nf]);
      }
    }
    us* pl = &p_lds[w][0];
    if (far){
      const int cidx = (q0 > k0) ? 63 : 0;
      float cq[4];
#pragma unroll
      for (int j=0;j<4;j++) cq[j] = (q0 > k0) ? cq63[j] : cq0[j];
#pragma unroll
      for (int nf=0; nf<4; nf++){
        int kloc = nf*16 + li;
        bool mk = mptr[k0 + kloc] != 0;
        float ck = b2f(p2c[((size_t)bh*1024 + k0 + kloc)*64 + cidx]);
        int col = kloc;
#pragma unroll
        for (int j=0;j<4;j++){
          float p = mk ? 0.f : exp2f(fmaf(sfr[nf][j], QS2, cq[j] + ck));
          lrow[j] += p;
          int row = lg*4 + j;
          pl[row*64 + ((col & 7) | ((((col >> 3) ^ (row & 7))) << 3))] = f2bf(p);
        }
      }
    } else {
#pragma unroll
      for (int nf=0; nf<4; nf++){
        int kloc = nf*16 + li;
        bool mk = mptr[k0 + kloc] != 0;
        int col = kloc;
#pragma unroll
        for (int j=0;j<4;j++){
          int qloc = w*16 + lg*4 + j;
          int d = (q0 + qloc) - (k0 + kloc);
          int idx = (int)idx_lds[d + 1023];
          float s2 = fmaf(sfr[nf][j], QS2,
                          b2f(c2p_lds[qloc*72 + idx]) + b2f(p2c_lds[kloc*72 + idx]));
          float p = mk ? 0.f : exp2f(s2);
          lrow[j] += p;
          int row = lg*4 + j;
          pl[row*64 + ((col & 7) | ((((col >> 3) ^ (row & 7))) << 3))] = f2bf(p);
        }
      }
    }
    // PV single product (p_lds wave-private; same-wave DS ordering)
#pragma unroll
    for (int kk=0;kk<2;kk++){
      int kc = kk*4 + lg;
      bf16x8 af = *(const bf16x8*)((char*)pl + li*128 + ((kc ^ (li & 7)) * 16));
#pragma unroll
      for (int nf=0;nf<4;nf++){
        int r = nf*16 + li;
        bf16x8 bh_ = *(const bf16x8*)&vhi_lds[r*64 + ((kc ^ (r & 7))*8)];
        accO[nf] = mfma16(af, bh_, accO[nf]);
      }
    }
  }

  for (int o=1;o<16;o<<=1)
#pragma unroll
    for (int j=0;j<4;j++)
      lrow[j] += __shfl_xor(lrow[j], o);
#pragma unroll
  for (int nf=0;nf<4;nf++)
#pragma unroll
    for (int j=0;j<4;j++){
      int qloc = w*16 + lg*4 + j;
      float o = accO[nf][j] / lrow[j];
      size_t idx = ((size_t)(b*1024 + q0 + qloc))*1024 + h*64 + nf*16 + li;
      ctx_hi[idx] = f2bf(o);
    }
}

// ---------------- launch ----------------
extern "C" void kernel_launch(void* const* d_in, const int* in_sizes, int n_in,
                              void* d_out, int out_size, void* d_ws, size_t ws_size,
                              hipStream_t stream)
{
  (void)in_sizes; (void)n_in; (void)out_size; (void)ws_size;
  const float* query = (const float*)d_in[0];
  const float* kvst  = (const float*)d_in[1];
  const unsigned char* mask = (const unsigned char*)d_in[2];
  const float* Wq = (const float*)d_in[3];  const float* bq = (const float*)d_in[4];
  const float* Wk = (const float*)d_in[5];  const float* bk = (const float*)d_in[6];
  const float* Wv = (const float*)d_in[7];  const float* bv = (const float*)d_in[8];
  const float* Wo = (const float*)d_in[9];  const float* bo = (const float*)d_in[10];
  const float* rel = (const float*)d_in[11];
  const float* lng = (const float*)d_in[12]; const float* lnb = (const float*)d_in[13];
  const float* Wpk = (const float*)d_in[14]; const float* bpk = (const float*)d_in[15];
  const float* Wpq = (const float*)d_in[16]; const float* bpq = (const float*)d_in[17];

  char* ws = (char*)d_ws;
  const size_t MB = 1024*1024;
  us* Xq_hi  = (us*)(ws + 0);        // [0,8)   dead after k_qkvp
  us* p2c    = (us*)(ws + 8*MB);     // [8,16)  k_cp z=1 writes (after k_qkvp)
  us* Xkv_hi = (us*)(ws + 16*MB);    // [16,24) dead after k_qkvp
  us* c2p    = (us*)(ws + 16*MB);    //         k_cp z=0 writes
  us* vtb    = (us*)(ws + 24*MB);    // [24,32) k_qkvp V writes; k_attn reads
  us* Wt     = (us*)(ws + 32*MB);    // [32,56) 6 slots x 4MB
  us* ctx_hi = (us*)(ws + 32*MB);    //         k_attn writes over Wq/Wk slots (dead)
  us* reln_hi = (us*)(ws + 56*MB);
  us* posk_hi = (us*)(ws + 56*MB + 256*1024);
  us* posq_hi = (us*)(ws + 56*MB + 512*1024);
  signed char* idxt = (signed char*)(ws + 56*MB + 768*1024);
  us* qbuf_hi = (us*)(ws + 57*MB);   // [57,65)
  us* kbuf_hi = (us*)(ws + 65*MB);   // [65,73)

  k_prep<<<14409, 256, 0, stream>>>(query, kvst, Wq, Wk, Wv, Wpk, Wpq, Wo,
                                    rel, lng, lnb,
                                    Xq_hi, Xkv_hi, Wt, reln_hi, idxt);

  k_qkvp<<<800, 256, 0, stream>>>(Xq_hi, Xkv_hi, Wt, bq, bk, bv,
                                  reln_hi, bpk, bpq,
                                  qbuf_hi, kbuf_hi, vtb, posk_hi, posq_hi);

  k_cp<<<dim3(16,64,2), 256, 0, stream>>>(qbuf_hi, kbuf_hi, posk_hi, posq_hi, c2p, p2c);

  k_attn<<<512, 512, 0, stream>>>(qbuf_hi, kbuf_hi, vtb,
                                  c2p, p2c, idxt, mask, ctx_hi);

  k_gemmo<<<512, 256, 0, stream>>>(ctx_hi, Wt + 5*2097152, Wt + 5*2097152 + 1048576, bo, (float*)d_out);
}

// Round 18
// 165.839 us; speedup vs baseline: 1.2842x; 1.0198x over previous
//
#include <hip/hip_runtime.h>
#include <cstdint>
#include <math.h>

typedef unsigned short us;
typedef __attribute__((ext_vector_type(8))) __bf16 bf16x8;
typedef __attribute__((ext_vector_type(8))) unsigned short ushort8;
typedef __attribute__((ext_vector_type(4))) float f32x4;

__device__ __forceinline__ us f2bf(float x){
  union { float f; unsigned int u; } v; v.f = x;
  unsigned int r = v.u + 0x7FFFu + ((v.u >> 16) & 1u);   // RNE
  return (us)(r >> 16);
}
__device__ __forceinline__ float b2f(us u){
  union { unsigned int u; float f; } v; v.u = ((unsigned int)u) << 16; return v.f;
}
__device__ __forceinline__ void split2(float x, us& hi, us& lo){
  hi = f2bf(x); lo = f2bf(x - b2f(hi));
}
__device__ __forceinline__ f32x4 fzero(){ f32x4 v; v.x=0.f; v.y=0.f; v.z=0.f; v.w=0.f; return v; }
__device__ __forceinline__ f32x4 mfma16(bf16x8 a, bf16x8 b, f32x4 c){
  return __builtin_amdgcn_mfma_f32_16x16x32_bf16(a, b, c, 0, 0, 0);
}
__device__ __forceinline__ void gload_lds16(const void* g, void* l){
  __builtin_amdgcn_global_load_lds(
      (const __attribute__((address_space(1))) unsigned int*)(uintptr_t)g,
      (__attribute__((address_space(3))) unsigned int*)(uintptr_t)l,
      16, 0, 0);
}

// exp2-folded scales
#define QS2 (0.07216878364870322f * 1.4426950408889634f)   // 1/sqrt(192) * log2(e)
#define BS  (0.08838834764831845f * 1.4426950408889634f)   // 1/sqrt(128) * log2(e)

// ---------------- 1: fused prep: convx | convw | lnrel | bucket ----------------
__global__ __launch_bounds__(256) void k_prep(const float* __restrict__ xq,
                                              const float* __restrict__ xkv,
                                              const float* __restrict__ w0, const float* __restrict__ w1,
                                              const float* __restrict__ w2, const float* __restrict__ w3,
                                              const float* __restrict__ w4, const float* __restrict__ w5,
                                              const float* __restrict__ rel,
                                              const float* __restrict__ g, const float* __restrict__ bLN,
                                              us* __restrict__ qhi, us* __restrict__ kvhi,
                                              us* __restrict__ wt, us* __restrict__ reln_hi,
                                              signed char* __restrict__ idxt)
{
  __shared__ float tile[32][33];
  __shared__ float sm[8];
  const int bid = blockIdx.x, t = threadIdx.x;

  if (bid < 8192){                      // ---- convx (hi only)
    int i = bid * 256 + t;
    const float* src; us* dh;
    if (i < 1048576){ src = xq  + (size_t)i*4;           dh = qhi  + (size_t)i*4; }
    else            { src = xkv + (size_t)(i-1048576)*4; dh = kvhi + (size_t)(i-1048576)*4; }
    f32x4 v = *(const f32x4*)src;
    dh[0]=f2bf(v.x); dh[1]=f2bf(v.y); dh[2]=f2bf(v.z); dh[3]=f2bf(v.w);
    return;
  }
  if (bid < 14336){                     // ---- convw: transpose + hi/lo split
    int rem = bid - 8192;
    int z = rem >> 10, r2 = rem & 1023;
    const float* W = (z==0)?w0:(z==1)?w1:(z==2)?w2:(z==3)?w3:(z==4)?w4:w5;
    us* dst_hi = wt + (size_t)z * 2097152;
    us* dst_lo = dst_hi + 1048576;
    bool wlo = (z == 2) || (z == 5);
    int n0 = (r2 & 31) * 32, k0 = (r2 >> 5) * 32;
    int c = t & 31, r = t >> 5;
#pragma unroll
    for (int i = 0; i < 4; i++)
      tile[r + i*8][c] = W[(size_t)(k0 + r + i*8)*1024 + n0 + c];
    __syncthreads();
#pragma unroll
    for (int i = 0; i < 4; i++){
      int nn = r + i*8;
      us h,l; split2(tile[c][nn], h, l);
      dst_hi[(size_t)(n0 + nn)*1024 + k0 + c] = h;
      if (wlo) dst_lo[(size_t)(n0 + nn)*1024 + k0 + c] = l;
    }
    return;
  }
  if (bid < 14400){                     // ---- lnrel
    int row = bid - 14336;
    const float* x = rel + (size_t)row * 1024;
    float v[4]; float s = 0.f, ss = 0.f;
#pragma unroll
    for (int i=0;i<4;i++){ v[i] = x[t + 256*i]; s += v[i]; ss += v[i]*v[i]; }
    for (int o=32;o;o>>=1){ s += __shfl_xor(s,o); ss += __shfl_xor(ss,o); }
    int w = t >> 6;
    if ((t & 63) == 0){ sm[w] = s; sm[4+w] = ss; }
    __syncthreads();
    s  = sm[0]+sm[1]+sm[2]+sm[3];
    ss = sm[4]+sm[5]+sm[6]+sm[7];
    float mu  = s  * (1.0f/1024.0f);
    float var = ss * (1.0f/1024.0f) - mu*mu;
    float rs  = rsqrtf(var + 1e-5f);
#pragma unroll
    for (int i=0;i<4;i++){
      int cc = t + 256*i;
      reln_hi[(size_t)row*1024 + cc] = f2bf((v[i]-mu)*rs*g[cc] + bLN[cc]);
    }
    return;
  }
  {                                     // ---- bucket table
    int i = (bid - 14400) * 256 + t;
    if (i >= 2052) return;
    int d = i - 1023;
    int ad = d < 0 ? -d : d;
    int abspos = (d < 16 && d > -16) ? 15 : ad;
    int bucket;
    if (abspos <= 16) bucket = d;
    else {
      float num = (float)log((double)abspos * 0.0625);
      float den = (float)log(7.9375);
      float lp = ceilf(num / den * 15.0f) + 16.0f;
      bucket = (int)lp * (d > 0 ? 1 : -1);
    }
    int s = bucket + 32;
    s = s < 0 ? 0 : (s > 63 ? 63 : s);
    idxt[i] = (signed char)s;
  }
}

// ---------------- 2: merged QKV GEMM + pos projections, grid=800 ----------------
__global__ __launch_bounds__(256) void k_qkvp(const us* __restrict__ Xq, const us* __restrict__ Xkv,
                                              const us* __restrict__ wt,
                                              const float* __restrict__ bq, const float* __restrict__ bk,
                                              const float* __restrict__ bv,
                                              const us* __restrict__ reln_hi,
                                              const float* __restrict__ bpk, const float* __restrict__ bpq,
                                              us* __restrict__ qbuf, us* __restrict__ kbuf,
                                              us* __restrict__ vtb,
                                              us* __restrict__ posk_hi, us* __restrict__ posq_hi)
{
  __shared__ __align__(16) us a_lds[2][4096];   // 128 x 32
  __shared__ __align__(16) us b_lds[2][8192];   // Q/K: first 4096 used ; V: hi [0,4096) + lo [4096,8192)
  const int bid = blockIdx.x;
  const int t = threadIdx.x, w = t >> 6, lane = t & 63, lg = lane >> 4, li = lane & 15;

  if (bid < 32){                        // ---- pos projections
    int ntile = bid & 15, z = bid >> 4;
    const us* W_hi = wt + (size_t)(3 + z) * 2097152;
    const float* bias = z ? bpq : bpk;
    us* out_hi = z ? posq_hi : posk_hi;
    f32x4 acc[4];
#pragma unroll
    for (int i=0;i<4;i++) acc[i] = fzero();
    int srow = w*16 + li;
    for (int kt = 0; kt < 32; kt++){
      int k0 = kt*32 + lg*8;
      bf16x8 a = *(const bf16x8*)(reln_hi + (size_t)srow*1024 + k0);
#pragma unroll
      for (int nf=0; nf<4; nf++){
        int n = ntile*64 + nf*16 + li;
        bf16x8 b = *(const bf16x8*)(W_hi + (size_t)n*1024 + k0);
        acc[nf] = mfma16(a, b, acc[nf]);
      }
    }
#pragma unroll
    for (int nf=0;nf<4;nf++){
      int n = ntile*64 + nf*16 + li;
      float bn = bias[n];
      int h = n >> 6, hd = n & 63;
#pragma unroll
      for (int j=0;j<4;j++){
        int s = w*16 + lg*4 + j;
        out_hi[(size_t)h*4096 + s*64 + hd] = f2bf(acc[nf][j] + bn);
      }
    }
    return;
  }

  if (bid < 544){                       // ---- Q / K classes (proven geometry)
    int cls = (bid - 32) >> 8;          // 0:Q 1:K
    int u = (bid - 32) & 255;
    int tile = (u & 7) * 32 + (u >> 3); // XCD-contiguous chunk within class
    int mt = tile >> 3, nt = tile & 7;
    int m0 = mt * 128, n0 = nt * 128;
    const us* A  = cls ? Xkv : Xq;
    const us* Bp = wt + (size_t)cls * 2097152;
    const float* bias = cls ? bk : bq;
    us* out = cls ? kbuf : qbuf;
    int wm = w >> 1, wn = w & 1;
    f32x4 acc[4][4];
#pragma unroll
    for (int i=0;i<4;i++)
#pragma unroll
      for (int j=0;j<4;j++) acc[i][j] = fzero();

    auto stage = [&](int buf, int kt){
      int k0 = kt * 32;
#pragma unroll
      for (int c = 0; c < 2; c++){
        int slot = c*256 + t;
        int g = slot ^ ((slot >> 3) & 7);
        int r = g >> 2, kc = g & 3;
        gload_lds16(A  + (size_t)(m0 + r)*1024 + k0 + kc*8, (char*)&a_lds[buf][0] + slot*16);
        gload_lds16(Bp + (size_t)(n0 + r)*1024 + k0 + kc*8, (char*)&b_lds[buf][0] + slot*16);
      }
    };

    stage(0, 0);
    __syncthreads();
    int buf = 0;
    for (int kt = 0; kt < 32; kt++){
      if (kt + 1 < 32) stage(buf ^ 1, kt + 1);
      bf16x8 af[4], bfv[4];
#pragma unroll
      for (int mi=0;mi<4;mi++){
        int r = wm*64 + mi*16 + li;
        int s = (r*4 + lg); s ^= ((s >> 3) & 7);
        af[mi] = *(const bf16x8*)((char*)&a_lds[buf][0] + s*16);
      }
#pragma unroll
      for (int ni=0;ni<4;ni++){
        int r = wn*64 + ni*16 + li;
        int s = (r*4 + lg); s ^= ((s >> 3) & 7);
        bfv[ni] = *(const bf16x8*)((char*)&b_lds[buf][0] + s*16);
      }
#pragma unroll
      for (int mi=0;mi<4;mi++)
#pragma unroll
        for (int ni=0;ni<4;ni++)
          acc[mi][ni] = mfma16(af[mi], bfv[ni], acc[mi][ni]);
      __syncthreads();
      buf ^= 1;
    }

#pragma unroll
    for (int ni=0;ni<4;ni++){
      int n = n0 + wn*64 + ni*16 + li;
      float bn = bias[n];
      int hh = n >> 6, hd = n & 63;
#pragma unroll
      for (int mi=0;mi<4;mi++){
        int mb = m0 + wm*64 + mi*16 + lg*4;
#pragma unroll
        for (int j=0;j<4;j++){
          int m = mb + j;
          int bb = m >> 10, tp = m & 1023;
          out[(((size_t)(bb*16 + hh))*1024 + tp)*64 + hd] = f2bf(acc[mi][ni][j] + bn);
        }
      }
    }
    return;
  }

  // ---- V class: BM=128, BN=128, 32 iters, fused hi+lo (32 MFMA/interval), 256 blocks
  {
    int u = bid - 544;
    int tile = (u & 7) * 32 + (u >> 3);
    int mt = tile >> 3, nt = tile & 7;
    int m0 = mt * 128, n0 = nt * 128;
    const us* Bh = wt + (size_t)2 * 2097152;
    const us* Bl = Bh + 1048576;
    int wm = w >> 1, wn = w & 1;
    f32x4 acc[4][4];
#pragma unroll
    for (int i=0;i<4;i++)
#pragma unroll
      for (int j=0;j<4;j++) acc[i][j] = fzero();

    auto stage = [&](int buf, int kt){
      int k0 = kt * 32;
#pragma unroll
      for (int c = 0; c < 2; c++){
        int slot = c*256 + t;
        int g = slot ^ ((slot >> 3) & 7);
        int r = g >> 2, kc = g & 3;
        gload_lds16(Xkv + (size_t)(m0 + r)*1024 + k0 + kc*8, (char*)&a_lds[buf][0] + slot*16);
        gload_lds16(Bh  + (size_t)(n0 + r)*1024 + k0 + kc*8, (char*)&b_lds[buf][0] + slot*16);
        gload_lds16(Bl  + (size_t)(n0 + r)*1024 + k0 + kc*8, (char*)&b_lds[buf][0] + 8192 + slot*16);
      }
    };

    stage(0, 0);
    __syncthreads();
    int buf = 0;
    for (int kt = 0; kt < 32; kt++){
      if (kt + 1 < 32) stage(buf ^ 1, kt + 1);
      bf16x8 af[4], bh_[4], bl_[4];
#pragma unroll
      for (int mi=0;mi<4;mi++){
        int r = wm*64 + mi*16 + li;
        int s = (r*4 + lg); s ^= ((s >> 3) & 7);
        af[mi] = *(const bf16x8*)((char*)&a_lds[buf][0] + s*16);
      }
#pragma unroll
      for (int ni=0;ni<4;ni++){
        int r = wn*64 + ni*16 + li;
        int s = (r*4 + lg); s ^= ((s >> 3) & 7);
        bh_[ni] = *(const bf16x8*)((char*)&b_lds[buf][0] + s*16);
        bl_[ni] = *(const bf16x8*)((char*)&b_lds[buf][0] + 8192 + s*16);
      }
#pragma unroll
      for (int mi=0;mi<4;mi++)
#pragma unroll
        for (int ni=0;ni<4;ni++){
          acc[mi][ni] = mfma16(af[mi], bh_[ni], acc[mi][ni]);
          acc[mi][ni] = mfma16(af[mi], bl_[ni], acc[mi][ni]);
        }
      __syncthreads();
      buf ^= 1;
    }

#pragma unroll
    for (int ni=0;ni<4;ni++){
      int n = n0 + wn*64 + ni*16 + li;
      float bn = bv[n];
      int hh = n >> 6, hd = n & 63;
#pragma unroll
      for (int mi=0;mi<4;mi++){
        int mb = m0 + wm*64 + mi*16 + lg*4;
#pragma unroll
        for (int j=0;j<4;j++){
          int m = mb + j;
          int bb = m >> 10, tp = m & 1023;
          vtb[(((size_t)(bb*16 + hh))*64 + hd)*1024 + tp] = f2bf(acc[mi][ni][j] + bn);
        }
      }
    }
  }
}

// ---------------- 3: O GEMM: fused 2 products, 32 iters; B staged as FULL 64x32 per half ----------------
__global__ __launch_bounds__(256, 2) void k_gemmo(const us* __restrict__ A_hi,
                                                  const us* __restrict__ B_hi, const us* __restrict__ B_lo,
                                                  const float* __restrict__ bias,
                                                  float* __restrict__ out_f)
{
  __shared__ __align__(16) us a_lds[2][4096];   // 128 x 32
  __shared__ __align__(16) us b_lds[2][4096];   // Bhi 64x32 bytes [0,4096) + Blo 64x32 bytes [4096,8192)
  int bid = blockIdx.x;
  int wg = (bid & 7) * 64 + (bid >> 3);        // 512 % 8 == 0
  int mt = wg >> 4, nt = wg & 15;
  int m0 = mt * 128, n0 = nt * 64;
  int t = threadIdx.x, w = t >> 6, lane = t & 63, lg = lane >> 4, li = lane & 15;
  int wm = w >> 1, wn = w & 1;
  f32x4 acc[4][2];
#pragma unroll
  for (int i=0;i<4;i++){ acc[i][0]=fzero(); acc[i][1]=fzero(); }

  auto stage = [&](int buf, int kt){
    int k0 = kt * 32;
#pragma unroll
    for (int c = 0; c < 2; c++){     // A: 128x32 = 512 chunks
      int slot = c*256 + t;
      int g = slot ^ ((slot >> 3) & 7);
      int r = g >> 2, kc = g & 3;
      gload_lds16(A_hi + (size_t)(m0 + r)*1024 + k0 + kc*8, (char*)&a_lds[buf][0] + slot*16);
    }
#pragma unroll
    for (int c = 0; c < 2; c++){     // B: Bhi 256 chunks + Blo 256 chunks
      int slot = c*256 + t;
      int half = slot >> 8;          // 0: Bhi, 1: Blo
      int s2 = slot & 255;
      int g = s2 ^ ((s2 >> 3) & 7);
      int r = g >> 2, kc = g & 3;
      const us* Bp = half ? B_lo : B_hi;
      gload_lds16(Bp + (size_t)(n0 + r)*1024 + k0 + kc*8,
                  (char*)&b_lds[buf][0] + half*4096 + s2*16);
    }
  };

  stage(0, 0);
  __syncthreads();
  int buf = 0;
  for (int kt = 0; kt < 32; kt++){
    if (kt + 1 < 32) stage(buf ^ 1, kt + 1);
    bf16x8 af[4], bhv[2], blv[2];
#pragma unroll
    for (int mi=0;mi<4;mi++){
      int r = wm*64 + mi*16 + li;
      int s = (r*4 + lg); s ^= ((s >> 3) & 7);
      af[mi] = *(const bf16x8*)((char*)&a_lds[buf][0] + s*16);
    }
#pragma unroll
    for (int ni=0;ni<2;ni++){
      int r = wn*32 + ni*16 + li;
      int s = (r*4 + lg); s ^= ((s >> 3) & 7);
      bhv[ni] = *(const bf16x8*)((char*)&b_lds[buf][0] + s*16);
      blv[ni] = *(const bf16x8*)((char*)&b_lds[buf][0] + 4096 + s*16);
    }
#pragma unroll
    for (int mi=0;mi<4;mi++)
#pragma unroll
      for (int ni=0;ni<2;ni++){
        acc[mi][ni] = mfma16(af[mi], bhv[ni], acc[mi][ni]);
        acc[mi][ni] = mfma16(af[mi], blv[ni], acc[mi][ni]);
      }
    __syncthreads();
    buf ^= 1;
  }

#pragma unroll
  for (int ni=0;ni<2;ni++){
    int n = n0 + wn*32 + ni*16 + li;
    float bn = bias[n];
#pragma unroll
    for (int mi=0;mi<4;mi++){
      int mb = m0 + wm*64 + mi*16 + lg*4;
#pragma unroll
      for (int j=0;j<4;j++)
        out_f[(size_t)(mb + j)*1024 + n] = acc[mi][ni][j] + bn;
    }
  }
}

// ---------------- 4: c2p/p2c (single product, pre-scaled by BS for exp2) ----------------
__global__ __launch_bounds__(256) void k_cp(const us* __restrict__ q_hi,
                                            const us* __restrict__ k_hi,
                                            const us* __restrict__ pk_hi,
                                            const us* __restrict__ pq_hi,
                                            us* __restrict__ c2p, us* __restrict__ p2c)
{
  int qt = blockIdx.x, bh = blockIdx.y, z = blockIdx.z;
  const us* X_hi = z ? k_hi : q_hi;
  const us* P_hi = z ? pq_hi : pk_hi;
  us* out = z ? p2c : c2p;
  int h = bh & 15;
  int t = threadIdx.x, w = t >> 6, lane = t & 63, lg = lane >> 4, li = lane & 15;
  f32x4 acc[4];
#pragma unroll
  for (int i=0;i<4;i++) acc[i] = fzero();
  size_t row = (size_t)bh*1024 + qt*64 + w*16 + li;
#pragma unroll
  for (int kk=0;kk<2;kk++){
    int k = kk*32 + lg*8;
    bf16x8 ah = *(const bf16x8*)(X_hi + row*64 + k);
#pragma unroll
    for (int nf=0;nf<4;nf++){
      int s = nf*16 + li;
      bf16x8 bh_ = *(const bf16x8*)(P_hi + (size_t)h*4096 + s*64 + k);
      acc[nf] = mfma16(ah, bh_, acc[nf]);
    }
  }
  size_t obase = ((size_t)bh*1024 + qt*64 + w*16 + lg*4) * 64;
#pragma unroll
  for (int nf=0;nf<4;nf++)
#pragma unroll
    for (int j=0;j<4;j++)
      out[obase + (size_t)j*64 + nf*16 + li] = f2bf(acc[nf][j] * BS);
}

// ---------------- 5: fused attention: 8 waves, QBLK=128, bh-pinned XCD swizzle ----------------
__global__ __launch_bounds__(512) void k_attn(const us* __restrict__ qhi,
                                              const us* __restrict__ khi,
                                              const us* __restrict__ vhi,
                                              const us* __restrict__ c2p, const us* __restrict__ p2c,
                                              const signed char* __restrict__ idxt,
                                              const unsigned char* __restrict__ mask,
                                              us* __restrict__ ctx_hi)
{
  __shared__ __align__(16) us khi_lds[4096], vhi_lds[4096];
  __shared__ __align__(16) us c2p_lds[128*72], p2c_lds[64*72];   // padded rows: 144B stride
  __shared__ __align__(16) us p_lds[8][1024];
  __shared__ signed char idx_lds[2048];

  const int bid = blockIdx.x;
  const int xg = bid & 7, rest = bid >> 3;
  const int qt = rest & 7;
  const int bh = xg + ((rest >> 3) << 3);
  const int b = bh >> 4, h = bh & 15;
  const int t = threadIdx.x, w = t >> 6, lane = t & 63, lg = lane >> 4, li = lane & 15;
  const int q0 = qt * 128;

  for (int i = t; i < 2047; i += 512) idx_lds[i] = idxt[i];
  {
    const us* src = c2p + ((size_t)bh*1024 + q0) * 64;
#pragma unroll
    for (int c = 0; c < 2; c++){
      int f = c*512 + t, r = f >> 3, kc = f & 7;
      *(ushort8*)&c2p_lds[r*72 + kc*8] = *(const ushort8*)(src + r*64 + kc*8);
    }
  }
  bf16x8 qfh[2];
  {
    const us* qph = qhi + ((size_t)bh*1024 + q0 + w*16 + li)*64 + lg*8;
    qfh[0] = *(const bf16x8*)(qph); qfh[1] = *(const bf16x8*)(qph + 32);
  }
  __syncthreads();
  // far-path per-row bias (scaled) for idx=0 / idx=63
  float cq0[4], cq63[4];
#pragma unroll
  for (int j=0;j<4;j++){
    int qloc = w*16 + lg*4 + j;
    cq0[j]  = b2f(c2p_lds[qloc*72 + 0]);
    cq63[j] = b2f(c2p_lds[qloc*72 + 63]);
  }

  float lrow[4];
  f32x4 accO[4];
#pragma unroll
  for (int j=0;j<4;j++){ lrow[j] = 0.f; accO[j] = fzero(); }
  const unsigned char* mptr = mask + b*1024;

  for (int kt = 0; kt < 16; kt++){
    const int k0 = kt * 64;
    const bool far = (q0 - k0 >= 192) || (k0 - q0 >= 256);
    __syncthreads();
    {  // stage K,V: one 16B chunk each per thread
      int r = t >> 3, kc = t & 7;
      *(ushort8*)&khi_lds[r*64 + ((kc ^ (r & 7))*8)] =
          *(const ushort8*)(khi + ((size_t)bh*1024 + k0 + r)*64 + kc*8);
      *(ushort8*)&vhi_lds[r*64 + ((kc ^ (r & 7))*8)] =
          *(const ushort8*)(vhi + ((size_t)bh*64 + r)*1024 + k0 + kc*8);
      if (!far)
        *(ushort8*)&p2c_lds[r*72 + kc*8] =
            *(const ushort8*)(p2c + ((size_t)bh*1024 + k0 + r)*64 + kc*8);
    }
    __syncthreads();

    // far-path boundary-column gathers: issue BEFORE the MFMAs so L2 latency hides under QK^T
    float ck0 = 0.f, ck1 = 0.f, ck2 = 0.f, ck3 = 0.f;
    if (far){
      const int cidx = (q0 > k0) ? 63 : 0;
      const us* pp = p2c + ((size_t)bh*1024 + k0 + li)*64 + cidx;
      ck0 = b2f(pp[0*16*64]);
      ck1 = b2f(pp[1*16*64]);
      ck2 = b2f(pp[2*16*64]);
      ck3 = b2f(pp[3*16*64]);
    }

    // QK^T single product
    f32x4 sfr[4];
#pragma unroll
    for (int nf=0;nf<4;nf++) sfr[nf] = fzero();
#pragma unroll
    for (int kk=0; kk<2; kk++){
      int kc = kk*4 + lg;
#pragma unroll
      for (int nf=0; nf<4; nf++){
        int r = nf*16 + li;
        bf16x8 bh_ = *(const bf16x8*)&khi_lds[r*64 + ((kc ^ (r & 7))*8)];
        sfr[nf] = mfma16(qfh[kk], bh_, sfr[nf]);
      }
    }
    us* pl = &p_lds[w][0];
    if (far){
      float cq[4];
#pragma unroll
      for (int j=0;j<4;j++) cq[j] = (q0 > k0) ? cq63[j] : cq0[j];
#pragma unroll
      for (int nf=0; nf<4; nf++){
        int kloc = nf*16 + li;
        bool mk = mptr[k0 + kloc] != 0;
        float ck = (nf==0) ? ck0 : (nf==1) ? ck1 : (nf==2) ? ck2 : ck3;
        int col = kloc;
#pragma unroll
        for (int j=0;j<4;j++){
          float p = mk ? 0.f : exp2f(fmaf(sfr[nf][j], QS2, cq[j] + ck));
          lrow[j] += p;
          int row = lg*4 + j;
          pl[row*64 + ((col & 7) | ((((col >> 3) ^ (row & 7))) << 3))] = f2bf(p);
        }
      }
    } else {
#pragma unroll
      for (int nf=0; nf<4; nf++){
        int kloc = nf*16 + li;
        bool mk = mptr[k0 + kloc] != 0;
        int col = kloc;
#pragma unroll
        for (int j=0;j<4;j++){
          int qloc = w*16 + lg*4 + j;
          int d = (q0 + qloc) - (k0 + kloc);
          int idx = (int)idx_lds[d + 1023];
          float s2 = fmaf(sfr[nf][j], QS2,
                          b2f(c2p_lds[qloc*72 + idx]) + b2f(p2c_lds[kloc*72 + idx]));
          float p = mk ? 0.f : exp2f(s2);
          lrow[j] += p;
          int row = lg*4 + j;
          pl[row*64 + ((col & 7) | ((((col >> 3) ^ (row & 7))) << 3))] = f2bf(p);
        }
      }
    }
    // PV single product (p_lds wave-private; same-wave DS ordering)
#pragma unroll
    for (int kk=0;kk<2;kk++){
      int kc = kk*4 + lg;
      bf16x8 af = *(const bf16x8*)((char*)pl + li*128 + ((kc ^ (li & 7)) * 16));
#pragma unroll
      for (int nf=0;nf<4;nf++){
        int r = nf*16 + li;
        bf16x8 bh_ = *(const bf16x8*)&vhi_lds[r*64 + ((kc ^ (r & 7))*8)];
        accO[nf] = mfma16(af, bh_, accO[nf]);
      }
    }
  }

  for (int o=1;o<16;o<<=1)
#pragma unroll
    for (int j=0;j<4;j++)
      lrow[j] += __shfl_xor(lrow[j], o);
#pragma unroll
  for (int nf=0;nf<4;nf++)
#pragma unroll
    for (int j=0;j<4;j++){
      int qloc = w*16 + lg*4 + j;
      float o = accO[nf][j] / lrow[j];
      size_t idx = ((size_t)(b*1024 + q0 + qloc))*1024 + h*64 + nf*16 + li;
      ctx_hi[idx] = f2bf(o);
    }
}

// ---------------- launch ----------------
extern "C" void kernel_launch(void* const* d_in, const int* in_sizes, int n_in,
                              void* d_out, int out_size, void* d_ws, size_t ws_size,
                              hipStream_t stream)
{
  (void)in_sizes; (void)n_in; (void)out_size; (void)ws_size;
  const float* query = (const float*)d_in[0];
  const float* kvst  = (const float*)d_in[1];
  const unsigned char* mask = (const unsigned char*)d_in[2];
  const float* Wq = (const float*)d_in[3];  const float* bq = (const float*)d_in[4];
  const float* Wk = (const float*)d_in[5];  const float* bk = (const float*)d_in[6];
  const float* Wv = (const float*)d_in[7];  const float* bv = (const float*)d_in[8];
  const float* Wo = (const float*)d_in[9];  const float* bo = (const float*)d_in[10];
  const float* rel = (const float*)d_in[11];
  const float* lng = (const float*)d_in[12]; const float* lnb = (const float*)d_in[13];
  const float* Wpk = (const float*)d_in[14]; const float* bpk = (const float*)d_in[15];
  const float* Wpq = (const float*)d_in[16]; const float* bpq = (const float*)d_in[17];

  char* ws = (char*)d_ws;
  const size_t MB = 1024*1024;
  us* Xq_hi  = (us*)(ws + 0);        // [0,8)   dead after k_qkvp
  us* p2c    = (us*)(ws + 8*MB);     // [8,16)  k_cp z=1 writes (after k_qkvp)
  us* Xkv_hi = (us*)(ws + 16*MB);    // [16,24) dead after k_qkvp
  us* c2p    = (us*)(ws + 16*MB);    //         k_cp z=0 writes
  us* vtb    = (us*)(ws + 24*MB);    // [24,32) k_qkvp V writes; k_attn reads
  us* Wt     = (us*)(ws + 32*MB);    // [32,56) 6 slots x 4MB
  us* ctx_hi = (us*)(ws + 32*MB);    //         k_attn writes over Wq/Wk slots (dead)
  us* reln_hi = (us*)(ws + 56*MB);
  us* posk_hi = (us*)(ws + 56*MB + 256*1024);
  us* posq_hi = (us*)(ws + 56*MB + 512*1024);
  signed char* idxt = (signed char*)(ws + 56*MB + 768*1024);
  us* qbuf_hi = (us*)(ws + 57*MB);   // [57,65)
  us* kbuf_hi = (us*)(ws + 65*MB);   // [65,73)

  k_prep<<<14409, 256, 0, stream>>>(query, kvst, Wq, Wk, Wv, Wpk, Wpq, Wo,
                                    rel, lng, lnb,
                                    Xq_hi, Xkv_hi, Wt, reln_hi, idxt);

  k_qkvp<<<800, 256, 0, stream>>>(Xq_hi, Xkv_hi, Wt, bq, bk, bv,
                                  reln_hi, bpk, bpq,
                                  qbuf_hi, kbuf_hi, vtb, posk_hi, posq_hi);

  k_cp<<<dim3(16,64,2), 256, 0, stream>>>(qbuf_hi, kbuf_hi, posk_hi, posq_hi, c2p, p2c);

  k_attn<<<512, 512, 0, stream>>>(qbuf_hi, kbuf_hi, vtb,
                                  c2p, p2c, idxt, mask, ctx_hi);

  k_gemmo<<<512, 256, 0, stream>>>(ctx_hi, Wt + 5*2097152, Wt + 5*2097152 + 1048576, bo, (float*)d_out);
}

// Round 19
// 161.867 us; speedup vs baseline: 1.3157x; 1.0245x over previous
//
#include <hip/hip_runtime.h>
#include <cstdint>
#include <math.h>

typedef unsigned short us;
typedef __attribute__((ext_vector_type(8))) __bf16 bf16x8;
typedef __attribute__((ext_vector_type(8))) unsigned short ushort8;
typedef __attribute__((ext_vector_type(4))) float f32x4;

__device__ __forceinline__ us f2bf(float x){
  union { float f; unsigned int u; } v; v.f = x;
  unsigned int r = v.u + 0x7FFFu + ((v.u >> 16) & 1u);   // RNE
  return (us)(r >> 16);
}
__device__ __forceinline__ float b2f(us u){
  union { unsigned int u; float f; } v; v.u = ((unsigned int)u) << 16; return v.f;
}
__device__ __forceinline__ void split2(float x, us& hi, us& lo){
  hi = f2bf(x); lo = f2bf(x - b2f(hi));
}
__device__ __forceinline__ f32x4 fzero(){ f32x4 v; v.x=0.f; v.y=0.f; v.z=0.f; v.w=0.f; return v; }
__device__ __forceinline__ f32x4 mfma16(bf16x8 a, bf16x8 b, f32x4 c){
  return __builtin_amdgcn_mfma_f32_16x16x32_bf16(a, b, c, 0, 0, 0);
}
__device__ __forceinline__ void gload_lds16(const void* g, void* l){
  __builtin_amdgcn_global_load_lds(
      (const __attribute__((address_space(1))) unsigned int*)(uintptr_t)g,
      (__attribute__((address_space(3))) unsigned int*)(uintptr_t)l,
      16, 0, 0);
}

// exp2-folded scales
#define QS2 (0.07216878364870322f * 1.4426950408889634f)   // 1/sqrt(192) * log2(e)
#define BS  (0.08838834764831845f * 1.4426950408889634f)   // 1/sqrt(128) * log2(e)

// ---------------- 1: fused prep: convx | convw | lnrel | bucket ----------------
__global__ __launch_bounds__(256) void k_prep(const float* __restrict__ xq,
                                              const float* __restrict__ xkv,
                                              const float* __restrict__ w0, const float* __restrict__ w1,
                                              const float* __restrict__ w2, const float* __restrict__ w3,
                                              const float* __restrict__ w4, const float* __restrict__ w5,
                                              const float* __restrict__ rel,
                                              const float* __restrict__ g, const float* __restrict__ bLN,
                                              us* __restrict__ qhi, us* __restrict__ kvhi,
                                              us* __restrict__ wt, us* __restrict__ reln_hi,
                                              signed char* __restrict__ idxt)
{
  __shared__ float tile[32][33];
  __shared__ float sm[8];
  const int bid = blockIdx.x, t = threadIdx.x;

  if (bid < 8192){                      // ---- convx (hi only)
    int i = bid * 256 + t;
    const float* src; us* dh;
    if (i < 1048576){ src = xq  + (size_t)i*4;           dh = qhi  + (size_t)i*4; }
    else            { src = xkv + (size_t)(i-1048576)*4; dh = kvhi + (size_t)(i-1048576)*4; }
    f32x4 v = *(const f32x4*)src;
    dh[0]=f2bf(v.x); dh[1]=f2bf(v.y); dh[2]=f2bf(v.z); dh[3]=f2bf(v.w);
    return;
  }
  if (bid < 14336){                     // ---- convw: transpose + hi/lo split
    int rem = bid - 8192;
    int z = rem >> 10, r2 = rem & 1023;
    const float* W = (z==0)?w0:(z==1)?w1:(z==2)?w2:(z==3)?w3:(z==4)?w4:w5;
    us* dst_hi = wt + (size_t)z * 2097152;
    us* dst_lo = dst_hi + 1048576;
    bool wlo = (z == 2) || (z == 5);
    int n0 = (r2 & 31) * 32, k0 = (r2 >> 5) * 32;
    int c = t & 31, r = t >> 5;
#pragma unroll
    for (int i = 0; i < 4; i++)
      tile[r + i*8][c] = W[(size_t)(k0 + r + i*8)*1024 + n0 + c];
    __syncthreads();
#pragma unroll
    for (int i = 0; i < 4; i++){
      int nn = r + i*8;
      us h,l; split2(tile[c][nn], h, l);
      dst_hi[(size_t)(n0 + nn)*1024 + k0 + c] = h;
      if (wlo) dst_lo[(size_t)(n0 + nn)*1024 + k0 + c] = l;
    }
    return;
  }
  if (bid < 14400){                     // ---- lnrel
    int row = bid - 14336;
    const float* x = rel + (size_t)row * 1024;
    float v[4]; float s = 0.f, ss = 0.f;
#pragma unroll
    for (int i=0;i<4;i++){ v[i] = x[t + 256*i]; s += v[i]; ss += v[i]*v[i]; }
    for (int o=32;o;o>>=1){ s += __shfl_xor(s,o); ss += __shfl_xor(ss,o); }
    int w = t >> 6;
    if ((t & 63) == 0){ sm[w] = s; sm[4+w] = ss; }
    __syncthreads();
    s  = sm[0]+sm[1]+sm[2]+sm[3];
    ss = sm[4]+sm[5]+sm[6]+sm[7];
    float mu  = s  * (1.0f/1024.0f);
    float var = ss * (1.0f/1024.0f) - mu*mu;
    float rs  = rsqrtf(var + 1e-5f);
#pragma unroll
    for (int i=0;i<4;i++){
      int cc = t + 256*i;
      reln_hi[(size_t)row*1024 + cc] = f2bf((v[i]-mu)*rs*g[cc] + bLN[cc]);
    }
    return;
  }
  {                                     // ---- bucket table
    int i = (bid - 14400) * 256 + t;
    if (i >= 2052) return;
    int d = i - 1023;
    int ad = d < 0 ? -d : d;
    int abspos = (d < 16 && d > -16) ? 15 : ad;
    int bucket;
    if (abspos <= 16) bucket = d;
    else {
      float num = (float)log((double)abspos * 0.0625);
      float den = (float)log(7.9375);
      float lp = ceilf(num / den * 15.0f) + 16.0f;
      bucket = (int)lp * (d > 0 ? 1 : -1);
    }
    int s = bucket + 32;
    s = s < 0 ? 0 : (s > 63 ? 63 : s);
    idxt[i] = (signed char)s;
  }
}

// ---------------- 2: merged QKV GEMM + pos projections, grid=800 ----------------
__global__ __launch_bounds__(256) void k_qkvp(const us* __restrict__ Xq, const us* __restrict__ Xkv,
                                              const us* __restrict__ wt,
                                              const float* __restrict__ bq, const float* __restrict__ bk,
                                              const float* __restrict__ bv,
                                              const us* __restrict__ reln_hi,
                                              const float* __restrict__ bpk, const float* __restrict__ bpq,
                                              us* __restrict__ qbuf, us* __restrict__ kbuf,
                                              us* __restrict__ vtb,
                                              us* __restrict__ posk_hi, us* __restrict__ posq_hi)
{
  __shared__ __align__(16) us a_lds[2][4096];   // 128 x 32
  __shared__ __align__(16) us b_lds[2][8192];   // Q/K: first 4096 used ; V: hi [0,4096) + lo [4096,8192)
  const int bid = blockIdx.x;
  const int t = threadIdx.x, w = t >> 6, lane = t & 63, lg = lane >> 4, li = lane & 15;

  if (bid < 32){                        // ---- pos projections
    int ntile = bid & 15, z = bid >> 4;
    const us* W_hi = wt + (size_t)(3 + z) * 2097152;
    const float* bias = z ? bpq : bpk;
    us* out_hi = z ? posq_hi : posk_hi;
    f32x4 acc[4];
#pragma unroll
    for (int i=0;i<4;i++) acc[i] = fzero();
    int srow = w*16 + li;
    for (int kt = 0; kt < 32; kt++){
      int k0 = kt*32 + lg*8;
      bf16x8 a = *(const bf16x8*)(reln_hi + (size_t)srow*1024 + k0);
#pragma unroll
      for (int nf=0; nf<4; nf++){
        int n = ntile*64 + nf*16 + li;
        bf16x8 b = *(const bf16x8*)(W_hi + (size_t)n*1024 + k0);
        acc[nf] = mfma16(a, b, acc[nf]);
      }
    }
#pragma unroll
    for (int nf=0;nf<4;nf++){
      int n = ntile*64 + nf*16 + li;
      float bn = bias[n];
      int h = n >> 6, hd = n & 63;
#pragma unroll
      for (int j=0;j<4;j++){
        int s = w*16 + lg*4 + j;
        out_hi[(size_t)h*4096 + s*64 + hd] = f2bf(acc[nf][j] + bn);
      }
    }
    return;
  }

  if (bid < 544){                       // ---- Q / K classes (proven geometry)
    int cls = (bid - 32) >> 8;          // 0:Q 1:K
    int u = (bid - 32) & 255;
    int tile = (u & 7) * 32 + (u >> 3); // XCD-contiguous chunk within class
    int mt = tile >> 3, nt = tile & 7;
    int m0 = mt * 128, n0 = nt * 128;
    const us* A  = cls ? Xkv : Xq;
    const us* Bp = wt + (size_t)cls * 2097152;
    const float* bias = cls ? bk : bq;
    us* out = cls ? kbuf : qbuf;
    int wm = w >> 1, wn = w & 1;
    f32x4 acc[4][4];
#pragma unroll
    for (int i=0;i<4;i++)
#pragma unroll
      for (int j=0;j<4;j++) acc[i][j] = fzero();

    auto stage = [&](int buf, int kt){
      int k0 = kt * 32;
#pragma unroll
      for (int c = 0; c < 2; c++){
        int slot = c*256 + t;
        int g = slot ^ ((slot >> 3) & 7);
        int r = g >> 2, kc = g & 3;
        gload_lds16(A  + (size_t)(m0 + r)*1024 + k0 + kc*8, (char*)&a_lds[buf][0] + slot*16);
        gload_lds16(Bp + (size_t)(n0 + r)*1024 + k0 + kc*8, (char*)&b_lds[buf][0] + slot*16);
      }
    };

    stage(0, 0);
    __syncthreads();
    int buf = 0;
    for (int kt = 0; kt < 32; kt++){
      if (kt + 1 < 32) stage(buf ^ 1, kt + 1);
      bf16x8 af[4], bfv[4];
#pragma unroll
      for (int mi=0;mi<4;mi++){
        int r = wm*64 + mi*16 + li;
        int s = (r*4 + lg); s ^= ((s >> 3) & 7);
        af[mi] = *(const bf16x8*)((char*)&a_lds[buf][0] + s*16);
      }
#pragma unroll
      for (int ni=0;ni<4;ni++){
        int r = wn*64 + ni*16 + li;
        int s = (r*4 + lg); s ^= ((s >> 3) & 7);
        bfv[ni] = *(const bf16x8*)((char*)&b_lds[buf][0] + s*16);
      }
#pragma unroll
      for (int mi=0;mi<4;mi++)
#pragma unroll
        for (int ni=0;ni<4;ni++)
          acc[mi][ni] = mfma16(af[mi], bfv[ni], acc[mi][ni]);
      __syncthreads();
      buf ^= 1;
    }

#pragma unroll
    for (int ni=0;ni<4;ni++){
      int n = n0 + wn*64 + ni*16 + li;
      float bn = bias[n];
      int hh = n >> 6, hd = n & 63;
#pragma unroll
      for (int mi=0;mi<4;mi++){
        int mb = m0 + wm*64 + mi*16 + lg*4;
#pragma unroll
        for (int j=0;j<4;j++){
          int m = mb + j;
          int bb = m >> 10, tp = m & 1023;
          out[(((size_t)(bb*16 + hh))*1024 + tp)*64 + hd] = f2bf(acc[mi][ni][j] + bn);
        }
      }
    }
    return;
  }

  // ---- V class: BM=128, BN=128, 32 iters, fused hi+lo (32 MFMA/interval), 256 blocks
  {
    int u = bid - 544;
    int tile = (u & 7) * 32 + (u >> 3);
    int mt = tile >> 3, nt = tile & 7;
    int m0 = mt * 128, n0 = nt * 128;
    const us* Bh = wt + (size_t)2 * 2097152;
    const us* Bl = Bh + 1048576;
    int wm = w >> 1, wn = w & 1;
    f32x4 acc[4][4];
#pragma unroll
    for (int i=0;i<4;i++)
#pragma unroll
      for (int j=0;j<4;j++) acc[i][j] = fzero();

    auto stage = [&](int buf, int kt){
      int k0 = kt * 32;
#pragma unroll
      for (int c = 0; c < 2; c++){
        int slot = c*256 + t;
        int g = slot ^ ((slot >> 3) & 7);
        int r = g >> 2, kc = g & 3;
        gload_lds16(Xkv + (size_t)(m0 + r)*1024 + k0 + kc*8, (char*)&a_lds[buf][0] + slot*16);
        gload_lds16(Bh  + (size_t)(n0 + r)*1024 + k0 + kc*8, (char*)&b_lds[buf][0] + slot*16);
        gload_lds16(Bl  + (size_t)(n0 + r)*1024 + k0 + kc*8, (char*)&b_lds[buf][0] + 8192 + slot*16);
      }
    };

    stage(0, 0);
    __syncthreads();
    int buf = 0;
    for (int kt = 0; kt < 32; kt++){
      if (kt + 1 < 32) stage(buf ^ 1, kt + 1);
      bf16x8 af[4], bh_[4], bl_[4];
#pragma unroll
      for (int mi=0;mi<4;mi++){
        int r = wm*64 + mi*16 + li;
        int s = (r*4 + lg); s ^= ((s >> 3) & 7);
        af[mi] = *(const bf16x8*)((char*)&a_lds[buf][0] + s*16);
      }
#pragma unroll
      for (int ni=0;ni<4;ni++){
        int r = wn*64 + ni*16 + li;
        int s = (r*4 + lg); s ^= ((s >> 3) & 7);
        bh_[ni] = *(const bf16x8*)((char*)&b_lds[buf][0] + s*16);
        bl_[ni] = *(const bf16x8*)((char*)&b_lds[buf][0] + 8192 + s*16);
      }
#pragma unroll
      for (int mi=0;mi<4;mi++)
#pragma unroll
        for (int ni=0;ni<4;ni++){
          acc[mi][ni] = mfma16(af[mi], bh_[ni], acc[mi][ni]);
          acc[mi][ni] = mfma16(af[mi], bl_[ni], acc[mi][ni]);
        }
      __syncthreads();
      buf ^= 1;
    }

#pragma unroll
    for (int ni=0;ni<4;ni++){
      int n = n0 + wn*64 + ni*16 + li;
      float bn = bv[n];
      int hh = n >> 6, hd = n & 63;
#pragma unroll
      for (int mi=0;mi<4;mi++){
        int mb = m0 + wm*64 + mi*16 + lg*4;
#pragma unroll
        for (int j=0;j<4;j++){
          int m = mb + j;
          int bb = m >> 10, tp = m & 1023;
          vtb[(((size_t)(bb*16 + hh))*64 + hd)*1024 + tp] = f2bf(acc[mi][ni][j] + bn);
        }
      }
    }
  }
}

// ---------------- 3: O GEMM: fused 2 products, 32 iters; B staged as FULL 64x32 per half ----------------
__global__ __launch_bounds__(256, 2) void k_gemmo(const us* __restrict__ A_hi,
                                                  const us* __restrict__ B_hi, const us* __restrict__ B_lo,
                                                  const float* __restrict__ bias,
                                                  float* __restrict__ out_f)
{
  __shared__ __align__(16) us a_lds[2][4096];   // 128 x 32
  __shared__ __align__(16) us b_lds[2][4096];   // Bhi 64x32 bytes [0,4096) + Blo 64x32 bytes [4096,8192)
  int bid = blockIdx.x;
  int wg = (bid & 7) * 64 + (bid >> 3);        // 512 % 8 == 0
  int mt = wg >> 4, nt = wg & 15;
  int m0 = mt * 128, n0 = nt * 64;
  int t = threadIdx.x, w = t >> 6, lane = t & 63, lg = lane >> 4, li = lane & 15;
  int wm = w >> 1, wn = w & 1;
  f32x4 acc[4][2];
#pragma unroll
  for (int i=0;i<4;i++){ acc[i][0]=fzero(); acc[i][1]=fzero(); }

  auto stage = [&](int buf, int kt){
    int k0 = kt * 32;
#pragma unroll
    for (int c = 0; c < 2; c++){     // A: 128x32 = 512 chunks
      int slot = c*256 + t;
      int g = slot ^ ((slot >> 3) & 7);
      int r = g >> 2, kc = g & 3;
      gload_lds16(A_hi + (size_t)(m0 + r)*1024 + k0 + kc*8, (char*)&a_lds[buf][0] + slot*16);
    }
#pragma unroll
    for (int c = 0; c < 2; c++){     // B: Bhi 256 chunks + Blo 256 chunks
      int slot = c*256 + t;
      int half = slot >> 8;          // 0: Bhi, 1: Blo
      int s2 = slot & 255;
      int g = s2 ^ ((s2 >> 3) & 7);
      int r = g >> 2, kc = g & 3;
      const us* Bp = half ? B_lo : B_hi;
      gload_lds16(Bp + (size_t)(n0 + r)*1024 + k0 + kc*8,
                  (char*)&b_lds[buf][0] + half*4096 + s2*16);
    }
  };

  stage(0, 0);
  __syncthreads();
  int buf = 0;
  for (int kt = 0; kt < 32; kt++){
    if (kt + 1 < 32) stage(buf ^ 1, kt + 1);
    bf16x8 af[4], bhv[2], blv[2];
#pragma unroll
    for (int mi=0;mi<4;mi++){
      int r = wm*64 + mi*16 + li;
      int s = (r*4 + lg); s ^= ((s >> 3) & 7);
      af[mi] = *(const bf16x8*)((char*)&a_lds[buf][0] + s*16);
    }
#pragma unroll
    for (int ni=0;ni<2;ni++){
      int r = wn*32 + ni*16 + li;
      int s = (r*4 + lg); s ^= ((s >> 3) & 7);
      bhv[ni] = *(const bf16x8*)((char*)&b_lds[buf][0] + s*16);
      blv[ni] = *(const bf16x8*)((char*)&b_lds[buf][0] + 4096 + s*16);
    }
#pragma unroll
    for (int mi=0;mi<4;mi++)
#pragma unroll
      for (int ni=0;ni<2;ni++){
        acc[mi][ni] = mfma16(af[mi], bhv[ni], acc[mi][ni]);
        acc[mi][ni] = mfma16(af[mi], blv[ni], acc[mi][ni]);
      }
    __syncthreads();
    buf ^= 1;
  }

#pragma unroll
  for (int ni=0;ni<2;ni++){
    int n = n0 + wn*32 + ni*16 + li;
    float bn = bias[n];
#pragma unroll
    for (int mi=0;mi<4;mi++){
      int mb = m0 + wm*64 + mi*16 + lg*4;
#pragma unroll
      for (int j=0;j<4;j++)
        out_f[(size_t)(mb + j)*1024 + n] = acc[mi][ni][j] + bn;
    }
  }
}

// ---------------- 4: c2p/p2c (single product, pre-scaled by BS for exp2) ----------------
__global__ __launch_bounds__(256) void k_cp(const us* __restrict__ q_hi,
                                            const us* __restrict__ k_hi,
                                            const us* __restrict__ pk_hi,
                                            const us* __restrict__ pq_hi,
                                            us* __restrict__ c2p, us* __restrict__ p2c)
{
  int qt = blockIdx.x, bh = blockIdx.y, z = blockIdx.z;
  const us* X_hi = z ? k_hi : q_hi;
  const us* P_hi = z ? pq_hi : pk_hi;
  us* out = z ? p2c : c2p;
  int h = bh & 15;
  int t = threadIdx.x, w = t >> 6, lane = t & 63, lg = lane >> 4, li = lane & 15;
  f32x4 acc[4];
#pragma unroll
  for (int i=0;i<4;i++) acc[i] = fzero();
  size_t row = (size_t)bh*1024 + qt*64 + w*16 + li;
#pragma unroll
  for (int kk=0;kk<2;kk++){
    int k = kk*32 + lg*8;
    bf16x8 ah = *(const bf16x8*)(X_hi + row*64 + k);
#pragma unroll
    for (int nf=0;nf<4;nf++){
      int s = nf*16 + li;
      bf16x8 bh_ = *(const bf16x8*)(P_hi + (size_t)h*4096 + s*64 + k);
      acc[nf] = mfma16(ah, bh_, acc[nf]);
    }
  }
  size_t obase = ((size_t)bh*1024 + qt*64 + w*16 + lg*4) * 64;
#pragma unroll
  for (int nf=0;nf<4;nf++)
#pragma unroll
    for (int j=0;j<4;j++)
      out[obase + (size_t)j*64 + nf*16 + li] = f2bf(acc[nf][j] * BS);
}

// ---------------- 5: fused attention: 8 waves, QBLK=128, bh-pinned XCD swizzle (r16 form) ----------------
__global__ __launch_bounds__(512) void k_attn(const us* __restrict__ qhi,
                                              const us* __restrict__ khi,
                                              const us* __restrict__ vhi,
                                              const us* __restrict__ c2p, const us* __restrict__ p2c,
                                              const signed char* __restrict__ idxt,
                                              const unsigned char* __restrict__ mask,
                                              us* __restrict__ ctx_hi)
{
  __shared__ __align__(16) us khi_lds[4096], vhi_lds[4096];
  __shared__ __align__(16) us c2p_lds[128*72], p2c_lds[64*72];   // padded rows: 144B stride
  __shared__ __align__(16) us p_lds[8][1024];
  __shared__ signed char idx_lds[2048];

  const int bid = blockIdx.x;
  const int xg = bid & 7, rest = bid >> 3;
  const int qt = rest & 7;
  const int bh = xg + ((rest >> 3) << 3);
  const int b = bh >> 4, h = bh & 15;
  const int t = threadIdx.x, w = t >> 6, lane = t & 63, lg = lane >> 4, li = lane & 15;
  const int q0 = qt * 128;

  for (int i = t; i < 2047; i += 512) idx_lds[i] = idxt[i];
  {
    const us* src = c2p + ((size_t)bh*1024 + q0) * 64;
#pragma unroll
    for (int c = 0; c < 2; c++){
      int f = c*512 + t, r = f >> 3, kc = f & 7;
      *(ushort8*)&c2p_lds[r*72 + kc*8] = *(const ushort8*)(src + r*64 + kc*8);
    }
  }
  bf16x8 qfh[2];
  {
    const us* qph = qhi + ((size_t)bh*1024 + q0 + w*16 + li)*64 + lg*8;
    qfh[0] = *(const bf16x8*)(qph); qfh[1] = *(const bf16x8*)(qph + 32);
  }
  __syncthreads();
  // far-path per-row bias (scaled) for idx=0 / idx=63
  float cq0[4], cq63[4];
#pragma unroll
  for (int j=0;j<4;j++){
    int qloc = w*16 + lg*4 + j;
    cq0[j]  = b2f(c2p_lds[qloc*72 + 0]);
    cq63[j] = b2f(c2p_lds[qloc*72 + 63]);
  }

  float lrow[4];
  f32x4 accO[4];
#pragma unroll
  for (int j=0;j<4;j++){ lrow[j] = 0.f; accO[j] = fzero(); }
  const unsigned char* mptr = mask + b*1024;

  for (int kt = 0; kt < 16; kt++){
    const int k0 = kt * 64;
    const bool far = (q0 - k0 >= 192) || (k0 - q0 >= 256);
    __syncthreads();
    {  // stage K,V: one 16B chunk each per thread
      int r = t >> 3, kc = t & 7;
      *(ushort8*)&khi_lds[r*64 + ((kc ^ (r & 7))*8)] =
          *(const ushort8*)(khi + ((size_t)bh*1024 + k0 + r)*64 + kc*8);
      *(ushort8*)&vhi_lds[r*64 + ((kc ^ (r & 7))*8)] =
          *(const ushort8*)(vhi + ((size_t)bh*64 + r)*1024 + k0 + kc*8);
      if (!far)
        *(ushort8*)&p2c_lds[r*72 + kc*8] =
            *(const ushort8*)(p2c + ((size_t)bh*1024 + k0 + r)*64 + kc*8);
    }
    __syncthreads();

    // QK^T single product
    f32x4 sfr[4];
#pragma unroll
    for (int nf=0;nf<4;nf++) sfr[nf] = fzero();
#pragma unroll
    for (int kk=0; kk<2; kk++){
      int kc = kk*4 + lg;
#pragma unroll
      for (int nf=0; nf<4; nf++){
        int r = nf*16 + li;
        bf16x8 bh_ = *(const bf16x8*)&khi_lds[r*64 + ((kc ^ (r & 7))*8)];
        sfr[nf] = mfma16(qfh[kk], bh_, sfr[nf]);
      }
    }
    us* pl = &p_lds[w][0];
    if (far){
      const int cidx = (q0 > k0) ? 63 : 0;
      float cq[4];
#pragma unroll
      for (int j=0;j<4;j++) cq[j] = (q0 > k0) ? cq63[j] : cq0[j];
#pragma unroll
      for (int nf=0; nf<4; nf++){
        int kloc = nf*16 + li;
        bool mk = mptr[k0 + kloc] != 0;
        float ck = b2f(p2c[((size_t)bh*1024 + k0 + kloc)*64 + cidx]);
        int col = kloc;
#pragma unroll
        for (int j=0;j<4;j++){
          float p = mk ? 0.f : exp2f(fmaf(sfr[nf][j], QS2, cq[j] + ck));
          lrow[j] += p;
          int row = lg*4 + j;
          pl[row*64 + ((col & 7) | ((((col >> 3) ^ (row & 7))) << 3))] = f2bf(p);
        }
      }
    } else {
#pragma unroll
      for (int nf=0; nf<4; nf++){
        int kloc = nf*16 + li;
        bool mk = mptr[k0 + kloc] != 0;
        int col = kloc;
#pragma unroll
        for (int j=0;j<4;j++){
          int qloc = w*16 + lg*4 + j;
          int d = (q0 + qloc) - (k0 + kloc);
          int idx = (int)idx_lds[d + 1023];
          float s2 = fmaf(sfr[nf][j], QS2,
                          b2f(c2p_lds[qloc*72 + idx]) + b2f(p2c_lds[kloc*72 + idx]));
          float p = mk ? 0.f : exp2f(s2);
          lrow[j] += p;
          int row = lg*4 + j;
          pl[row*64 + ((col & 7) | ((((col >> 3) ^ (row & 7))) << 3))] = f2bf(p);
        }
      }
    }
    // PV single product (p_lds wave-private; same-wave DS ordering)
#pragma unroll
    for (int kk=0;kk<2;kk++){
      int kc = kk*4 + lg;
      bf16x8 af = *(const bf16x8*)((char*)pl + li*128 + ((kc ^ (li & 7)) * 16));
#pragma unroll
      for (int nf=0;nf<4;nf++){
        int r = nf*16 + li;
        bf16x8 bh_ = *(const bf16x8*)&vhi_lds[r*64 + ((kc ^ (r & 7))*8)];
        accO[nf] = mfma16(af, bh_, accO[nf]);
      }
    }
  }

  for (int o=1;o<16;o<<=1)
#pragma unroll
    for (int j=0;j<4;j++)
      lrow[j] += __shfl_xor(lrow[j], o);
#pragma unroll
  for (int nf=0;nf<4;nf++)
#pragma unroll
    for (int j=0;j<4;j++){
      int qloc = w*16 + lg*4 + j;
      float o = accO[nf][j] / lrow[j];
      size_t idx = ((size_t)(b*1024 + q0 + qloc))*1024 + h*64 + nf*16 + li;
      ctx_hi[idx] = f2bf(o);
    }
}

// ---------------- launch ----------------
extern "C" void kernel_launch(void* const* d_in, const int* in_sizes, int n_in,
                              void* d_out, int out_size, void* d_ws, size_t ws_size,
                              hipStream_t stream)
{
  (void)in_sizes; (void)n_in; (void)out_size; (void)ws_size;
  const float* query = (const float*)d_in[0];
  const float* kvst  = (const float*)d_in[1];
  const unsigned char* mask = (const unsigned char*)d_in[2];
  const float* Wq = (const float*)d_in[3];  const float* bq = (const float*)d_in[4];
  const float* Wk = (const float*)d_in[5];  const float* bk = (const float*)d_in[6];
  const float* Wv = (const float*)d_in[7];  const float* bv = (const float*)d_in[8];
  const float* Wo = (const float*)d_in[9];  const float* bo = (const float*)d_in[10];
  const float* rel = (const float*)d_in[11];
  const float* lng = (const float*)d_in[12]; const float* lnb = (const float*)d_in[13];
  const float* Wpk = (const float*)d_in[14]; const float* bpk = (const float*)d_in[15];
  const float* Wpq = (const float*)d_in[16]; const float* bpq = (const float*)d_in[17];

  char* ws = (char*)d_ws;
  const size_t MB = 1024*1024;
  us* Xq_hi  = (us*)(ws + 0);        // [0,8)   dead after k_qkvp
  us* p2c    = (us*)(ws + 8*MB);     // [8,16)  k_cp z=1 writes (after k_qkvp)
  us* Xkv_hi = (us*)(ws + 16*MB);    // [16,24) dead after k_qkvp
  us* c2p    = (us*)(ws + 16*MB);    //         k_cp z=0 writes
  us* vtb    = (us*)(ws + 24*MB);    // [24,32) k_qkvp V writes; k_attn reads
  us* Wt     = (us*)(ws + 32*MB);    // [32,56) 6 slots x 4MB
  us* ctx_hi = (us*)(ws + 32*MB);    //         k_attn writes over Wq/Wk slots (dead)
  us* reln_hi = (us*)(ws + 56*MB);
  us* posk_hi = (us*)(ws + 56*MB + 256*1024);
  us* posq_hi = (us*)(ws + 56*MB + 512*1024);
  signed char* idxt = (signed char*)(ws + 56*MB + 768*1024);
  us* qbuf_hi = (us*)(ws + 57*MB);   // [57,65)
  us* kbuf_hi = (us*)(ws + 65*MB);   // [65,73)

  k_prep<<<14409, 256, 0, stream>>>(query, kvst, Wq, Wk, Wv, Wpk, Wpq, Wo,
                                    rel, lng, lnb,
                                    Xq_hi, Xkv_hi, Wt, reln_hi, idxt);

  k_qkvp<<<800, 256, 0, stream>>>(Xq_hi, Xkv_hi, Wt, bq, bk, bv,
                                  reln_hi, bpk, bpq,
                                  qbuf_hi, kbuf_hi, vtb, posk_hi, posq_hi);

  k_cp<<<dim3(16,64,2), 256, 0, stream>>>(qbuf_hi, kbuf_hi, posk_hi, posq_hi, c2p, p2c);

  k_attn<<<512, 512, 0, stream>>>(qbuf_hi, kbuf_hi, vtb,
                                  c2p, p2c, idxt, mask, ctx_hi);

  k_gemmo<<<512, 256, 0, stream>>>(ctx_hi, Wt + 5*2097152, Wt + 5*2097152 + 1048576, bo, (float*)d_out);
}